// Round 1
// baseline (11695.491 us; speedup 1.0000x reference)
//
#include <hip/hip_runtime.h>
#include <cmath>

// ============================ constants ============================
static constexpr int kAImg = 159375;   // anchors per image
static constexpr int kNCand = 7875;    // 2000+2000+2000+1875
static constexpr int kPostNms = 2000;

__constant__ int c_AOFF[4]   = {0, 120000, 150000, 157500};
__constant__ int c_ALVL[4]   = {120000, 30000, 7500, 1875};
__constant__ int c_CBASE[4]  = {0, 2000, 4000, 6000};
__constant__ int c_LW[4]     = {200, 100, 50, 25};
__constant__ int c_LH[4]     = {200, 100, 50, 25};
__constant__ int c_STRIDE[4] = {4, 8, 16, 32};

struct Cand     { float x1, y1, x2, y2; unsigned key; unsigned lvl; unsigned pad0, pad1; };
struct HeadCand { float x1, y1, x2, y2; float score; unsigned key; unsigned pad0, pad1; };
struct RoiParam { int lvl; float x1, y1, rw, rh; int pad0, pad1, pad2; };
struct AnchTab  { float v[4][3][4]; };

// ============================ device helpers ============================
__device__ __forceinline__ unsigned keyOf(float f) {
  unsigned u = __float_as_uint(f);
  return (u & 0x80000000u) ? ~u : (u | 0x80000000u);
}

__device__ __forceinline__ float iou_pair(float4 a, float4 b) {
#pragma clang fp contract(off)
  float ix1 = fmaxf(a.x, b.x), iy1 = fmaxf(a.y, b.y);
  float ix2 = fminf(a.z, b.z), iy2 = fminf(a.w, b.w);
  float iw = fmaxf(ix2 - ix1, 0.f), ih = fmaxf(iy2 - iy1, 0.f);
  float inter = iw * ih;
  float a1 = (a.z - a.x) * (a.w - a.y);
  float a2 = (b.z - b.x) * (b.w - b.y);
  float uni = a1 + a2 - inter;
  return uni > 0.f ? inter / uni : 0.f;
}

__device__ __forceinline__ float4 decode_clip(float bx1, float by1, float bx2, float by2,
                                              float d0, float d1, float d2, float d3,
                                              float wx, float wy, float ww, float wh) {
#pragma clang fp contract(off)
  float w = bx2 - bx1, h = by2 - by1;
  float cx = bx1 + 0.5f * w, cy = by1 + 0.5f * h;
  float dx = d0 / wx, dy = d1 / wy;
  float dw = fminf(d2 / ww, 4.135166556742356f);
  float dh = fminf(d3 / wh, 4.135166556742356f);
  float pcx = dx * w + cx, pcy = dy * h + cy;
  float pw = expf(dw) * w, ph = expf(dh) * h;
  float x1 = pcx - 0.5f * pw, y1 = pcy - 0.5f * ph;
  float x2 = pcx + 0.5f * pw, y2 = pcy + 0.5f * ph;
  x1 = fminf(fmaxf(x1, 0.f), 800.f); y1 = fminf(fmaxf(y1, 0.f), 800.f);
  x2 = fminf(fmaxf(x2, 0.f), 800.f); y2 = fminf(fmaxf(y2, 0.f), 800.f);
  return make_float4(x1, y1, x2, y2);
}

// block-wide exclusive scan of a bool over 1024 threads (16 waves)
__device__ __forceinline__ unsigned block_scan_bool(bool p, unsigned* wbuf, unsigned& total) {
  unsigned long long m = __ballot(p);
  int lane = threadIdx.x & 63;
  int wid = threadIdx.x >> 6;
  unsigned exc = (unsigned)__popcll(m & ((lane == 0) ? 0ull : ((~0ull) >> (64 - lane))));
  if (lane == 0) wbuf[wid] = (unsigned)__popcll(m);
  __syncthreads();
  unsigned pre = 0, tot = 0;
#pragma unroll
  for (int w = 0; w < 16; w++) { unsigned c = wbuf[w]; if (w < wid) pre += c; tot += c; }
  total = tot;
  __syncthreads();
  return pre + exc;
}

// ============================ RPN conv (3x3+relu fused with 1x1 heads) ============================
// block: 256 threads -> 128 out-channels x 16 positions (one row segment).
__global__ __launch_bounds__(256) void rpn_conv_kernel(
    const float* __restrict__ feat, int H, int W,
    const float* __restrict__ w3, const float* __restrict__ b3,
    const float* __restrict__ wc, const float* __restrict__ bcs,
    const float* __restrict__ wb, const float* __restrict__ bbx,
    unsigned* __restrict__ keys, float* __restrict__ deltas, int aoff) {
  __shared__ float Wl[128 * 73];          // 8-ci chunk of weights, padded stride 73
  __shared__ float patch[8][3][20];       // 8 ci x 3 rows x 18(+pad) cols
  __shared__ float tt[16][129];           // hidden t tile [pos][co], padded
  int tid = threadIdx.x;
  int co = tid & 127, half = tid >> 7;
  int x0 = blockIdx.x * 16;
  int y = blockIdx.y;
  float acc[8];
#pragma unroll
  for (int j = 0; j < 8; j++) acc[j] = 0.f;

  for (int ci0 = 0; ci0 < 128; ci0 += 8) {
    for (int e = tid; e < 128 * 72; e += 256) {
      int r = e / 72, q = e - r * 72;
      Wl[r * 73 + q] = w3[r * 1152 + ci0 * 9 + q];
    }
    for (int e = tid; e < 8 * 54; e += 256) {
      int ci = e / 54, q = e - ci * 54;
      int dy = q / 18, dx = q - dy * 18;
      int gy = y + dy - 1, gx = x0 + dx - 1;
      float v = 0.f;
      if (gy >= 0 && gy < H && gx >= 0 && gx < W)
        v = feat[(size_t)(ci0 + ci) * H * W + gy * W + gx];
      patch[ci][dy][dx] = v;
    }
    __syncthreads();
    for (int ci = 0; ci < 8; ci++) {
#pragma unroll
      for (int ky = 0; ky < 3; ky++) {
        float row[10];
#pragma unroll
        for (int d = 0; d < 10; d++) row[d] = patch[ci][ky][half * 8 + d];
#pragma unroll
        for (int kx = 0; kx < 3; kx++) {
          float wv = Wl[co * 73 + ci * 9 + ky * 3 + kx];
#pragma unroll
          for (int j = 0; j < 8; j++) acc[j] = fmaf(wv, row[j + kx], acc[j]);
        }
      }
    }
    __syncthreads();
  }
  float bias3 = b3[co];
#pragma unroll
  for (int j = 0; j < 8; j++) tt[half * 8 + j][co] = fmaxf(acc[j] + bias3, 0.f);
  __syncthreads();
  if (tid < 240) {
    int oc = tid / 16, p = tid - (tid / 16) * 16;
    int x = x0 + p;
    if (x < W) {
      const float* wrow = (oc < 3) ? (wc + oc * 128) : (wb + (oc - 3) * 128);
      float bias = (oc < 3) ? bcs[oc] : bbx[oc - 3];
      float dot = 0.f;
      for (int k = 0; k < 128; k++) dot = fmaf(wrow[k], tt[p][k], dot);
      float s = dot + bias;
      int pos = y * W + x;
      if (oc < 3) {
        keys[aoff + pos * 3 + oc] = keyOf(s);
      } else {
        int bc = oc - 3, a = bc >> 2, comp = bc & 3;
        deltas[(size_t)(aoff + pos * 3 + a) * 4 + comp] = s;
      }
    }
  }
}

// ============================ radix select (kth largest key) per (image,level 0..2) ============================
__global__ __launch_bounds__(1024) void radix_select_kernel(
    const unsigned* __restrict__ keys, unsigned* __restrict__ tkT, unsigned* __restrict__ tkNeed) {
  int job = blockIdx.x;
  int b = job / 3, l = job - b * 3;
  const unsigned* kb = keys + (size_t)b * kAImg + c_AOFF[l];
  int n = c_ALVL[l];
  __shared__ unsigned hist[256];
  __shared__ unsigned s_sel, s_remk;
  unsigned prefix = 0, pmask = 0, remk = 2000;
  for (int shift = 24; shift >= 0; shift -= 8) {
    if (threadIdx.x < 256) hist[threadIdx.x] = 0;
    __syncthreads();
    for (int i = threadIdx.x; i < n; i += 1024) {
      unsigned key = kb[i];
      if ((key & pmask) == prefix) atomicAdd(&hist[(key >> shift) & 255u], 1u);
    }
    __syncthreads();
    if (threadIdx.x == 0) {
      unsigned cum = 0; int sel = 0;
      for (int d = 255; d >= 0; d--) {
        unsigned c = hist[d];
        if (cum + c >= remk) { sel = d; break; }
        cum += c;
      }
      s_sel = (unsigned)sel; s_remk = remk - cum;
    }
    __syncthreads();
    prefix |= (s_sel << shift);
    pmask |= (255u << shift);
    remk = s_remk;
    __syncthreads();
  }
  if (threadIdx.x == 0) { tkT[b * 4 + l] = prefix; tkNeed[b * 4 + l] = remk; }
}

// ============================ candidate build (stable compaction + decode + clip) ============================
__global__ __launch_bounds__(1024) void cand_build_kernel(
    const unsigned* __restrict__ keys, const float* __restrict__ deltas,
    const unsigned* __restrict__ tkT, const unsigned* __restrict__ tkNeed,
    Cand* __restrict__ cand, AnchTab tab) {
  int b = blockIdx.x >> 2, l = blockIdx.x & 3;
  int n = c_ALVL[l];
  int W = c_LW[l];
  int stride = c_STRIDE[l];
  const unsigned* kb = keys + (size_t)b * kAImg + c_AOFF[l];
  const float* db = deltas + ((size_t)b * kAImg + c_AOFF[l]) * 4;
  Cand* cb = cand + (size_t)b * kNCand + c_CBASE[l];
  bool selAll = (l == 3);
  unsigned T = selAll ? 0u : tkT[b * 4 + l];
  unsigned need = selAll ? 0u : tkNeed[b * 4 + l];
  __shared__ unsigned wbuf[16];
  __shared__ unsigned s_runeq, s_runout;
  if (threadIdx.x == 0) { s_runeq = 0; s_runout = 0; }
  __syncthreads();
  for (int c0 = 0; c0 < n; c0 += 1024) {
    int i = c0 + (int)threadIdx.x;
    bool act = i < n;
    unsigned key = act ? kb[i] : 0u;
    bool isEq = (!selAll) && act && (key == T);
    unsigned eqTot;
    unsigned eqExc = block_scan_bool(isEq, wbuf, eqTot);
    unsigned runeq = s_runeq;
    unsigned runout = s_runout;
    bool isSel = act && (selAll || key > T || (isEq && (runeq + eqExc) < need));
    unsigned selTot;
    unsigned selExc = block_scan_bool(isSel, wbuf, selTot);
    if (isSel) {
      int slot = (int)(runout + selExc);
      int pos = i / 3, a = i - pos * 3;
      int yy = pos / W, xx = pos - yy * W;
      float sx = (float)(xx * stride), sy = (float)(yy * stride);
      float ax1 = tab.v[l][a][0] + sx;
      float ay1 = tab.v[l][a][1] + sy;
      float ax2 = tab.v[l][a][2] + sx;
      float ay2 = tab.v[l][a][3] + sy;
      float d0 = db[(size_t)i * 4 + 0], d1 = db[(size_t)i * 4 + 1];
      float d2 = db[(size_t)i * 4 + 2], d3 = db[(size_t)i * 4 + 3];
      float4 bx = decode_clip(ax1, ay1, ax2, ay2, d0, d1, d2, d3, 1.f, 1.f, 1.f, 1.f);
      bool ok = (bx.z - bx.x >= 0.001f) && (bx.w - bx.y >= 0.001f);
      Cand cd;
      cd.x1 = bx.x; cd.y1 = bx.y; cd.x2 = bx.z; cd.y2 = bx.w;
      cd.key = ok ? key : 0u; cd.lvl = (unsigned)l; cd.pad0 = 0; cd.pad1 = 0;
      cb[slot] = cd;
    }
    __syncthreads();
    if (threadIdx.x == 0) { s_runeq = runeq + eqTot; s_runout = runout + selTot; }
    __syncthreads();
  }
}

// ============================ single-block bitonic sort (desc key, asc slot) ============================
template <int NPAD>
__global__ __launch_bounds__(1024) void sort_desc_kernel(
    const unsigned* __restrict__ keyBase, int strideWords, int nFixed,
    const unsigned* __restrict__ nPtr, unsigned* __restrict__ sortedSlot,
    unsigned* __restrict__ validCnt, int imgStrideKeyWords, int imgStrideSlot) {
  __shared__ unsigned sk[NPAD];
  __shared__ unsigned short sslot[NPAD];
  __shared__ unsigned s_cnt;
  int b = blockIdx.x;
  const unsigned* kbase = keyBase + (size_t)b * imgStrideKeyWords;
  unsigned* oslot = sortedSlot + (size_t)b * imgStrideSlot;
  unsigned* ocnt = validCnt + b;
  int n = nFixed;
  if (nPtr) { int m = (int)nPtr[b]; n = n < m ? n : m; }
  for (int i = threadIdx.x; i < NPAD; i += 1024) {
    sk[i] = (i < n) ? kbase[(size_t)i * strideWords] : 0u;
    sslot[i] = (unsigned short)i;
  }
  if (threadIdx.x == 0) s_cnt = 0;
  __syncthreads();
  for (int k2 = 2; k2 <= NPAD; k2 <<= 1) {
    for (int j = k2 >> 1; j > 0; j >>= 1) {
      for (int i = threadIdx.x; i < NPAD; i += 1024) {
        int ixj = i ^ j;
        if (ixj > i) {
          unsigned ka = sk[i], kb2 = sk[ixj];
          unsigned short sa = sslot[i], sb = sslot[ixj];
          bool aGreater = (ka > kb2) || (ka == kb2 && sa < sb);
          bool up = ((i & k2) == 0);
          bool doSwap = up ? (!aGreater) : aGreater;
          if (doSwap) { sk[i] = kb2; sk[ixj] = ka; sslot[i] = sb; sslot[ixj] = sa; }
        }
      }
      __syncthreads();
    }
  }
  unsigned local = 0;
  for (int i = threadIdx.x; i < NPAD; i += 1024) {
    oslot[i] = (unsigned)sslot[i];
    if (sk[i] > 0u) local++;
  }
  atomicAdd(&s_cnt, local);
  __syncthreads();
  if (threadIdx.x == 0) *ocnt = s_cnt;
}

// ============================ RPN greedy NMS (sorted forward suppression) ============================
__global__ __launch_bounds__(1024) void rpn_nms_kernel(
    const Cand* __restrict__ cand, const unsigned* __restrict__ sortedSlot,
    const unsigned* __restrict__ validCnt, float* __restrict__ rois, unsigned* __restrict__ Mout) {
  int b = blockIdx.x;
  const Cand* cb = cand + (size_t)b * kNCand;
  const unsigned* ss = sortedSlot + (size_t)b * 8192;
  int valid = (int)validCnt[b];
  float* rb = rois + (size_t)b * kPostNms * 4;
  __shared__ unsigned char flag[8192];
  __shared__ int s_next, s_kept, s_i, s_lvl;
  __shared__ float4 s_box;
  for (int i = threadIdx.x; i < 8192; i += 1024) flag[i] = 0;
  if (threadIdx.x == 0) { s_kept = 0; s_i = 0; }
  __syncthreads();
  while (true) {
    if (threadIdx.x == 0) {
      int nxt = -1;
      if (s_kept < kPostNms) {
        int i = s_i;
        while (i < valid && flag[i]) i++;
        if (i < valid) { nxt = i; s_i = i + 1; }
      }
      if (nxt >= 0) {
        Cand c = cb[ss[nxt]];
        s_box = make_float4(c.x1, c.y1, c.x2, c.y2);
        s_lvl = (int)c.lvl;
        rb[s_kept * 4 + 0] = c.x1; rb[s_kept * 4 + 1] = c.y1;
        rb[s_kept * 4 + 2] = c.x2; rb[s_kept * 4 + 3] = c.y2;
        s_kept++;
      }
      s_next = nxt;
    }
    __syncthreads();
    int nxt = s_next;
    if (nxt < 0) break;
    float4 box = s_box;
    int lv = s_lvl;
    for (int j = nxt + 1 + (int)threadIdx.x; j < valid; j += 1024) {
      if (!flag[j]) {
        Cand c = cb[ss[j]];
        if ((int)c.lvl == lv) {
          if (iou_pair(box, make_float4(c.x1, c.y1, c.x2, c.y2)) > 0.7f) flag[j] = 1;
        }
      }
    }
    __syncthreads();
  }
  if (threadIdx.x == 0) Mout[b] = (unsigned)s_kept;
}

// ============================ ROI params (level map + scaled coords) ============================
__global__ __launch_bounds__(256) void roi_params_kernel(
    const float* __restrict__ rois, const unsigned* __restrict__ Mc, RoiParam* __restrict__ par) {
  int b = blockIdx.y;
  int i = blockIdx.x * 256 + threadIdx.x;
  if (i >= (int)Mc[b]) return;
  const float* r = rois + ((size_t)b * kPostNms + i) * 4;
  float x1 = r[0], y1 = r[1], x2 = r[2], y2 = r[3];
  float area = (x2 - x1) * (y2 - y1);
  float tgt = floorf(4.0f + log2f(sqrtf(fmaxf(area, 0.f)) / 224.0f + 1e-6f));
  tgt = fminf(fmaxf(tgt, 2.f), 5.f);
  int l = (int)tgt - 2;
  const float scales[4] = {0.25f, 0.125f, 0.0625f, 0.03125f};
  float sc = scales[l];
  RoiParam p;
  p.lvl = l;
  p.x1 = x1 * sc; p.y1 = y1 * sc;
  p.rw = fmaxf(x2 * sc - p.x1, 1.0f);
  p.rh = fmaxf(y2 * sc - p.y1, 1.0f);
  p.pad0 = p.pad1 = p.pad2 = 0;
  par[(size_t)b * kPostNms + i] = p;
}

// ============================ multi-scale ROI align ============================
__global__ __launch_bounds__(256) void roi_align_kernel(
    const float* __restrict__ f0, const float* __restrict__ f1,
    const float* __restrict__ f2, const float* __restrict__ f3,
    const RoiParam* __restrict__ par, const unsigned* __restrict__ Mc,
    float* __restrict__ pooled, int b) {
  int idx = blockIdx.x * 256 + threadIdx.x;
  int roi = idx / 6272;
  if (roi >= (int)Mc[b]) return;
  int rem = idx - roi * 6272;
  int c = rem / 49, bin = rem - c * 49;
  int py = bin / 7, px = bin - py * 7;
  RoiParam p = par[roi];
  int H = c_LH[p.lvl], W = c_LW[p.lvl];
  const float* f = (p.lvl == 0 ? f0 : p.lvl == 1 ? f1 : p.lvl == 2 ? f2 : f3);
  f += ((size_t)b * 128 + c) * (size_t)(H * W);
  float Hf = (float)H, Wf = (float)W;
  float rh7 = p.rh / 7.0f, rw7 = p.rw / 7.0f;
  float sum = 0.f;
#pragma unroll
  for (int sy = 0; sy < 2; sy++) {
    float offy = (float)py + ((float)sy + 0.5f) * 0.5f;
    float Y = p.y1 + offy * rh7;
    float yc = fminf(fmaxf(Y, 0.f), Hf - 1.f);
    float y0f = floorf(yc);
    int y0 = (int)y0f;
    int y1 = min(y0 + 1, H - 1);
    float ly = yc - y0f, hy = 1.f - ly;
#pragma unroll
    for (int sx = 0; sx < 2; sx++) {
      float offx = (float)px + ((float)sx + 0.5f) * 0.5f;
      float X = p.x1 + offx * rw7;
      bool valid = (Y > -1.f) && (Y < Hf) && (X > -1.f) && (X < Wf);
      float xc = fminf(fmaxf(X, 0.f), Wf - 1.f);
      float x0f = floorf(xc);
      int x0 = (int)x0f;
      int x1i = min(x0 + 1, W - 1);
      float lx = xc - x0f, hx = 1.f - lx;
      float v = hy * hx * f[y0 * W + x0] + hy * lx * f[y0 * W + x1i] +
                ly * hx * f[y1 * W + x0] + ly * lx * f[y1 * W + x1i];
      sum += valid ? v : 0.f;
    }
  }
  pooled[idx] = sum * 0.25f;
}

// ============================ tiled fp32 GEMM: C[m][n] = relu(sum_k A[m][k]*B[n][k] + bias[n]) ============================
__global__ __launch_bounds__(256) void gemm_bias_relu(
    const float* __restrict__ A, const float* __restrict__ B, const float* __restrict__ bias,
    float* __restrict__ C, int K, int N, const unsigned* __restrict__ Mc) {
  int M = (int)*Mc;
  int bm = blockIdx.y;
  if (bm * 64 >= M) return;
  int bn = blockIdx.x;
  __shared__ float As[32][68], Bs[32][68];
  float acc[4][4];
#pragma unroll
  for (int i = 0; i < 4; i++)
#pragma unroll
    for (int j = 0; j < 4; j++) acc[i][j] = 0.f;
  int tx = threadIdx.x & 15, ty = threadIdx.x >> 4;
  for (int k0 = 0; k0 < K; k0 += 32) {
    for (int e = threadIdx.x; e < 512; e += 256) {
      int m = e >> 3, kk = (e & 7) << 2;
      int gm = bm * 64 + m;
      float4 v = make_float4(0.f, 0.f, 0.f, 0.f);
      if (gm < M) v = *(const float4*)(A + (size_t)gm * K + k0 + kk);
      As[kk + 0][m] = v.x; As[kk + 1][m] = v.y; As[kk + 2][m] = v.z; As[kk + 3][m] = v.w;
      int gn = bn * 64 + m;
      float4 u = *(const float4*)(B + (size_t)gn * K + k0 + kk);
      Bs[kk + 0][m] = u.x; Bs[kk + 1][m] = u.y; Bs[kk + 2][m] = u.z; Bs[kk + 3][m] = u.w;
    }
    __syncthreads();
#pragma unroll
    for (int kk = 0; kk < 32; kk++) {
      float4 av = *(const float4*)(&As[kk][ty * 4]);
      float4 bv = *(const float4*)(&Bs[kk][tx * 4]);
      acc[0][0] = fmaf(av.x, bv.x, acc[0][0]); acc[0][1] = fmaf(av.x, bv.y, acc[0][1]);
      acc[0][2] = fmaf(av.x, bv.z, acc[0][2]); acc[0][3] = fmaf(av.x, bv.w, acc[0][3]);
      acc[1][0] = fmaf(av.y, bv.x, acc[1][0]); acc[1][1] = fmaf(av.y, bv.y, acc[1][1]);
      acc[1][2] = fmaf(av.y, bv.z, acc[1][2]); acc[1][3] = fmaf(av.y, bv.w, acc[1][3]);
      acc[2][0] = fmaf(av.z, bv.x, acc[2][0]); acc[2][1] = fmaf(av.z, bv.y, acc[2][1]);
      acc[2][2] = fmaf(av.z, bv.z, acc[2][2]); acc[2][3] = fmaf(av.z, bv.w, acc[2][3]);
      acc[3][0] = fmaf(av.w, bv.x, acc[3][0]); acc[3][1] = fmaf(av.w, bv.y, acc[3][1]);
      acc[3][2] = fmaf(av.w, bv.z, acc[3][2]); acc[3][3] = fmaf(av.w, bv.w, acc[3][3]);
    }
    __syncthreads();
  }
#pragma unroll
  for (int i = 0; i < 4; i++) {
    int gm = bm * 64 + ty * 4 + i;
    if (gm < M) {
#pragma unroll
      for (int j = 0; j < 4; j++) {
        int gn = bn * 64 + tx * 4 + j;
        C[(size_t)gm * N + gn] = fmaxf(acc[i][j] + bias[gn], 0.f);
      }
    }
  }
}

// ============================ head linear (cls 2 + bbox 8 per roi) ============================
__global__ __launch_bounds__(64) void head_linear_kernel(
    const float* __restrict__ H2, const float* __restrict__ cw, const float* __restrict__ cb2,
    const float* __restrict__ bw, const float* __restrict__ bb2,
    const unsigned* __restrict__ Mc, float* __restrict__ out10) {
  int r = blockIdx.x;
  if (r >= (int)*Mc) return;
  __shared__ float x[1024];
  const float* h = H2 + (size_t)r * 1024;
  for (int i = threadIdx.x; i < 1024; i += 64) x[i] = h[i];
  __syncthreads();
  int t = threadIdx.x;
  if (t < 10) {
    const float* w = (t < 2) ? (cw + t * 1024) : (bw + (t - 2) * 1024);
    float bias = (t < 2) ? cb2[t] : bb2[t - 2];
    float dot = 0.f;
    for (int k = 0; k < 1024; k++) dot = fmaf(w[k], x[k], dot);
    out10[r * 10 + t] = dot + bias;
  }
}

// ============================ head decode (softmax + box decode + filter) ============================
__global__ __launch_bounds__(256) void head_decode_kernel(
    const float* __restrict__ out10, const float* __restrict__ rois,
    const unsigned* __restrict__ Mc, HeadCand* __restrict__ hc, int b) {
#pragma clang fp contract(off)
  int r = blockIdx.x * 256 + threadIdx.x;
  if (r >= (int)Mc[b]) return;
  const float* h = out10 + (size_t)r * 10;
  float l0 = h[0], l1 = h[1];
  float mx = fmaxf(l0, l1);
  float e0 = expf(l0 - mx), e1 = expf(l1 - mx);
  float sfg = e1 / (e0 + e1);
  const float* rr = rois + ((size_t)b * kPostNms + r) * 4;
  float4 bx = decode_clip(rr[0], rr[1], rr[2], rr[3], h[6], h[7], h[8], h[9],
                          10.f, 10.f, 5.f, 5.f);
  bool keep = (sfg > 0.05f) && (bx.z - bx.x >= 0.01f) && (bx.w - bx.y >= 0.01f);
  HeadCand c;
  c.x1 = bx.x; c.y1 = bx.y; c.x2 = bx.z; c.y2 = bx.w;
  c.score = sfg;
  c.key = keep ? keyOf(sfg) : 0u;
  c.pad0 = c.pad1 = 0;
  hc[r] = c;
}

// ============================ head greedy NMS ============================
__global__ __launch_bounds__(1024) void head_nms_kernel(
    const HeadCand* __restrict__ hc, const unsigned* __restrict__ sortedSlot,
    const unsigned* __restrict__ validCnt, float* __restrict__ detBox,
    float* __restrict__ detSc, unsigned* __restrict__ detCnt) {
  int valid = (int)*validCnt;
  __shared__ unsigned char flag[2048];
  __shared__ int s_next, s_kept, s_i;
  __shared__ float4 s_box;
  for (int i = threadIdx.x; i < 2048; i += 1024) flag[i] = 0;
  if (threadIdx.x == 0) { s_kept = 0; s_i = 0; }
  __syncthreads();
  while (true) {
    if (threadIdx.x == 0) {
      int nxt = -1;
      if (s_kept < 100) {
        int i = s_i;
        while (i < valid && flag[i]) i++;
        if (i < valid) { nxt = i; s_i = i + 1; }
      }
      if (nxt >= 0) {
        HeadCand c = hc[sortedSlot[nxt]];
        s_box = make_float4(c.x1, c.y1, c.x2, c.y2);
        detBox[s_kept * 4 + 0] = c.x1; detBox[s_kept * 4 + 1] = c.y1;
        detBox[s_kept * 4 + 2] = c.x2; detBox[s_kept * 4 + 3] = c.y2;
        detSc[s_kept] = c.score;
        s_kept++;
      }
      s_next = nxt;
    }
    __syncthreads();
    int nxt = s_next;
    if (nxt < 0) break;
    float4 box = s_box;
    for (int j = nxt + 1 + (int)threadIdx.x; j < valid; j += 1024) {
      if (!flag[j]) {
        HeadCand c = hc[sortedSlot[j]];
        if (iou_pair(box, make_float4(c.x1, c.y1, c.x2, c.y2)) > 0.5f) flag[j] = 1;
      }
    }
    __syncthreads();
  }
  if (threadIdx.x == 0) *detCnt = (unsigned)s_kept;
}

// ============================ final output ============================
__global__ __launch_bounds__(256) void output_kernel(
    const float* __restrict__ detBox, const float* __restrict__ detSc,
    const unsigned* __restrict__ detCnt, float* __restrict__ out) {
  int t = threadIdx.x;
  if (t >= 200) return;
  int b = t / 100, q = t - b * 100;
  int cnt = (int)detCnt[b];
  float bx0 = 0.f, bx1 = 0.f, bx2 = 0.f, bx3 = 0.f, sc = 0.f, lb = 0.f;
  if (q < cnt) {
    const float* d = detBox + ((size_t)b * 100 + q) * 4;
    bx0 = d[0]; bx1 = d[1]; bx2 = d[2]; bx3 = d[3];
    sc = detSc[b * 100 + q];
    lb = 1.0f;
  }
  float* ob = out + ((size_t)b * 100 + q) * 4;
  ob[0] = bx0; ob[1] = bx1; ob[2] = bx2; ob[3] = bx3;
  out[800 + t] = sc;
  out[1000 + t] = lb;
}

// ============================ host launcher ============================
extern "C" void kernel_launch(void* const* d_in, const int* in_sizes, int n_in,
                              void* d_out, int out_size, void* d_ws, size_t ws_size,
                              hipStream_t stream) {
  (void)in_sizes; (void)n_in; (void)out_size; (void)ws_size;
  const float* feats[4] = {(const float*)d_in[0], (const float*)d_in[1],
                           (const float*)d_in[2], (const float*)d_in[3]};
  const float* w3 = (const float*)d_in[4];
  const float* b3 = (const float*)d_in[5];
  const float* wc = (const float*)d_in[6];
  const float* bcs = (const float*)d_in[7];
  const float* wb = (const float*)d_in[8];
  const float* bbx = (const float*)d_in[9];
  const float* fc6w = (const float*)d_in[10];
  const float* fc6b = (const float*)d_in[11];
  const float* fc7w = (const float*)d_in[12];
  const float* fc7b = (const float*)d_in[13];
  const float* clsw = (const float*)d_in[14];
  const float* clsb = (const float*)d_in[15];
  const float* bboxw = (const float*)d_in[16];
  const float* bboxb = (const float*)d_in[17];

  unsigned char* base = (unsigned char*)d_ws;
  size_t off = 0;
  auto alloc = [&](size_t bytes) -> void* {
    void* p = base + off;
    off += (bytes + 255) & ~(size_t)255;
    return p;
  };
  unsigned* keys = (unsigned*)alloc((size_t)2 * kAImg * 4);
  float* deltas = (float*)alloc((size_t)2 * kAImg * 16);
  unsigned* tkT = (unsigned*)alloc(32);
  unsigned* tkNeed = (unsigned*)alloc(32);
  Cand* cand = (Cand*)alloc((size_t)2 * kNCand * sizeof(Cand));
  unsigned* sortedSlot = (unsigned*)alloc((size_t)2 * 8192 * 4);
  unsigned* validCnt = (unsigned*)alloc(8);
  float* rois = (float*)alloc((size_t)2 * kPostNms * 16);
  unsigned* Mc = (unsigned*)alloc(8);
  RoiParam* roiPar = (RoiParam*)alloc((size_t)2 * kPostNms * sizeof(RoiParam));
  float* pooled = (float*)alloc((size_t)kPostNms * 6272 * 4);
  float* H1 = (float*)alloc((size_t)kPostNms * 1024 * 4);
  float* H2buf = (float*)alloc((size_t)kPostNms * 1024 * 4);
  float* out10 = (float*)alloc((size_t)kPostNms * 10 * 4);
  HeadCand* hc = (HeadCand*)alloc((size_t)kPostNms * sizeof(HeadCand));
  unsigned* hsorted = (unsigned*)alloc((size_t)2048 * 4);
  unsigned* hvalid = (unsigned*)alloc(4);
  float* detBox = (float*)alloc((size_t)2 * 100 * 4 * 4);
  float* detSc = (float*)alloc((size_t)2 * 100 * 4);
  unsigned* detCnt = (unsigned*)alloc(8);

  // anchor base table, double precision, round-half-even (matches np.round)
  AnchTab tab;
  {
    const double aspects[3] = {0.5, 1.0, 2.0};
    const int sizes[4] = {32, 64, 128, 256};
    for (int l = 0; l < 4; l++)
      for (int a = 0; a < 3; a++) {
        double hr = sqrt(aspects[a]);
        double wr = 1.0 / hr;
        double wsz = wr * sizes[l], hsz = hr * sizes[l];
        tab.v[l][a][0] = (float)rint(-wsz / 2.0);
        tab.v[l][a][1] = (float)rint(-hsz / 2.0);
        tab.v[l][a][2] = (float)rint(wsz / 2.0);
        tab.v[l][a][3] = (float)rint(hsz / 2.0);
      }
  }

  const int LH[4] = {200, 100, 50, 25}, LW[4] = {200, 100, 50, 25};
  const int AOFF[4] = {0, 120000, 150000, 157500};

  for (int b = 0; b < 2; b++) {
    for (int l = 0; l < 4; l++) {
      int H = LH[l], W = LW[l];
      dim3 grid((W + 15) / 16, H);
      rpn_conv_kernel<<<grid, 256, 0, stream>>>(
          feats[l] + (size_t)b * 128 * H * W, H, W, w3, b3, wc, bcs, wb, bbx,
          keys + (size_t)b * kAImg, deltas + (size_t)b * kAImg * 4, AOFF[l]);
    }
  }
  radix_select_kernel<<<6, 1024, 0, stream>>>(keys, tkT, tkNeed);
  cand_build_kernel<<<8, 1024, 0, stream>>>(keys, deltas, tkT, tkNeed, cand, tab);
  sort_desc_kernel<8192><<<2, 1024, 0, stream>>>(
      ((const unsigned*)cand) + 4, 8, kNCand, nullptr, sortedSlot, validCnt, kNCand * 8, 8192);
  rpn_nms_kernel<<<2, 1024, 0, stream>>>(cand, sortedSlot, validCnt, rois, Mc);
  roi_params_kernel<<<dim3(8, 2), 256, 0, stream>>>(rois, Mc, roiPar);

  for (int b = 0; b < 2; b++) {
    roi_align_kernel<<<49000, 256, 0, stream>>>(
        feats[0], feats[1], feats[2], feats[3], roiPar + (size_t)b * kPostNms, Mc, pooled, b);
    gemm_bias_relu<<<dim3(16, 32), 256, 0, stream>>>(pooled, fc6w, fc6b, H1, 6272, 1024, Mc + b);
    gemm_bias_relu<<<dim3(16, 32), 256, 0, stream>>>(H1, fc7w, fc7b, H2buf, 1024, 1024, Mc + b);
    head_linear_kernel<<<2000, 64, 0, stream>>>(H2buf, clsw, clsb, bboxw, bboxb, Mc + b, out10);
    head_decode_kernel<<<8, 256, 0, stream>>>(out10, rois, Mc, hc, b);
    sort_desc_kernel<2048><<<1, 1024, 0, stream>>>(
        ((const unsigned*)hc) + 5, 8, 2000, Mc + b, hsorted, hvalid, 0, 0);
    head_nms_kernel<<<1, 1024, 0, stream>>>(
        hc, hsorted, hvalid, detBox + (size_t)b * 400, detSc + (size_t)b * 100, detCnt + b);
  }
  output_kernel<<<1, 256, 0, stream>>>(detBox, detSc, detCnt, (float*)d_out);
}

// Round 3
// 4131.501 us; speedup vs baseline: 2.8308x; 2.8308x over previous
//
#include <hip/hip_runtime.h>
#include <cmath>

// ============================ constants ============================
static constexpr int kAImg = 159375;   // anchors per image
static constexpr int kNCand = 7875;    // 2000+2000+2000+1875
static constexpr int kPostNms = 2000;

__constant__ int c_AOFF[4]   = {0, 120000, 150000, 157500};
__constant__ int c_ALVL[4]   = {120000, 30000, 7500, 1875};
__constant__ int c_CBASE[4]  = {0, 2000, 4000, 6000};
__constant__ int c_LW[4]     = {200, 100, 50, 25};
__constant__ int c_LH[4]     = {200, 100, 50, 25};
__constant__ int c_STRIDE[4] = {4, 8, 16, 32};

struct Cand     { float x1, y1, x2, y2; unsigned key; unsigned lvl; unsigned pad0, pad1; };
struct HeadCand { float x1, y1, x2, y2; float score; unsigned key; unsigned pad0, pad1; };
struct RoiParam { int lvl; float x1, y1, rw, rh; int pad0, pad1, pad2; };
struct AnchTab  { float v[4][3][4]; };

// ============================ device helpers ============================
__device__ __forceinline__ unsigned keyOf(float f) {
  unsigned u = __float_as_uint(f);
  return (u & 0x80000000u) ? ~u : (u | 0x80000000u);
}

__device__ __forceinline__ unsigned long long shfl64(unsigned long long v, int src) {
  int lo = __shfl((int)(unsigned)(v & 0xffffffffull), src);
  int hi = __shfl((int)(unsigned)(v >> 32), src);
  return ((unsigned long long)(unsigned)hi << 32) | (unsigned)lo;
}

__device__ __forceinline__ float iou_pair(float4 a, float4 b) {
#pragma clang fp contract(off)
  float ix1 = fmaxf(a.x, b.x), iy1 = fmaxf(a.y, b.y);
  float ix2 = fminf(a.z, b.z), iy2 = fminf(a.w, b.w);
  float iw = fmaxf(ix2 - ix1, 0.f), ih = fmaxf(iy2 - iy1, 0.f);
  float inter = iw * ih;
  float a1 = (a.z - a.x) * (a.w - a.y);
  float a2 = (b.z - b.x) * (b.w - b.y);
  float uni = a1 + a2 - inter;
  return uni > 0.f ? inter / uni : 0.f;
}

__device__ __forceinline__ float4 decode_clip(float bx1, float by1, float bx2, float by2,
                                              float d0, float d1, float d2, float d3,
                                              float wx, float wy, float ww, float wh) {
#pragma clang fp contract(off)
  float w = bx2 - bx1, h = by2 - by1;
  float cx = bx1 + 0.5f * w, cy = by1 + 0.5f * h;
  float dx = d0 / wx, dy = d1 / wy;
  float dw = fminf(d2 / ww, 4.135166556742356f);
  float dh = fminf(d3 / wh, 4.135166556742356f);
  float pcx = dx * w + cx, pcy = dy * h + cy;
  float pw = expf(dw) * w, ph = expf(dh) * h;
  float x1 = pcx - 0.5f * pw, y1 = pcy - 0.5f * ph;
  float x2 = pcx + 0.5f * pw, y2 = pcy + 0.5f * ph;
  x1 = fminf(fmaxf(x1, 0.f), 800.f); y1 = fminf(fmaxf(y1, 0.f), 800.f);
  x2 = fminf(fmaxf(x2, 0.f), 800.f); y2 = fminf(fmaxf(y2, 0.f), 800.f);
  return make_float4(x1, y1, x2, y2);
}

// block-wide exclusive scan of a bool over 1024 threads (16 waves)
__device__ __forceinline__ unsigned block_scan_bool(bool p, unsigned* wbuf, unsigned& total) {
  unsigned long long m = __ballot(p);
  int lane = threadIdx.x & 63;
  int wid = threadIdx.x >> 6;
  unsigned exc = (unsigned)__popcll(m & ((lane == 0) ? 0ull : ((~0ull) >> (64 - lane))));
  if (lane == 0) wbuf[wid] = (unsigned)__popcll(m);
  __syncthreads();
  unsigned pre = 0, tot = 0;
#pragma unroll
  for (int w = 0; w < 16; w++) { unsigned c = wbuf[w]; if (w < wid) pre += c; tot += c; }
  total = tot;
  __syncthreads();
  return pre + exc;
}

// ============================ RPN conv (3x3+relu fused with 1x1 heads) ============================
__global__ __launch_bounds__(256) void rpn_conv_kernel(
    const float* __restrict__ feat, int H, int W,
    const float* __restrict__ w3, const float* __restrict__ b3,
    const float* __restrict__ wc, const float* __restrict__ bcs,
    const float* __restrict__ wb, const float* __restrict__ bbx,
    unsigned* __restrict__ keys, float* __restrict__ deltas, int aoff) {
  __shared__ float Wl[128 * 73];
  __shared__ float patch[8][3][20];
  __shared__ float tt[16][129];
  int tid = threadIdx.x;
  int co = tid & 127, half = tid >> 7;
  int x0 = blockIdx.x * 16;
  int y = blockIdx.y;
  float acc[8];
#pragma unroll
  for (int j = 0; j < 8; j++) acc[j] = 0.f;

  for (int ci0 = 0; ci0 < 128; ci0 += 8) {
    for (int e = tid; e < 128 * 72; e += 256) {
      int r = e / 72, q = e - r * 72;
      Wl[r * 73 + q] = w3[r * 1152 + ci0 * 9 + q];
    }
    for (int e = tid; e < 8 * 54; e += 256) {
      int ci = e / 54, q = e - ci * 54;
      int dy = q / 18, dx = q - dy * 18;
      int gy = y + dy - 1, gx = x0 + dx - 1;
      float v = 0.f;
      if (gy >= 0 && gy < H && gx >= 0 && gx < W)
        v = feat[(size_t)(ci0 + ci) * H * W + gy * W + gx];
      patch[ci][dy][dx] = v;
    }
    __syncthreads();
    for (int ci = 0; ci < 8; ci++) {
#pragma unroll
      for (int ky = 0; ky < 3; ky++) {
        float row[10];
#pragma unroll
        for (int d = 0; d < 10; d++) row[d] = patch[ci][ky][half * 8 + d];
#pragma unroll
        for (int kx = 0; kx < 3; kx++) {
          float wv = Wl[co * 73 + ci * 9 + ky * 3 + kx];
#pragma unroll
          for (int j = 0; j < 8; j++) acc[j] = fmaf(wv, row[j + kx], acc[j]);
        }
      }
    }
    __syncthreads();
  }
  float bias3 = b3[co];
#pragma unroll
  for (int j = 0; j < 8; j++) tt[half * 8 + j][co] = fmaxf(acc[j] + bias3, 0.f);
  __syncthreads();
  if (tid < 240) {
    int oc = tid / 16, p = tid - (tid / 16) * 16;
    int x = x0 + p;
    if (x < W) {
      const float* wrow = (oc < 3) ? (wc + oc * 128) : (wb + (oc - 3) * 128);
      float bias = (oc < 3) ? bcs[oc] : bbx[oc - 3];
      float dot = 0.f;
      for (int k = 0; k < 128; k++) dot = fmaf(wrow[k], tt[p][k], dot);
      float s = dot + bias;
      int pos = y * W + x;
      if (oc < 3) {
        keys[aoff + pos * 3 + oc] = keyOf(s);
      } else {
        int bc = oc - 3, a = bc >> 2, comp = bc & 3;
        deltas[(size_t)(aoff + pos * 3 + a) * 4 + comp] = s;
      }
    }
  }
}

// ============================ radix select per (image,level 0..2) ============================
__global__ __launch_bounds__(1024) void radix_select_kernel(
    const unsigned* __restrict__ keys, unsigned* __restrict__ tkT, unsigned* __restrict__ tkNeed) {
  int job = blockIdx.x;
  int b = job / 3, l = job - b * 3;
  const unsigned* kb = keys + (size_t)b * kAImg + c_AOFF[l];
  int n = c_ALVL[l];
  __shared__ unsigned hist[256];
  __shared__ unsigned s_sel, s_remk;
  unsigned prefix = 0, pmask = 0, remk = 2000;
  for (int shift = 24; shift >= 0; shift -= 8) {
    if (threadIdx.x < 256) hist[threadIdx.x] = 0;
    __syncthreads();
    for (int i = threadIdx.x; i < n; i += 1024) {
      unsigned key = kb[i];
      if ((key & pmask) == prefix) atomicAdd(&hist[(key >> shift) & 255u], 1u);
    }
    __syncthreads();
    if (threadIdx.x == 0) {
      unsigned cum = 0; int sel = 0;
      for (int d = 255; d >= 0; d--) {
        unsigned c = hist[d];
        if (cum + c >= remk) { sel = d; break; }
        cum += c;
      }
      s_sel = (unsigned)sel; s_remk = remk - cum;
    }
    __syncthreads();
    prefix |= (s_sel << shift);
    pmask |= (255u << shift);
    remk = s_remk;
    __syncthreads();
  }
  if (threadIdx.x == 0) { tkT[b * 4 + l] = prefix; tkNeed[b * 4 + l] = remk; }
}

// ============================ candidate build ============================
__global__ __launch_bounds__(1024) void cand_build_kernel(
    const unsigned* __restrict__ keys, const float* __restrict__ deltas,
    const unsigned* __restrict__ tkT, const unsigned* __restrict__ tkNeed,
    Cand* __restrict__ cand, AnchTab tab) {
  int b = blockIdx.x >> 2, l = blockIdx.x & 3;
  int n = c_ALVL[l];
  int W = c_LW[l];
  int stride = c_STRIDE[l];
  const unsigned* kb = keys + (size_t)b * kAImg + c_AOFF[l];
  const float* db = deltas + ((size_t)b * kAImg + c_AOFF[l]) * 4;
  Cand* cb = cand + (size_t)b * kNCand + c_CBASE[l];
  bool selAll = (l == 3);
  unsigned T = selAll ? 0u : tkT[b * 4 + l];
  unsigned need = selAll ? 0u : tkNeed[b * 4 + l];
  __shared__ unsigned wbuf[16];
  __shared__ unsigned s_runeq, s_runout;
  if (threadIdx.x == 0) { s_runeq = 0; s_runout = 0; }
  __syncthreads();
  for (int c0 = 0; c0 < n; c0 += 1024) {
    int i = c0 + (int)threadIdx.x;
    bool act = i < n;
    unsigned key = act ? kb[i] : 0u;
    bool isEq = (!selAll) && act && (key == T);
    unsigned eqTot;
    unsigned eqExc = block_scan_bool(isEq, wbuf, eqTot);
    unsigned runeq = s_runeq;
    unsigned runout = s_runout;
    bool isSel = act && (selAll || key > T || (isEq && (runeq + eqExc) < need));
    unsigned selTot;
    unsigned selExc = block_scan_bool(isSel, wbuf, selTot);
    if (isSel) {
      int slot = (int)(runout + selExc);
      int pos = i / 3, a = i - pos * 3;
      int yy = pos / W, xx = pos - yy * W;
      float sx = (float)(xx * stride), sy = (float)(yy * stride);
      float ax1 = tab.v[l][a][0] + sx;
      float ay1 = tab.v[l][a][1] + sy;
      float ax2 = tab.v[l][a][2] + sx;
      float ay2 = tab.v[l][a][3] + sy;
      float d0 = db[(size_t)i * 4 + 0], d1 = db[(size_t)i * 4 + 1];
      float d2 = db[(size_t)i * 4 + 2], d3 = db[(size_t)i * 4 + 3];
      float4 bx = decode_clip(ax1, ay1, ax2, ay2, d0, d1, d2, d3, 1.f, 1.f, 1.f, 1.f);
      bool ok = (bx.z - bx.x >= 0.001f) && (bx.w - bx.y >= 0.001f);
      Cand cd;
      cd.x1 = bx.x; cd.y1 = bx.y; cd.x2 = bx.z; cd.y2 = bx.w;
      cd.key = ok ? key : 0u; cd.lvl = (unsigned)l; cd.pad0 = 0; cd.pad1 = 0;
      cb[slot] = cd;
    }
    __syncthreads();
    if (threadIdx.x == 0) { s_runeq = runeq + eqTot; s_runout = runout + selTot; }
    __syncthreads();
  }
}

// ============================ single-block bitonic sort (desc key, asc slot) ============================
template <int NPAD>
__global__ __launch_bounds__(1024) void sort_desc_kernel(
    const unsigned* __restrict__ keyBase, int strideWords, int nFixed,
    const unsigned* __restrict__ nPtr, unsigned* __restrict__ sortedSlot,
    unsigned* __restrict__ validCnt, int imgStrideKeyWords, int imgStrideSlot) {
  __shared__ unsigned sk[NPAD];
  __shared__ unsigned short sslot[NPAD];
  __shared__ unsigned s_cnt;
  int b = blockIdx.x;
  const unsigned* kbase = keyBase + (size_t)b * imgStrideKeyWords;
  unsigned* oslot = sortedSlot + (size_t)b * imgStrideSlot;
  unsigned* ocnt = validCnt + b;
  int n = nFixed;
  if (nPtr) { int m = (int)nPtr[b]; n = n < m ? n : m; }
  for (int i = threadIdx.x; i < NPAD; i += 1024) {
    sk[i] = (i < n) ? kbase[(size_t)i * strideWords] : 0u;
    sslot[i] = (unsigned short)i;
  }
  if (threadIdx.x == 0) s_cnt = 0;
  __syncthreads();
  for (int k2 = 2; k2 <= NPAD; k2 <<= 1) {
    for (int j = k2 >> 1; j > 0; j >>= 1) {
      for (int i = threadIdx.x; i < NPAD; i += 1024) {
        int ixj = i ^ j;
        if (ixj > i) {
          unsigned ka = sk[i], kb2 = sk[ixj];
          unsigned short sa = sslot[i], sb = sslot[ixj];
          bool aGreater = (ka > kb2) || (ka == kb2 && sa < sb);
          bool up = ((i & k2) == 0);
          bool doSwap = up ? (!aGreater) : aGreater;
          if (doSwap) { sk[i] = kb2; sk[ixj] = ka; sslot[i] = sb; sslot[ixj] = sa; }
        }
      }
      __syncthreads();
    }
  }
  unsigned local = 0;
  for (int i = threadIdx.x; i < NPAD; i += 1024) {
    oslot[i] = (unsigned)sslot[i];
    if (sk[i] > 0u) local++;
  }
  atomicAdd(&s_cnt, local);
  __syncthreads();
  if (threadIdx.x == 0) *ocnt = s_cnt;
}

// ============================ sorted gather (RPN): offset + raw boxes ============================
__global__ __launch_bounds__(256) void rpn_sort_gather(
    const Cand* __restrict__ cand, const unsigned* __restrict__ ss,
    const unsigned* __restrict__ validCnt, float4* __restrict__ boxOff,
    float4* __restrict__ boxRaw) {
  int b = blockIdx.y;
  int pos = blockIdx.x * 256 + threadIdx.x;
  int valid = (int)validCnt[b];
  float4 raw = make_float4(0.f, 0.f, 0.f, 0.f);
  float4 off4 = raw;
  if (pos < valid) {
#pragma clang fp contract(off)
    Cand c = cand[(size_t)b * kNCand + ss[(size_t)b * 8192 + pos]];
    float off = 801.0f * (float)c.lvl;
    raw = make_float4(c.x1, c.y1, c.x2, c.y2);
    off4 = make_float4(c.x1 + off, c.y1 + off, c.x2 + off, c.y2 + off);
  }
  boxOff[(size_t)b * 8192 + pos] = off4;
  boxRaw[(size_t)b * 8192 + pos] = raw;
}

// ============================ sorted gather (head): boxes + scores ============================
__global__ __launch_bounds__(256) void head_sort_gather(
    const HeadCand* __restrict__ hc, const unsigned* __restrict__ hsorted,
    const unsigned* __restrict__ hvalid, float4* __restrict__ hbox, float* __restrict__ hsc) {
  int pos = blockIdx.x * 256 + threadIdx.x;
  int valid = (int)*hvalid;
  float4 v = make_float4(0.f, 0.f, 0.f, 0.f);
  float s = 0.f;
  if (pos < valid) {
    HeadCand c = hc[hsorted[pos]];
    v = make_float4(c.x1, c.y1, c.x2, c.y2);
    s = c.score;
  }
  hbox[pos] = v;
  hsc[pos] = s;
}

// ============================ NMS suppression-mask build ============================
// grid (rowBlocks, colBlocks, images); 64 threads; each thread computes one u64 mask word.
__global__ __launch_bounds__(64) void nms_mask_kernel(
    const float4* __restrict__ boxesOff, const unsigned* __restrict__ validCnt,
    unsigned long long* __restrict__ mask, int rowStrideWords,
    int imgBoxStride, long long imgMaskStride, float th) {
  int b = blockIdx.z;
  const float4* bx = boxesOff + (size_t)b * imgBoxStride;
  unsigned long long* mrow = mask + (size_t)b * imgMaskStride;
  int valid = (int)validCnt[b];
  int i = blockIdx.x * 64 + threadIdx.x;
  int j0 = blockIdx.y * 64;
  __shared__ float4 sb[64];
  sb[threadIdx.x] = bx[j0 + threadIdx.x];
  __syncthreads();
  float4 a = bx[i];
  unsigned long long bits = 0;
  for (int t = 0; t < 64; t++) {
    int j = j0 + t;
    if (j > i && j < valid && iou_pair(a, sb[t]) > th) bits |= (1ull << t);
  }
  mrow[(size_t)i * rowStrideWords + (j0 >> 6)] = bits;
}

// ============================ NMS reduce (serial scan with register-resident removed mask) ============================
template <int WORDS, int KMAX>
__global__ __launch_bounds__(64) void nms_reduce_kernel(
    const unsigned long long* __restrict__ mask, const unsigned* __restrict__ validCnt,
    unsigned* __restrict__ keptIdx, unsigned* __restrict__ keptCnt,
    long long imgMaskStride) {
  constexpr int WPT = (WORDS + 63) / 64;
  constexpr int C = 8;
  int b = blockIdx.x;
  const unsigned long long* mrow = mask + (size_t)b * imgMaskStride;
  int valid = (int)validCnt[b];
  unsigned* kout = keptIdx + (size_t)b * KMAX;
  int lane = threadIdx.x;
  unsigned long long removed[WPT];
#pragma unroll
  for (int p = 0; p < WPT; p++) removed[p] = 0ull;
  int kept = 0;
  unsigned long long bufA[C][WPT], bufB[C][WPT];

  auto loadc = [&](unsigned long long (&bf)[C][WPT], int cbase) {
#pragma unroll
    for (int t = 0; t < C; t++) {
      int i = cbase + t;
#pragma unroll
      for (int p = 0; p < WPT; p++) {
        int w = lane + 64 * p;
        unsigned long long v = 0ull;
        if (w < WORDS && i < valid) v = mrow[(size_t)i * WORDS + w];
        bf[t][p] = v;
      }
    }
  };

  unsigned long long curw = 0ull;
  int curWidx = -1;

  auto procc = [&](unsigned long long (&bf)[C][WPT], int cbase) {
#pragma unroll
    for (int t = 0; t < C; t++) {
      int i = cbase + t;
      bool act = (i < valid) && (kept < KMAX);
      if (act) {
        int w = i >> 6;
        if (w != curWidx) {
          curWidx = w;
          unsigned long long rv = (WPT > 1 && w >= 64) ? removed[WPT - 1] : removed[0];
          curw = shfl64(rv, w & 63);
        }
        if (!((curw >> (i & 63)) & 1ull)) {
#pragma unroll
          for (int p = 0; p < WPT; p++) removed[p] |= bf[t][p];
          unsigned long long bv = (WPT > 1 && w >= 64) ? bf[t][WPT - 1] : bf[t][0];
          curw |= shfl64(bv, w & 63);
          if (lane == 0) kout[kept] = (unsigned)i;
          kept++;
        }
      }
    }
  };

  loadc(bufA, 0);
  for (int c0 = 0; c0 < valid; c0 += 2 * C) {
    loadc(bufB, c0 + C);
    procc(bufA, c0);
    if (kept >= KMAX) break;
    loadc(bufA, c0 + 2 * C);
    procc(bufB, c0 + C);
    if (kept >= KMAX) break;
  }
  if (threadIdx.x == 0) keptCnt[b] = (unsigned)kept;
}

// ============================ kept-index gathers ============================
__global__ __launch_bounds__(256) void rpn_roi_gather(
    const unsigned* __restrict__ keptIdx, const unsigned* __restrict__ Mc,
    const float4* __restrict__ boxRaw, float* __restrict__ rois) {
  int b = blockIdx.y;
  int k = blockIdx.x * 256 + threadIdx.x;
  if (k >= (int)Mc[b]) return;
  unsigned i = keptIdx[(size_t)b * kPostNms + k];
  float4 v = boxRaw[(size_t)b * 8192 + i];
  float* r = rois + ((size_t)b * kPostNms + k) * 4;
  r[0] = v.x; r[1] = v.y; r[2] = v.z; r[3] = v.w;
}

__global__ __launch_bounds__(128) void head_det_gather(
    const unsigned* __restrict__ keptIdx, const unsigned* __restrict__ cnt,
    const float4* __restrict__ hbox, const float* __restrict__ hsc,
    float* __restrict__ detBox, float* __restrict__ detSc) {
  int k = threadIdx.x;
  if (k >= (int)*cnt || k >= 100) return;
  unsigned i = keptIdx[k];
  float4 v = hbox[i];
  detBox[k * 4 + 0] = v.x; detBox[k * 4 + 1] = v.y;
  detBox[k * 4 + 2] = v.z; detBox[k * 4 + 3] = v.w;
  detSc[k] = hsc[i];
}

// ============================ ROI params ============================
__global__ __launch_bounds__(256) void roi_params_kernel(
    const float* __restrict__ rois, const unsigned* __restrict__ Mc, RoiParam* __restrict__ par) {
  int b = blockIdx.y;
  int i = blockIdx.x * 256 + threadIdx.x;
  if (i >= (int)Mc[b]) return;
  const float* r = rois + ((size_t)b * kPostNms + i) * 4;
  float x1 = r[0], y1 = r[1], x2 = r[2], y2 = r[3];
  float area = (x2 - x1) * (y2 - y1);
  float tgt = floorf(4.0f + log2f(sqrtf(fmaxf(area, 0.f)) / 224.0f + 1e-6f));
  tgt = fminf(fmaxf(tgt, 2.f), 5.f);
  int l = (int)tgt - 2;
  const float scales[4] = {0.25f, 0.125f, 0.0625f, 0.03125f};
  float sc = scales[l];
  RoiParam p;
  p.lvl = l;
  p.x1 = x1 * sc; p.y1 = y1 * sc;
  p.rw = fmaxf(x2 * sc - p.x1, 1.0f);
  p.rh = fmaxf(y2 * sc - p.y1, 1.0f);
  p.pad0 = p.pad1 = p.pad2 = 0;
  par[(size_t)b * kPostNms + i] = p;
}

// ============================ multi-scale ROI align ============================
__global__ __launch_bounds__(256) void roi_align_kernel(
    const float* __restrict__ f0, const float* __restrict__ f1,
    const float* __restrict__ f2, const float* __restrict__ f3,
    const RoiParam* __restrict__ par, const unsigned* __restrict__ Mc,
    float* __restrict__ pooled, int b) {
  int idx = blockIdx.x * 256 + threadIdx.x;
  int roi = idx / 6272;
  if (roi >= (int)Mc[b]) return;
  int rem = idx - roi * 6272;
  int c = rem / 49, bin = rem - c * 49;
  int py = bin / 7, px = bin - py * 7;
  RoiParam p = par[roi];
  int H = c_LH[p.lvl], W = c_LW[p.lvl];
  const float* f = (p.lvl == 0 ? f0 : p.lvl == 1 ? f1 : p.lvl == 2 ? f2 : f3);
  f += ((size_t)b * 128 + c) * (size_t)(H * W);
  float Hf = (float)H, Wf = (float)W;
  float rh7 = p.rh / 7.0f, rw7 = p.rw / 7.0f;
  float sum = 0.f;
#pragma unroll
  for (int sy = 0; sy < 2; sy++) {
    float offy = (float)py + ((float)sy + 0.5f) * 0.5f;
    float Y = p.y1 + offy * rh7;
    float yc = fminf(fmaxf(Y, 0.f), Hf - 1.f);
    float y0f = floorf(yc);
    int y0 = (int)y0f;
    int y1 = min(y0 + 1, H - 1);
    float ly = yc - y0f, hy = 1.f - ly;
#pragma unroll
    for (int sx = 0; sx < 2; sx++) {
      float offx = (float)px + ((float)sx + 0.5f) * 0.5f;
      float X = p.x1 + offx * rw7;
      bool valid = (Y > -1.f) && (Y < Hf) && (X > -1.f) && (X < Wf);
      float xc = fminf(fmaxf(X, 0.f), Wf - 1.f);
      float x0f = floorf(xc);
      int x0 = (int)x0f;
      int x1i = min(x0 + 1, W - 1);
      float lx = xc - x0f, hx = 1.f - lx;
      float v = hy * hx * f[y0 * W + x0] + hy * lx * f[y0 * W + x1i] +
                ly * hx * f[y1 * W + x0] + ly * lx * f[y1 * W + x1i];
      sum += valid ? v : 0.f;
    }
  }
  pooled[idx] = sum * 0.25f;
}

// ============================ tiled fp32 GEMM ============================
__global__ __launch_bounds__(256) void gemm_bias_relu(
    const float* __restrict__ A, const float* __restrict__ B, const float* __restrict__ bias,
    float* __restrict__ C, int K, int N, const unsigned* __restrict__ Mc) {
  int M = (int)*Mc;
  int bm = blockIdx.y;
  if (bm * 64 >= M) return;
  int bn = blockIdx.x;
  __shared__ float As[32][68], Bs[32][68];
  float acc[4][4];
#pragma unroll
  for (int i = 0; i < 4; i++)
#pragma unroll
    for (int j = 0; j < 4; j++) acc[i][j] = 0.f;
  int tx = threadIdx.x & 15, ty = threadIdx.x >> 4;
  for (int k0 = 0; k0 < K; k0 += 32) {
    for (int e = threadIdx.x; e < 512; e += 256) {
      int m = e >> 3, kk = (e & 7) << 2;
      int gm = bm * 64 + m;
      float4 v = make_float4(0.f, 0.f, 0.f, 0.f);
      if (gm < M) v = *(const float4*)(A + (size_t)gm * K + k0 + kk);
      As[kk + 0][m] = v.x; As[kk + 1][m] = v.y; As[kk + 2][m] = v.z; As[kk + 3][m] = v.w;
      int gn = bn * 64 + m;
      float4 u = *(const float4*)(B + (size_t)gn * K + k0 + kk);
      Bs[kk + 0][m] = u.x; Bs[kk + 1][m] = u.y; Bs[kk + 2][m] = u.z; Bs[kk + 3][m] = u.w;
    }
    __syncthreads();
#pragma unroll
    for (int kk = 0; kk < 32; kk++) {
      float4 av = *(const float4*)(&As[kk][ty * 4]);
      float4 bv = *(const float4*)(&Bs[kk][tx * 4]);
      acc[0][0] = fmaf(av.x, bv.x, acc[0][0]); acc[0][1] = fmaf(av.x, bv.y, acc[0][1]);
      acc[0][2] = fmaf(av.x, bv.z, acc[0][2]); acc[0][3] = fmaf(av.x, bv.w, acc[0][3]);
      acc[1][0] = fmaf(av.y, bv.x, acc[1][0]); acc[1][1] = fmaf(av.y, bv.y, acc[1][1]);
      acc[1][2] = fmaf(av.y, bv.z, acc[1][2]); acc[1][3] = fmaf(av.y, bv.w, acc[1][3]);
      acc[2][0] = fmaf(av.z, bv.x, acc[2][0]); acc[2][1] = fmaf(av.z, bv.y, acc[2][1]);
      acc[2][2] = fmaf(av.z, bv.z, acc[2][2]); acc[2][3] = fmaf(av.z, bv.w, acc[2][3]);
      acc[3][0] = fmaf(av.w, bv.x, acc[3][0]); acc[3][1] = fmaf(av.w, bv.y, acc[3][1]);
      acc[3][2] = fmaf(av.w, bv.z, acc[3][2]); acc[3][3] = fmaf(av.w, bv.w, acc[3][3]);
    }
    __syncthreads();
  }
#pragma unroll
  for (int i = 0; i < 4; i++) {
    int gm = bm * 64 + ty * 4 + i;
    if (gm < M) {
#pragma unroll
      for (int j = 0; j < 4; j++) {
        int gn = bn * 64 + tx * 4 + j;
        C[(size_t)gm * N + gn] = fmaxf(acc[i][j] + bias[gn], 0.f);
      }
    }
  }
}

// ============================ head linear (cls 2 + bbox 8 per roi) ============================
__global__ __launch_bounds__(64) void head_linear_kernel(
    const float* __restrict__ H2, const float* __restrict__ cw, const float* __restrict__ cb2,
    const float* __restrict__ bw, const float* __restrict__ bb2,
    const unsigned* __restrict__ Mc, float* __restrict__ out10) {
  int r = blockIdx.x;
  if (r >= (int)*Mc) return;
  __shared__ float x[1024];
  const float* h = H2 + (size_t)r * 1024;
  for (int i = threadIdx.x; i < 1024; i += 64) x[i] = h[i];
  __syncthreads();
  int t = threadIdx.x;
  if (t < 10) {
    const float* w = (t < 2) ? (cw + t * 1024) : (bw + (t - 2) * 1024);
    float bias = (t < 2) ? cb2[t] : bb2[t - 2];
    float dot = 0.f;
    for (int k = 0; k < 1024; k++) dot = fmaf(w[k], x[k], dot);
    out10[r * 10 + t] = dot + bias;
  }
}

// ============================ head decode ============================
__global__ __launch_bounds__(256) void head_decode_kernel(
    const float* __restrict__ out10, const float* __restrict__ rois,
    const unsigned* __restrict__ Mc, HeadCand* __restrict__ hc, int b) {
#pragma clang fp contract(off)
  int r = blockIdx.x * 256 + threadIdx.x;
  if (r >= (int)Mc[b]) return;
  const float* h = out10 + (size_t)r * 10;
  float l0 = h[0], l1 = h[1];
  float mx = fmaxf(l0, l1);
  float e0 = expf(l0 - mx), e1 = expf(l1 - mx);
  float sfg = e1 / (e0 + e1);
  const float* rr = rois + ((size_t)b * kPostNms + r) * 4;
  float4 bx = decode_clip(rr[0], rr[1], rr[2], rr[3], h[6], h[7], h[8], h[9],
                          10.f, 10.f, 5.f, 5.f);
  bool keep = (sfg > 0.05f) && (bx.z - bx.x >= 0.01f) && (bx.w - bx.y >= 0.01f);
  HeadCand c;
  c.x1 = bx.x; c.y1 = bx.y; c.x2 = bx.z; c.y2 = bx.w;
  c.score = sfg;
  c.key = keep ? keyOf(sfg) : 0u;
  c.pad0 = c.pad1 = 0;
  hc[r] = c;
}

// ============================ final output ============================
__global__ __launch_bounds__(256) void output_kernel(
    const float* __restrict__ detBox, const float* __restrict__ detSc,
    const unsigned* __restrict__ detCnt, float* __restrict__ out) {
  int t = threadIdx.x;
  if (t >= 200) return;
  int b = t / 100, q = t - b * 100;
  int cnt = (int)detCnt[b];
  float bx0 = 0.f, bx1 = 0.f, bx2 = 0.f, bx3 = 0.f, sc = 0.f, lb = 0.f;
  if (q < cnt) {
    const float* d = detBox + ((size_t)b * 100 + q) * 4;
    bx0 = d[0]; bx1 = d[1]; bx2 = d[2]; bx3 = d[3];
    sc = detSc[b * 100 + q];
    lb = 1.0f;
  }
  float* ob = out + ((size_t)b * 100 + q) * 4;
  ob[0] = bx0; ob[1] = bx1; ob[2] = bx2; ob[3] = bx3;
  out[800 + t] = sc;
  out[1000 + t] = lb;
}

// ============================ host launcher ============================
extern "C" void kernel_launch(void* const* d_in, const int* in_sizes, int n_in,
                              void* d_out, int out_size, void* d_ws, size_t ws_size,
                              hipStream_t stream) {
  (void)in_sizes; (void)n_in; (void)out_size; (void)ws_size;
  const float* feats[4] = {(const float*)d_in[0], (const float*)d_in[1],
                           (const float*)d_in[2], (const float*)d_in[3]};
  const float* w3 = (const float*)d_in[4];
  const float* b3 = (const float*)d_in[5];
  const float* wc = (const float*)d_in[6];
  const float* bcs = (const float*)d_in[7];
  const float* wb = (const float*)d_in[8];
  const float* bbx = (const float*)d_in[9];
  const float* fc6w = (const float*)d_in[10];
  const float* fc6b = (const float*)d_in[11];
  const float* fc7w = (const float*)d_in[12];
  const float* fc7b = (const float*)d_in[13];
  const float* clsw = (const float*)d_in[14];
  const float* clsb = (const float*)d_in[15];
  const float* bboxw = (const float*)d_in[16];
  const float* bboxb = (const float*)d_in[17];

  unsigned char* base = (unsigned char*)d_ws;
  size_t off = 0;
  auto alloc = [&](size_t bytes) -> void* {
    void* p = base + off;
    off += (bytes + 255) & ~(size_t)255;
    return p;
  };
  unsigned* keys = (unsigned*)alloc((size_t)2 * kAImg * 4);
  float* deltas = (float*)alloc((size_t)2 * kAImg * 16);
  unsigned* tkT = (unsigned*)alloc(32);
  unsigned* tkNeed = (unsigned*)alloc(32);
  Cand* cand = (Cand*)alloc((size_t)2 * kNCand * sizeof(Cand));
  unsigned* sortedSlot = (unsigned*)alloc((size_t)2 * 8192 * 4);
  unsigned* validCnt = (unsigned*)alloc(8);
  float4* boxOff = (float4*)alloc((size_t)2 * 8192 * 16);
  float4* boxRaw = (float4*)alloc((size_t)2 * 8192 * 16);
  unsigned long long* rpnMask = (unsigned long long*)alloc((size_t)2 * 8192 * 128 * 8);
  unsigned* keptIdx = (unsigned*)alloc((size_t)2 * kPostNms * 4);
  float* rois = (float*)alloc((size_t)2 * kPostNms * 16);
  unsigned* Mc = (unsigned*)alloc(8);
  RoiParam* roiPar = (RoiParam*)alloc((size_t)2 * kPostNms * sizeof(RoiParam));
  float* pooled = (float*)alloc((size_t)kPostNms * 6272 * 4);
  float* H1 = (float*)alloc((size_t)kPostNms * 1024 * 4);
  float* H2buf = (float*)alloc((size_t)kPostNms * 1024 * 4);
  float* out10 = (float*)alloc((size_t)kPostNms * 10 * 4);
  HeadCand* hc = (HeadCand*)alloc((size_t)kPostNms * sizeof(HeadCand));
  unsigned* hsorted = (unsigned*)alloc((size_t)2048 * 4);
  unsigned* hvalid = (unsigned*)alloc(4);
  float4* hbox = (float4*)alloc((size_t)2048 * 16);
  float* hsc = (float*)alloc((size_t)2048 * 4);
  unsigned long long* hMask = (unsigned long long*)alloc((size_t)2048 * 32 * 8);
  unsigned* hkept = (unsigned*)alloc((size_t)128 * 4);
  float* detBox = (float*)alloc((size_t)2 * 100 * 4 * 4);
  float* detSc = (float*)alloc((size_t)2 * 100 * 4);
  unsigned* detCnt = (unsigned*)alloc(8);

  // anchor base table, double precision, round-half-even (matches np.round)
  AnchTab tab;
  {
    const double aspects[3] = {0.5, 1.0, 2.0};
    const int sizes[4] = {32, 64, 128, 256};
    for (int l = 0; l < 4; l++)
      for (int a = 0; a < 3; a++) {
        double hr = sqrt(aspects[a]);
        double wr = 1.0 / hr;
        double wsz = wr * sizes[l], hsz = hr * sizes[l];
        tab.v[l][a][0] = (float)rint(-wsz / 2.0);
        tab.v[l][a][1] = (float)rint(-hsz / 2.0);
        tab.v[l][a][2] = (float)rint(wsz / 2.0);
        tab.v[l][a][3] = (float)rint(hsz / 2.0);
      }
  }

  const int LH[4] = {200, 100, 50, 25}, LW[4] = {200, 100, 50, 25};
  const int AOFF[4] = {0, 120000, 150000, 157500};

  for (int b = 0; b < 2; b++) {
    for (int l = 0; l < 4; l++) {
      int H = LH[l], W = LW[l];
      dim3 grid((W + 15) / 16, H);
      rpn_conv_kernel<<<grid, 256, 0, stream>>>(
          feats[l] + (size_t)b * 128 * H * W, H, W, w3, b3, wc, bcs, wb, bbx,
          keys + (size_t)b * kAImg, deltas + (size_t)b * kAImg * 4, AOFF[l]);
    }
  }
  radix_select_kernel<<<6, 1024, 0, stream>>>(keys, tkT, tkNeed);
  cand_build_kernel<<<8, 1024, 0, stream>>>(keys, deltas, tkT, tkNeed, cand, tab);
  sort_desc_kernel<8192><<<2, 1024, 0, stream>>>(
      ((const unsigned*)cand) + 4, 8, kNCand, nullptr, sortedSlot, validCnt, kNCand * 8, 8192);
  rpn_sort_gather<<<dim3(32, 2), 256, 0, stream>>>(cand, sortedSlot, validCnt, boxOff, boxRaw);
  nms_mask_kernel<<<dim3(128, 128, 2), 64, 0, stream>>>(
      boxOff, validCnt, rpnMask, 128, 8192, (long long)8192 * 128, 0.7f);
  nms_reduce_kernel<128, kPostNms><<<2, 64, 0, stream>>>(
      rpnMask, validCnt, keptIdx, Mc, (long long)8192 * 128);
  rpn_roi_gather<<<dim3(8, 2), 256, 0, stream>>>(keptIdx, Mc, boxRaw, rois);
  roi_params_kernel<<<dim3(8, 2), 256, 0, stream>>>(rois, Mc, roiPar);

  for (int b = 0; b < 2; b++) {
    roi_align_kernel<<<49000, 256, 0, stream>>>(
        feats[0], feats[1], feats[2], feats[3], roiPar + (size_t)b * kPostNms, Mc, pooled, b);
    gemm_bias_relu<<<dim3(16, 32), 256, 0, stream>>>(pooled, fc6w, fc6b, H1, 6272, 1024, Mc + b);
    gemm_bias_relu<<<dim3(16, 32), 256, 0, stream>>>(H1, fc7w, fc7b, H2buf, 1024, 1024, Mc + b);
    head_linear_kernel<<<2000, 64, 0, stream>>>(H2buf, clsw, clsb, bboxw, bboxb, Mc + b, out10);
    head_decode_kernel<<<8, 256, 0, stream>>>(out10, rois, Mc, hc, b);
    sort_desc_kernel<2048><<<1, 1024, 0, stream>>>(
        ((const unsigned*)hc) + 5, 8, 2000, Mc + b, hsorted, hvalid, 0, 0);
    head_sort_gather<<<8, 256, 0, stream>>>(hc, hsorted, hvalid, hbox, hsc);
    nms_mask_kernel<<<dim3(32, 32, 1), 64, 0, stream>>>(
        hbox, hvalid, hMask, 32, 0, 0, 0.5f);
    nms_reduce_kernel<32, 100><<<1, 64, 0, stream>>>(
        hMask, hvalid, hkept, detCnt + b, 0);
    head_det_gather<<<1, 128, 0, stream>>>(
        hkept, detCnt + b, hbox, hsc, detBox + (size_t)b * 400, detSc + (size_t)b * 100);
  }
  output_kernel<<<1, 256, 0, stream>>>(detBox, detSc, detCnt, (float*)d_out);
}

// Round 4
// 3469.165 us; speedup vs baseline: 3.3713x; 1.1909x over previous
//
#include <hip/hip_runtime.h>
#include <cmath>

// ============================ constants ============================
static constexpr int kAImg = 159375;   // anchors per image
static constexpr int kNCand = 7875;    // 2000+2000+2000+1875
static constexpr int kPostNms = 2000;
static constexpr int kMPad = 2048;     // padded roi count for MFMA GEMM

__constant__ int c_AOFF[4]   = {0, 120000, 150000, 157500};
__constant__ int c_ALVL[4]   = {120000, 30000, 7500, 1875};
__constant__ int c_CBASE[4]  = {0, 2000, 4000, 6000};
__constant__ int c_LW[4]     = {200, 100, 50, 25};
__constant__ int c_LH[4]     = {200, 100, 50, 25};
__constant__ int c_STRIDE[4] = {4, 8, 16, 32};

struct Cand     { float x1, y1, x2, y2; unsigned key; unsigned lvl; unsigned pad0, pad1; };
struct HeadCand { float x1, y1, x2, y2; float score; unsigned key; unsigned pad0, pad1; };
struct RoiParam { int lvl; float x1, y1, rw, rh; int pad0, pad1, pad2; };
struct AnchTab  { float v[4][3][4]; };

typedef unsigned short u16;
typedef __attribute__((ext_vector_type(8))) short short8;
typedef __attribute__((ext_vector_type(4))) float f32x4;

// ============================ device helpers ============================
__device__ __forceinline__ unsigned keyOf(float f) {
  unsigned u = __float_as_uint(f);
  return (u & 0x80000000u) ? ~u : (u | 0x80000000u);
}

__device__ __forceinline__ u16 f2bf_rne(float f) {
  unsigned u = __float_as_uint(f);
  unsigned r = u + 0x7FFFu + ((u >> 16) & 1u);
  return (u16)(r >> 16);
}
__device__ __forceinline__ float bf2f(u16 h) {
  return __uint_as_float(((unsigned)h) << 16);
}
__device__ __forceinline__ void split_bf16(float f, u16& hi, u16& lo) {
  hi = f2bf_rne(f);
  lo = f2bf_rne(f - bf2f(hi));
}

__device__ __forceinline__ unsigned long long shfl64(unsigned long long v, int src) {
  int lo = __shfl((int)(unsigned)(v & 0xffffffffull), src);
  int hi = __shfl((int)(unsigned)(v >> 32), src);
  return ((unsigned long long)(unsigned)hi << 32) | (unsigned)lo;
}

__device__ __forceinline__ float iou_pair(float4 a, float4 b) {
#pragma clang fp contract(off)
  float ix1 = fmaxf(a.x, b.x), iy1 = fmaxf(a.y, b.y);
  float ix2 = fminf(a.z, b.z), iy2 = fminf(a.w, b.w);
  float iw = fmaxf(ix2 - ix1, 0.f), ih = fmaxf(iy2 - iy1, 0.f);
  float inter = iw * ih;
  float a1 = (a.z - a.x) * (a.w - a.y);
  float a2 = (b.z - b.x) * (b.w - b.y);
  float uni = a1 + a2 - inter;
  return uni > 0.f ? inter / uni : 0.f;
}

__device__ __forceinline__ float4 decode_clip(float bx1, float by1, float bx2, float by2,
                                              float d0, float d1, float d2, float d3,
                                              float wx, float wy, float ww, float wh) {
#pragma clang fp contract(off)
  float w = bx2 - bx1, h = by2 - by1;
  float cx = bx1 + 0.5f * w, cy = by1 + 0.5f * h;
  float dx = d0 / wx, dy = d1 / wy;
  float dw = fminf(d2 / ww, 4.135166556742356f);
  float dh = fminf(d3 / wh, 4.135166556742356f);
  float pcx = dx * w + cx, pcy = dy * h + cy;
  float pw = expf(dw) * w, ph = expf(dh) * h;
  float x1 = pcx - 0.5f * pw, y1 = pcy - 0.5f * ph;
  float x2 = pcx + 0.5f * pw, y2 = pcy + 0.5f * ph;
  x1 = fminf(fmaxf(x1, 0.f), 800.f); y1 = fminf(fmaxf(y1, 0.f), 800.f);
  x2 = fminf(fmaxf(x2, 0.f), 800.f); y2 = fminf(fmaxf(y2, 0.f), 800.f);
  return make_float4(x1, y1, x2, y2);
}

// block-wide exclusive scan of a bool over 1024 threads (16 waves)
__device__ __forceinline__ unsigned block_scan_bool(bool p, unsigned* wbuf, unsigned& total) {
  unsigned long long m = __ballot(p);
  int lane = threadIdx.x & 63;
  int wid = threadIdx.x >> 6;
  unsigned exc = (unsigned)__popcll(m & ((lane == 0) ? 0ull : ((~0ull) >> (64 - lane))));
  if (lane == 0) wbuf[wid] = (unsigned)__popcll(m);
  __syncthreads();
  unsigned pre = 0, tot = 0;
#pragma unroll
  for (int w = 0; w < 16; w++) { unsigned c = wbuf[w]; if (w < wid) pre += c; tot += c; }
  total = tot;
  __syncthreads();
  return pre + exc;
}

// ============================ RPN conv (3x3+relu fused with 1x1 heads) ============================
__global__ __launch_bounds__(256) void rpn_conv_kernel(
    const float* __restrict__ feat, int H, int W,
    const float* __restrict__ w3, const float* __restrict__ b3,
    const float* __restrict__ wc, const float* __restrict__ bcs,
    const float* __restrict__ wb, const float* __restrict__ bbx,
    unsigned* __restrict__ keys, float* __restrict__ deltas, int aoff) {
  __shared__ float Wl[128 * 73];
  __shared__ float patch[8][3][20];
  __shared__ float tt[16][129];
  int tid = threadIdx.x;
  int co = tid & 127, half = tid >> 7;
  int x0 = blockIdx.x * 16;
  int y = blockIdx.y;
  float acc[8];
#pragma unroll
  for (int j = 0; j < 8; j++) acc[j] = 0.f;

  for (int ci0 = 0; ci0 < 128; ci0 += 8) {
    for (int e = tid; e < 128 * 72; e += 256) {
      int r = e / 72, q = e - r * 72;
      Wl[r * 73 + q] = w3[r * 1152 + ci0 * 9 + q];
    }
    for (int e = tid; e < 8 * 54; e += 256) {
      int ci = e / 54, q = e - ci * 54;
      int dy = q / 18, dx = q - dy * 18;
      int gy = y + dy - 1, gx = x0 + dx - 1;
      float v = 0.f;
      if (gy >= 0 && gy < H && gx >= 0 && gx < W)
        v = feat[(size_t)(ci0 + ci) * H * W + gy * W + gx];
      patch[ci][dy][dx] = v;
    }
    __syncthreads();
    for (int ci = 0; ci < 8; ci++) {
#pragma unroll
      for (int ky = 0; ky < 3; ky++) {
        float row[10];
#pragma unroll
        for (int d = 0; d < 10; d++) row[d] = patch[ci][ky][half * 8 + d];
#pragma unroll
        for (int kx = 0; kx < 3; kx++) {
          float wv = Wl[co * 73 + ci * 9 + ky * 3 + kx];
#pragma unroll
          for (int j = 0; j < 8; j++) acc[j] = fmaf(wv, row[j + kx], acc[j]);
        }
      }
    }
    __syncthreads();
  }
  float bias3 = b3[co];
#pragma unroll
  for (int j = 0; j < 8; j++) tt[half * 8 + j][co] = fmaxf(acc[j] + bias3, 0.f);
  __syncthreads();
  if (tid < 240) {
    int oc = tid / 16, p = tid - (tid / 16) * 16;
    int x = x0 + p;
    if (x < W) {
      const float* wrow = (oc < 3) ? (wc + oc * 128) : (wb + (oc - 3) * 128);
      float bias = (oc < 3) ? bcs[oc] : bbx[oc - 3];
      float dot = 0.f;
      for (int k = 0; k < 128; k++) dot = fmaf(wrow[k], tt[p][k], dot);
      float s = dot + bias;
      int pos = y * W + x;
      if (oc < 3) {
        keys[aoff + pos * 3 + oc] = keyOf(s);
      } else {
        int bc = oc - 3, a = bc >> 2, comp = bc & 3;
        deltas[(size_t)(aoff + pos * 3 + a) * 4 + comp] = s;
      }
    }
  }
}

// ============================ radix select per (image,level 0..2) ============================
__global__ __launch_bounds__(1024) void radix_select_kernel(
    const unsigned* __restrict__ keys, unsigned* __restrict__ tkT, unsigned* __restrict__ tkNeed) {
  int job = blockIdx.x;
  int b = job / 3, l = job - b * 3;
  const unsigned* kb = keys + (size_t)b * kAImg + c_AOFF[l];
  int n = c_ALVL[l];
  __shared__ unsigned hist[256];
  __shared__ unsigned s_sel, s_remk;
  unsigned prefix = 0, pmask = 0, remk = 2000;
  for (int shift = 24; shift >= 0; shift -= 8) {
    if (threadIdx.x < 256) hist[threadIdx.x] = 0;
    __syncthreads();
    for (int i = threadIdx.x; i < n; i += 1024) {
      unsigned key = kb[i];
      if ((key & pmask) == prefix) atomicAdd(&hist[(key >> shift) & 255u], 1u);
    }
    __syncthreads();
    if (threadIdx.x == 0) {
      unsigned cum = 0; int sel = 0;
      for (int d = 255; d >= 0; d--) {
        unsigned c = hist[d];
        if (cum + c >= remk) { sel = d; break; }
        cum += c;
      }
      s_sel = (unsigned)sel; s_remk = remk - cum;
    }
    __syncthreads();
    prefix |= (s_sel << shift);
    pmask |= (255u << shift);
    remk = s_remk;
    __syncthreads();
  }
  if (threadIdx.x == 0) { tkT[b * 4 + l] = prefix; tkNeed[b * 4 + l] = remk; }
}

// ============================ candidate build ============================
__global__ __launch_bounds__(1024) void cand_build_kernel(
    const unsigned* __restrict__ keys, const float* __restrict__ deltas,
    const unsigned* __restrict__ tkT, const unsigned* __restrict__ tkNeed,
    Cand* __restrict__ cand, AnchTab tab) {
  int b = blockIdx.x >> 2, l = blockIdx.x & 3;
  int n = c_ALVL[l];
  int W = c_LW[l];
  int stride = c_STRIDE[l];
  const unsigned* kb = keys + (size_t)b * kAImg + c_AOFF[l];
  const float* db = deltas + ((size_t)b * kAImg + c_AOFF[l]) * 4;
  Cand* cb = cand + (size_t)b * kNCand + c_CBASE[l];
  bool selAll = (l == 3);
  unsigned T = selAll ? 0u : tkT[b * 4 + l];
  unsigned need = selAll ? 0u : tkNeed[b * 4 + l];
  __shared__ unsigned wbuf[16];
  __shared__ unsigned s_runeq, s_runout;
  if (threadIdx.x == 0) { s_runeq = 0; s_runout = 0; }
  __syncthreads();
  for (int c0 = 0; c0 < n; c0 += 1024) {
    int i = c0 + (int)threadIdx.x;
    bool act = i < n;
    unsigned key = act ? kb[i] : 0u;
    bool isEq = (!selAll) && act && (key == T);
    unsigned eqTot;
    unsigned eqExc = block_scan_bool(isEq, wbuf, eqTot);
    unsigned runeq = s_runeq;
    unsigned runout = s_runout;
    bool isSel = act && (selAll || key > T || (isEq && (runeq + eqExc) < need));
    unsigned selTot;
    unsigned selExc = block_scan_bool(isSel, wbuf, selTot);
    if (isSel) {
      int slot = (int)(runout + selExc);
      int pos = i / 3, a = i - pos * 3;
      int yy = pos / W, xx = pos - yy * W;
      float sx = (float)(xx * stride), sy = (float)(yy * stride);
      float ax1 = tab.v[l][a][0] + sx;
      float ay1 = tab.v[l][a][1] + sy;
      float ax2 = tab.v[l][a][2] + sx;
      float ay2 = tab.v[l][a][3] + sy;
      float d0 = db[(size_t)i * 4 + 0], d1 = db[(size_t)i * 4 + 1];
      float d2 = db[(size_t)i * 4 + 2], d3 = db[(size_t)i * 4 + 3];
      float4 bx = decode_clip(ax1, ay1, ax2, ay2, d0, d1, d2, d3, 1.f, 1.f, 1.f, 1.f);
      bool ok = (bx.z - bx.x >= 0.001f) && (bx.w - bx.y >= 0.001f);
      Cand cd;
      cd.x1 = bx.x; cd.y1 = bx.y; cd.x2 = bx.z; cd.y2 = bx.w;
      cd.key = ok ? key : 0u; cd.lvl = (unsigned)l; cd.pad0 = 0; cd.pad1 = 0;
      cb[slot] = cd;
    }
    __syncthreads();
    if (threadIdx.x == 0) { s_runeq = runeq + eqTot; s_runout = runout + selTot; }
    __syncthreads();
  }
}

// ============================ single-block bitonic sort (desc key, asc slot) ============================
template <int NPAD>
__global__ __launch_bounds__(1024) void sort_desc_kernel(
    const unsigned* __restrict__ keyBase, int strideWords, int nFixed,
    const unsigned* __restrict__ nPtr, unsigned* __restrict__ sortedSlot,
    unsigned* __restrict__ validCnt, int imgStrideKeyWords, int imgStrideSlot) {
  __shared__ unsigned sk[NPAD];
  __shared__ unsigned short sslot[NPAD];
  __shared__ unsigned s_cnt;
  int b = blockIdx.x;
  const unsigned* kbase = keyBase + (size_t)b * imgStrideKeyWords;
  unsigned* oslot = sortedSlot + (size_t)b * imgStrideSlot;
  unsigned* ocnt = validCnt + b;
  int n = nFixed;
  if (nPtr) { int m = (int)nPtr[b]; n = n < m ? n : m; }
  for (int i = threadIdx.x; i < NPAD; i += 1024) {
    sk[i] = (i < n) ? kbase[(size_t)i * strideWords] : 0u;
    sslot[i] = (unsigned short)i;
  }
  if (threadIdx.x == 0) s_cnt = 0;
  __syncthreads();
  for (int k2 = 2; k2 <= NPAD; k2 <<= 1) {
    for (int j = k2 >> 1; j > 0; j >>= 1) {
      for (int i = threadIdx.x; i < NPAD; i += 1024) {
        int ixj = i ^ j;
        if (ixj > i) {
          unsigned ka = sk[i], kb2 = sk[ixj];
          unsigned short sa = sslot[i], sb = sslot[ixj];
          bool aGreater = (ka > kb2) || (ka == kb2 && sa < sb);
          bool up = ((i & k2) == 0);
          bool doSwap = up ? (!aGreater) : aGreater;
          if (doSwap) { sk[i] = kb2; sk[ixj] = ka; sslot[i] = sb; sslot[ixj] = sa; }
        }
      }
      __syncthreads();
    }
  }
  unsigned local = 0;
  for (int i = threadIdx.x; i < NPAD; i += 1024) {
    oslot[i] = (unsigned)sslot[i];
    if (sk[i] > 0u) local++;
  }
  atomicAdd(&s_cnt, local);
  __syncthreads();
  if (threadIdx.x == 0) *ocnt = s_cnt;
}

// ============================ sorted gather (RPN): offset + raw boxes ============================
__global__ __launch_bounds__(256) void rpn_sort_gather(
    const Cand* __restrict__ cand, const unsigned* __restrict__ ss,
    const unsigned* __restrict__ validCnt, float4* __restrict__ boxOff,
    float4* __restrict__ boxRaw) {
  int b = blockIdx.y;
  int pos = blockIdx.x * 256 + threadIdx.x;
  int valid = (int)validCnt[b];
  float4 raw = make_float4(0.f, 0.f, 0.f, 0.f);
  float4 off4 = raw;
  if (pos < valid) {
#pragma clang fp contract(off)
    Cand c = cand[(size_t)b * kNCand + ss[(size_t)b * 8192 + pos]];
    float off = 801.0f * (float)c.lvl;
    raw = make_float4(c.x1, c.y1, c.x2, c.y2);
    off4 = make_float4(c.x1 + off, c.y1 + off, c.x2 + off, c.y2 + off);
  }
  boxOff[(size_t)b * 8192 + pos] = off4;
  boxRaw[(size_t)b * 8192 + pos] = raw;
}

// ============================ sorted gather (head): boxes + scores ============================
__global__ __launch_bounds__(256) void head_sort_gather(
    const HeadCand* __restrict__ hc, const unsigned* __restrict__ hsorted,
    const unsigned* __restrict__ hvalid, float4* __restrict__ hbox, float* __restrict__ hsc) {
  int pos = blockIdx.x * 256 + threadIdx.x;
  int valid = (int)*hvalid;
  float4 v = make_float4(0.f, 0.f, 0.f, 0.f);
  float s = 0.f;
  if (pos < valid) {
    HeadCand c = hc[hsorted[pos]];
    v = make_float4(c.x1, c.y1, c.x2, c.y2);
    s = c.score;
  }
  hbox[pos] = v;
  hsc[pos] = s;
}

// ============================ NMS suppression-mask build ============================
__global__ __launch_bounds__(64) void nms_mask_kernel(
    const float4* __restrict__ boxesOff, const unsigned* __restrict__ validCnt,
    unsigned long long* __restrict__ mask, int rowStrideWords,
    int imgBoxStride, long long imgMaskStride, float th) {
  int b = blockIdx.z;
  const float4* bx = boxesOff + (size_t)b * imgBoxStride;
  unsigned long long* mrow = mask + (size_t)b * imgMaskStride;
  int valid = (int)validCnt[b];
  int i = blockIdx.x * 64 + threadIdx.x;
  int j0 = blockIdx.y * 64;
  __shared__ float4 sb[64];
  sb[threadIdx.x] = bx[j0 + threadIdx.x];
  __syncthreads();
  float4 a = bx[i];
  unsigned long long bits = 0;
  for (int t = 0; t < 64; t++) {
    int j = j0 + t;
    if (j > i && j < valid && iou_pair(a, sb[t]) > th) bits |= (1ull << t);
  }
  mrow[(size_t)i * rowStrideWords + (j0 >> 6)] = bits;
}

// ============================ NMS reduce ============================
template <int WORDS, int KMAX>
__global__ __launch_bounds__(64) void nms_reduce_kernel(
    const unsigned long long* __restrict__ mask, const unsigned* __restrict__ validCnt,
    unsigned* __restrict__ keptIdx, unsigned* __restrict__ keptCnt,
    long long imgMaskStride) {
  constexpr int WPT = (WORDS + 63) / 64;
  constexpr int C = 8;
  int b = blockIdx.x;
  const unsigned long long* mrow = mask + (size_t)b * imgMaskStride;
  int valid = (int)validCnt[b];
  unsigned* kout = keptIdx + (size_t)b * KMAX;
  int lane = threadIdx.x;
  unsigned long long removed[WPT];
#pragma unroll
  for (int p = 0; p < WPT; p++) removed[p] = 0ull;
  int kept = 0;
  unsigned long long bufA[C][WPT], bufB[C][WPT];

  auto loadc = [&](unsigned long long (&bf)[C][WPT], int cbase) {
#pragma unroll
    for (int t = 0; t < C; t++) {
      int i = cbase + t;
#pragma unroll
      for (int p = 0; p < WPT; p++) {
        int w = lane + 64 * p;
        unsigned long long v = 0ull;
        if (w < WORDS && i < valid) v = mrow[(size_t)i * WORDS + w];
        bf[t][p] = v;
      }
    }
  };

  unsigned long long curw = 0ull;
  int curWidx = -1;

  auto procc = [&](unsigned long long (&bf)[C][WPT], int cbase) {
#pragma unroll
    for (int t = 0; t < C; t++) {
      int i = cbase + t;
      bool act = (i < valid) && (kept < KMAX);
      if (act) {
        int w = i >> 6;
        if (w != curWidx) {
          curWidx = w;
          unsigned long long rv = (WPT > 1 && w >= 64) ? removed[WPT - 1] : removed[0];
          curw = shfl64(rv, w & 63);
        }
        if (!((curw >> (i & 63)) & 1ull)) {
#pragma unroll
          for (int p = 0; p < WPT; p++) removed[p] |= bf[t][p];
          unsigned long long bv = (WPT > 1 && w >= 64) ? bf[t][WPT - 1] : bf[t][0];
          curw |= shfl64(bv, w & 63);
          if (lane == 0) kout[kept] = (unsigned)i;
          kept++;
        }
      }
    }
  };

  loadc(bufA, 0);
  for (int c0 = 0; c0 < valid; c0 += 2 * C) {
    loadc(bufB, c0 + C);
    procc(bufA, c0);
    if (kept >= KMAX) break;
    loadc(bufA, c0 + 2 * C);
    procc(bufB, c0 + C);
    if (kept >= KMAX) break;
  }
  if (threadIdx.x == 0) keptCnt[b] = (unsigned)kept;
}

// ============================ kept-index gathers ============================
__global__ __launch_bounds__(256) void rpn_roi_gather(
    const unsigned* __restrict__ keptIdx, const unsigned* __restrict__ Mc,
    const float4* __restrict__ boxRaw, float* __restrict__ rois) {
  int b = blockIdx.y;
  int k = blockIdx.x * 256 + threadIdx.x;
  if (k >= (int)Mc[b]) return;
  unsigned i = keptIdx[(size_t)b * kPostNms + k];
  float4 v = boxRaw[(size_t)b * 8192 + i];
  float* r = rois + ((size_t)b * kPostNms + k) * 4;
  r[0] = v.x; r[1] = v.y; r[2] = v.z; r[3] = v.w;
}

__global__ __launch_bounds__(128) void head_det_gather(
    const unsigned* __restrict__ keptIdx, const unsigned* __restrict__ cnt,
    const float4* __restrict__ hbox, const float* __restrict__ hsc,
    float* __restrict__ detBox, float* __restrict__ detSc) {
  int k = threadIdx.x;
  if (k >= (int)*cnt || k >= 100) return;
  unsigned i = keptIdx[k];
  float4 v = hbox[i];
  detBox[k * 4 + 0] = v.x; detBox[k * 4 + 1] = v.y;
  detBox[k * 4 + 2] = v.z; detBox[k * 4 + 3] = v.w;
  detSc[k] = hsc[i];
}

// ============================ ROI params ============================
__global__ __launch_bounds__(256) void roi_params_kernel(
    const float* __restrict__ rois, const unsigned* __restrict__ Mc, RoiParam* __restrict__ par) {
  int b = blockIdx.y;
  int i = blockIdx.x * 256 + threadIdx.x;
  if (i >= (int)Mc[b]) return;
  const float* r = rois + ((size_t)b * kPostNms + i) * 4;
  float x1 = r[0], y1 = r[1], x2 = r[2], y2 = r[3];
  float area = (x2 - x1) * (y2 - y1);
  float tgt = floorf(4.0f + log2f(sqrtf(fmaxf(area, 0.f)) / 224.0f + 1e-6f));
  tgt = fminf(fmaxf(tgt, 2.f), 5.f);
  int l = (int)tgt - 2;
  const float scales[4] = {0.25f, 0.125f, 0.0625f, 0.03125f};
  float sc = scales[l];
  RoiParam p;
  p.lvl = l;
  p.x1 = x1 * sc; p.y1 = y1 * sc;
  p.rw = fmaxf(x2 * sc - p.x1, 1.0f);
  p.rh = fmaxf(y2 * sc - p.y1, 1.0f);
  p.pad0 = p.pad1 = p.pad2 = 0;
  par[(size_t)b * kPostNms + i] = p;
}

// ============================ pooled pad (zero rows >= Mc) ============================
__global__ __launch_bounds__(256) void pad_pooled_kernel(
    u16* __restrict__ hi, u16* __restrict__ lo, const unsigned* __restrict__ Mc, int b) {
  int start = (int)Mc[b] * 6272;
  const int total = kMPad * 6272;
  for (int i = start + (int)(blockIdx.x * 256 + threadIdx.x); i < total; i += 512 * 256) {
    hi[i] = 0; lo[i] = 0;
  }
}

// ============================ multi-scale ROI align (writes split-bf16) ============================
__global__ __launch_bounds__(256) void roi_align_kernel(
    const float* __restrict__ f0, const float* __restrict__ f1,
    const float* __restrict__ f2, const float* __restrict__ f3,
    const RoiParam* __restrict__ par, const unsigned* __restrict__ Mc,
    u16* __restrict__ pooledHi, u16* __restrict__ pooledLo, int b) {
  int idx = blockIdx.x * 256 + threadIdx.x;
  int roi = idx / 6272;
  if (roi >= (int)Mc[b]) return;
  int rem = idx - roi * 6272;
  int c = rem / 49, bin = rem - c * 49;
  int py = bin / 7, px = bin - py * 7;
  RoiParam p = par[roi];
  int H = c_LH[p.lvl], W = c_LW[p.lvl];
  const float* f = (p.lvl == 0 ? f0 : p.lvl == 1 ? f1 : p.lvl == 2 ? f2 : f3);
  f += ((size_t)b * 128 + c) * (size_t)(H * W);
  float Hf = (float)H, Wf = (float)W;
  float rh7 = p.rh / 7.0f, rw7 = p.rw / 7.0f;
  float sum = 0.f;
#pragma unroll
  for (int sy = 0; sy < 2; sy++) {
    float offy = (float)py + ((float)sy + 0.5f) * 0.5f;
    float Y = p.y1 + offy * rh7;
    float yc = fminf(fmaxf(Y, 0.f), Hf - 1.f);
    float y0f = floorf(yc);
    int y0 = (int)y0f;
    int y1 = min(y0 + 1, H - 1);
    float ly = yc - y0f, hy = 1.f - ly;
#pragma unroll
    for (int sx = 0; sx < 2; sx++) {
      float offx = (float)px + ((float)sx + 0.5f) * 0.5f;
      float X = p.x1 + offx * rw7;
      bool valid = (Y > -1.f) && (Y < Hf) && (X > -1.f) && (X < Wf);
      float xc = fminf(fmaxf(X, 0.f), Wf - 1.f);
      float x0f = floorf(xc);
      int x0 = (int)x0f;
      int x1i = min(x0 + 1, W - 1);
      float lx = xc - x0f, hx = 1.f - lx;
      float v = hy * hx * f[y0 * W + x0] + hy * lx * f[y0 * W + x1i] +
                ly * hx * f[y1 * W + x0] + ly * lx * f[y1 * W + x1i];
      sum += valid ? v : 0.f;
    }
  }
  float v = sum * 0.25f;
  u16 hi, lo;
  split_bf16(v, hi, lo);
  pooledHi[idx] = hi;
  pooledLo[idx] = lo;
}

// ============================ weight split conversion ============================
__global__ __launch_bounds__(256) void convert_split_kernel(
    const float* __restrict__ src, u16* __restrict__ hi, u16* __restrict__ lo, int n) {
  for (int i = blockIdx.x * 256 + threadIdx.x; i < n; i += gridDim.x * 256) {
    u16 h, l;
    split_bf16(src[i], h, l);
    hi[i] = h; lo[i] = l;
  }
}

// ============================ bf16x3 split-K MFMA GEMM ============================
// C_part[z][m][n] = sum_{k in split z} A[m][k]*B[n][k], A=(Ah+Al), B=(Bh+Bl), drop Al*Bl.
// grid: x = N/128, y = M/128, z = splits. block 256 = 4 waves, each wave 64x64.
__global__ __launch_bounds__(256) void gemm_x3_kernel(
    const u16* __restrict__ Ah, const u16* __restrict__ Al,
    const u16* __restrict__ Bh, const u16* __restrict__ Bl,
    float* __restrict__ Cpart, int K, int kChunks) {
  __shared__ u16 sAh[128][40], sAl[128][40], sBh[128][40], sBl[128][40];
  int tid = threadIdx.x;
  int m0 = blockIdx.y * 128, n0 = blockIdx.x * 128;
  int kBase = blockIdx.z * kChunks * 32;
  int w = tid >> 6, lane = tid & 63;
  int wm = (w >> 1) * 64, wn = (w & 1) * 64;
  int quad = lane >> 4, lrow = lane & 15;
  f32x4 acc[4][4];
#pragma unroll
  for (int i = 0; i < 4; i++)
#pragma unroll
    for (int j = 0; j < 4; j++) acc[i][j] = (f32x4)0.f;

  for (int c = 0; c < kChunks; c++) {
    int k0 = kBase + c * 32;
    // stage 128x32 of each array; 512 ushort8 vectors per array, 2 per thread
    for (int e = tid; e < 512; e += 256) {
      int row = e >> 2, kk = (e & 3) * 8;
      size_t ga = (size_t)(m0 + row) * K + k0 + kk;
      size_t gb = (size_t)(n0 + row) * K + k0 + kk;
      *(short8*)&sAh[row][kk] = *(const short8*)&Ah[ga];
      *(short8*)&sAl[row][kk] = *(const short8*)&Al[ga];
      *(short8*)&sBh[row][kk] = *(const short8*)&Bh[gb];
      *(short8*)&sBl[row][kk] = *(const short8*)&Bl[gb];
    }
    __syncthreads();
    int kb = quad * 8;
    short8 afh[4], afl[4], bfh[4], bfl[4];
#pragma unroll
    for (int t = 0; t < 4; t++) {
      afh[t] = *(const short8*)&sAh[wm + t * 16 + lrow][kb];
      afl[t] = *(const short8*)&sAl[wm + t * 16 + lrow][kb];
      bfh[t] = *(const short8*)&sBh[wn + t * 16 + lrow][kb];
      bfl[t] = *(const short8*)&sBl[wn + t * 16 + lrow][kb];
    }
#pragma unroll
    for (int mt = 0; mt < 4; mt++)
#pragma unroll
      for (int nt = 0; nt < 4; nt++) {
        acc[mt][nt] = __builtin_amdgcn_mfma_f32_16x16x32_bf16(afh[mt], bfh[nt], acc[mt][nt], 0, 0, 0);
        acc[mt][nt] = __builtin_amdgcn_mfma_f32_16x16x32_bf16(afh[mt], bfl[nt], acc[mt][nt], 0, 0, 0);
        acc[mt][nt] = __builtin_amdgcn_mfma_f32_16x16x32_bf16(afl[mt], bfh[nt], acc[mt][nt], 0, 0, 0);
      }
    __syncthreads();
  }
  float* out = Cpart + (size_t)blockIdx.z * (kMPad * 1024);
#pragma unroll
  for (int mt = 0; mt < 4; mt++)
#pragma unroll
    for (int nt = 0; nt < 4; nt++) {
      int col = n0 + wn + nt * 16 + lrow;
#pragma unroll
      for (int reg = 0; reg < 4; reg++) {
        int row = m0 + wm + mt * 16 + quad * 4 + reg;
        out[(size_t)row * 1024 + col] = acc[mt][nt][reg];
      }
    }
}

// ============================ combine partials: bias+relu -> split-bf16 ============================
__global__ __launch_bounds__(256) void combine_relu_split_kernel(
    const float* __restrict__ part, const float* __restrict__ bias,
    u16* __restrict__ hi, u16* __restrict__ lo) {
  int idx = blockIdx.x * 256 + threadIdx.x;
  int n = idx & 1023;
  float v = fmaxf(part[idx] + part[idx + kMPad * 1024] + bias[n], 0.f);
  u16 h, l;
  split_bf16(v, h, l);
  hi[idx] = h; lo[idx] = l;
}

// ============================ combine partials: bias+relu -> f32 ============================
__global__ __launch_bounds__(256) void combine_relu_f32_kernel(
    const float* __restrict__ part, const float* __restrict__ bias,
    float* __restrict__ out) {
  int idx = blockIdx.x * 256 + threadIdx.x;
  int n = idx & 1023;
  out[idx] = fmaxf(part[idx] + part[idx + kMPad * 1024] + bias[n], 0.f);
}

// ============================ head linear (cls 2 + bbox 8 per roi) ============================
__global__ __launch_bounds__(64) void head_linear_kernel(
    const float* __restrict__ H2, const float* __restrict__ cw, const float* __restrict__ cb2,
    const float* __restrict__ bw, const float* __restrict__ bb2,
    const unsigned* __restrict__ Mc, float* __restrict__ out10) {
  int r = blockIdx.x;
  if (r >= (int)*Mc) return;
  __shared__ float x[1024];
  const float* h = H2 + (size_t)r * 1024;
  for (int i = threadIdx.x; i < 1024; i += 64) x[i] = h[i];
  __syncthreads();
  int t = threadIdx.x;
  if (t < 10) {
    const float* w = (t < 2) ? (cw + t * 1024) : (bw + (t - 2) * 1024);
    float bias = (t < 2) ? cb2[t] : bb2[t - 2];
    float dot = 0.f;
    for (int k = 0; k < 1024; k++) dot = fmaf(w[k], x[k], dot);
    out10[r * 10 + t] = dot + bias;
  }
}

// ============================ head decode ============================
__global__ __launch_bounds__(256) void head_decode_kernel(
    const float* __restrict__ out10, const float* __restrict__ rois,
    const unsigned* __restrict__ Mc, HeadCand* __restrict__ hc, int b) {
#pragma clang fp contract(off)
  int r = blockIdx.x * 256 + threadIdx.x;
  if (r >= (int)Mc[b]) return;
  const float* h = out10 + (size_t)r * 10;
  float l0 = h[0], l1 = h[1];
  float mx = fmaxf(l0, l1);
  float e0 = expf(l0 - mx), e1 = expf(l1 - mx);
  float sfg = e1 / (e0 + e1);
  const float* rr = rois + ((size_t)b * kPostNms + r) * 4;
  float4 bx = decode_clip(rr[0], rr[1], rr[2], rr[3], h[6], h[7], h[8], h[9],
                          10.f, 10.f, 5.f, 5.f);
  bool keep = (sfg > 0.05f) && (bx.z - bx.x >= 0.01f) && (bx.w - bx.y >= 0.01f);
  HeadCand c;
  c.x1 = bx.x; c.y1 = bx.y; c.x2 = bx.z; c.y2 = bx.w;
  c.score = sfg;
  c.key = keep ? keyOf(sfg) : 0u;
  c.pad0 = c.pad1 = 0;
  hc[r] = c;
}

// ============================ final output ============================
__global__ __launch_bounds__(256) void output_kernel(
    const float* __restrict__ detBox, const float* __restrict__ detSc,
    const unsigned* __restrict__ detCnt, float* __restrict__ out) {
  int t = threadIdx.x;
  if (t >= 200) return;
  int b = t / 100, q = t - b * 100;
  int cnt = (int)detCnt[b];
  float bx0 = 0.f, bx1 = 0.f, bx2 = 0.f, bx3 = 0.f, sc = 0.f, lb = 0.f;
  if (q < cnt) {
    const float* d = detBox + ((size_t)b * 100 + q) * 4;
    bx0 = d[0]; bx1 = d[1]; bx2 = d[2]; bx3 = d[3];
    sc = detSc[b * 100 + q];
    lb = 1.0f;
  }
  float* ob = out + ((size_t)b * 100 + q) * 4;
  ob[0] = bx0; ob[1] = bx1; ob[2] = bx2; ob[3] = bx3;
  out[800 + t] = sc;
  out[1000 + t] = lb;
}

// ============================ host launcher ============================
extern "C" void kernel_launch(void* const* d_in, const int* in_sizes, int n_in,
                              void* d_out, int out_size, void* d_ws, size_t ws_size,
                              hipStream_t stream) {
  (void)in_sizes; (void)n_in; (void)out_size; (void)ws_size;
  const float* feats[4] = {(const float*)d_in[0], (const float*)d_in[1],
                           (const float*)d_in[2], (const float*)d_in[3]};
  const float* w3 = (const float*)d_in[4];
  const float* b3 = (const float*)d_in[5];
  const float* wc = (const float*)d_in[6];
  const float* bcs = (const float*)d_in[7];
  const float* wb = (const float*)d_in[8];
  const float* bbx = (const float*)d_in[9];
  const float* fc6w = (const float*)d_in[10];
  const float* fc6b = (const float*)d_in[11];
  const float* fc7w = (const float*)d_in[12];
  const float* fc7b = (const float*)d_in[13];
  const float* clsw = (const float*)d_in[14];
  const float* clsb = (const float*)d_in[15];
  const float* bboxw = (const float*)d_in[16];
  const float* bboxb = (const float*)d_in[17];

  unsigned char* base = (unsigned char*)d_ws;
  size_t off = 0;
  auto alloc = [&](size_t bytes) -> void* {
    void* p = base + off;
    off += (bytes + 255) & ~(size_t)255;
    return p;
  };
  unsigned* keys = (unsigned*)alloc((size_t)2 * kAImg * 4);
  float* deltas = (float*)alloc((size_t)2 * kAImg * 16);
  unsigned* tkT = (unsigned*)alloc(32);
  unsigned* tkNeed = (unsigned*)alloc(32);
  Cand* cand = (Cand*)alloc((size_t)2 * kNCand * sizeof(Cand));
  unsigned* sortedSlot = (unsigned*)alloc((size_t)2 * 8192 * 4);
  unsigned* validCnt = (unsigned*)alloc(8);
  float4* boxOff = (float4*)alloc((size_t)2 * 8192 * 16);
  float4* boxRaw = (float4*)alloc((size_t)2 * 8192 * 16);
  unsigned long long* rpnMask = (unsigned long long*)alloc((size_t)2 * 8192 * 128 * 8);
  unsigned* keptIdx = (unsigned*)alloc((size_t)2 * kPostNms * 4);
  float* rois = (float*)alloc((size_t)2 * kPostNms * 16);
  unsigned* Mc = (unsigned*)alloc(8);
  RoiParam* roiPar = (RoiParam*)alloc((size_t)2 * kPostNms * sizeof(RoiParam));
  u16* pooledHi = (u16*)alloc((size_t)kMPad * 6272 * 2);
  u16* pooledLo = (u16*)alloc((size_t)kMPad * 6272 * 2);
  u16* fc6wHi = (u16*)alloc((size_t)1024 * 6272 * 2);
  u16* fc6wLo = (u16*)alloc((size_t)1024 * 6272 * 2);
  u16* fc7wHi = (u16*)alloc((size_t)1024 * 1024 * 2);
  u16* fc7wLo = (u16*)alloc((size_t)1024 * 1024 * 2);
  float* part = (float*)alloc((size_t)2 * kMPad * 1024 * 4);
  u16* H1hi = (u16*)alloc((size_t)kMPad * 1024 * 2);
  u16* H1lo = (u16*)alloc((size_t)kMPad * 1024 * 2);
  float* H2buf = (float*)alloc((size_t)kMPad * 1024 * 4);
  float* out10 = (float*)alloc((size_t)kPostNms * 10 * 4);
  HeadCand* hc = (HeadCand*)alloc((size_t)kPostNms * sizeof(HeadCand));
  unsigned* hsorted = (unsigned*)alloc((size_t)2048 * 4);
  unsigned* hvalid = (unsigned*)alloc(4);
  float4* hbox = (float4*)alloc((size_t)2048 * 16);
  float* hsc = (float*)alloc((size_t)2048 * 4);
  unsigned long long* hMask = (unsigned long long*)alloc((size_t)2048 * 32 * 8);
  unsigned* hkept = (unsigned*)alloc((size_t)128 * 4);
  float* detBox = (float*)alloc((size_t)2 * 100 * 4 * 4);
  float* detSc = (float*)alloc((size_t)2 * 100 * 4);
  unsigned* detCnt = (unsigned*)alloc(8);

  // anchor base table, double precision, round-half-even (matches np.round)
  AnchTab tab;
  {
    const double aspects[3] = {0.5, 1.0, 2.0};
    const int sizes[4] = {32, 64, 128, 256};
    for (int l = 0; l < 4; l++)
      for (int a = 0; a < 3; a++) {
        double hr = sqrt(aspects[a]);
        double wr = 1.0 / hr;
        double wsz = wr * sizes[l], hsz = hr * sizes[l];
        tab.v[l][a][0] = (float)rint(-wsz / 2.0);
        tab.v[l][a][1] = (float)rint(-hsz / 2.0);
        tab.v[l][a][2] = (float)rint(wsz / 2.0);
        tab.v[l][a][3] = (float)rint(hsz / 2.0);
      }
  }

  const int LH[4] = {200, 100, 50, 25}, LW[4] = {200, 100, 50, 25};
  const int AOFF[4] = {0, 120000, 150000, 157500};

  // weight conversion (same work every call; graph-capture safe)
  convert_split_kernel<<<4096, 256, 0, stream>>>(fc6w, fc6wHi, fc6wLo, 1024 * 6272);
  convert_split_kernel<<<1024, 256, 0, stream>>>(fc7w, fc7wHi, fc7wLo, 1024 * 1024);

  for (int b = 0; b < 2; b++) {
    for (int l = 0; l < 4; l++) {
      int H = LH[l], W = LW[l];
      dim3 grid((W + 15) / 16, H);
      rpn_conv_kernel<<<grid, 256, 0, stream>>>(
          feats[l] + (size_t)b * 128 * H * W, H, W, w3, b3, wc, bcs, wb, bbx,
          keys + (size_t)b * kAImg, deltas + (size_t)b * kAImg * 4, AOFF[l]);
    }
  }
  radix_select_kernel<<<6, 1024, 0, stream>>>(keys, tkT, tkNeed);
  cand_build_kernel<<<8, 1024, 0, stream>>>(keys, deltas, tkT, tkNeed, cand, tab);
  sort_desc_kernel<8192><<<2, 1024, 0, stream>>>(
      ((const unsigned*)cand) + 4, 8, kNCand, nullptr, sortedSlot, validCnt, kNCand * 8, 8192);
  rpn_sort_gather<<<dim3(32, 2), 256, 0, stream>>>(cand, sortedSlot, validCnt, boxOff, boxRaw);
  nms_mask_kernel<<<dim3(128, 128, 2), 64, 0, stream>>>(
      boxOff, validCnt, rpnMask, 128, 8192, (long long)8192 * 128, 0.7f);
  nms_reduce_kernel<128, kPostNms><<<2, 64, 0, stream>>>(
      rpnMask, validCnt, keptIdx, Mc, (long long)8192 * 128);
  rpn_roi_gather<<<dim3(8, 2), 256, 0, stream>>>(keptIdx, Mc, boxRaw, rois);
  roi_params_kernel<<<dim3(8, 2), 256, 0, stream>>>(rois, Mc, roiPar);

  for (int b = 0; b < 2; b++) {
    pad_pooled_kernel<<<512, 256, 0, stream>>>(pooledHi, pooledLo, Mc, b);
    roi_align_kernel<<<49000, 256, 0, stream>>>(
        feats[0], feats[1], feats[2], feats[3], roiPar + (size_t)b * kPostNms, Mc,
        pooledHi, pooledLo, b);
    // fc6: M=2048, N=1024, K=6272 (split 2 x 49 chunks of 32)
    gemm_x3_kernel<<<dim3(8, 16, 2), 256, 0, stream>>>(
        pooledHi, pooledLo, fc6wHi, fc6wLo, part, 6272, 98);
    combine_relu_split_kernel<<<8192, 256, 0, stream>>>(part, fc6b, H1hi, H1lo);
    // fc7: M=2048, N=1024, K=1024 (split 2 x 16 chunks of 32)
    gemm_x3_kernel<<<dim3(8, 16, 2), 256, 0, stream>>>(
        H1hi, H1lo, fc7wHi, fc7wLo, part, 1024, 16);
    combine_relu_f32_kernel<<<8192, 256, 0, stream>>>(part, fc7b, H2buf);
    head_linear_kernel<<<2000, 64, 0, stream>>>(H2buf, clsw, clsb, bboxw, bboxb, Mc + b, out10);
    head_decode_kernel<<<8, 256, 0, stream>>>(out10, rois, Mc, hc, b);
    sort_desc_kernel<2048><<<1, 1024, 0, stream>>>(
        ((const unsigned*)hc) + 5, 8, 2000, Mc + b, hsorted, hvalid, 0, 0);
    head_sort_gather<<<8, 256, 0, stream>>>(hc, hsorted, hvalid, hbox, hsc);
    nms_mask_kernel<<<dim3(32, 32, 1), 64, 0, stream>>>(
        hbox, hvalid, hMask, 32, 0, 0, 0.5f);
    nms_reduce_kernel<32, 100><<<1, 64, 0, stream>>>(
        hMask, hvalid, hkept, detCnt + b, 0);
    head_det_gather<<<1, 128, 0, stream>>>(
        hkept, detCnt + b, hbox, hsc, detBox + (size_t)b * 400, detSc + (size_t)b * 100);
  }
  output_kernel<<<1, 256, 0, stream>>>(detBox, detSc, detCnt, (float*)d_out);
}

// Round 5
// 2889.194 us; speedup vs baseline: 4.0480x; 1.2007x over previous
//
#include <hip/hip_runtime.h>
#include <cmath>

// ============================ constants ============================
static constexpr int kAImg = 159375;   // anchors per image
static constexpr int kNCand = 7875;    // 2000+2000+2000+1875
static constexpr int kPostNms = 2000;
static constexpr int kMPad = 2048;     // padded roi count for MFMA GEMM
static constexpr float kISC = 1.0f / 4096.0f;

__constant__ int c_AOFF[4]   = {0, 120000, 150000, 157500};
__constant__ int c_ALVL[4]   = {120000, 30000, 7500, 1875};
__constant__ int c_CBASE[4]  = {0, 2000, 4000, 6000};
__constant__ int c_LW[4]     = {200, 100, 50, 25};
__constant__ int c_LH[4]     = {200, 100, 50, 25};
__constant__ int c_STRIDE[4] = {4, 8, 16, 32};

struct Cand     { float x1, y1, x2, y2; unsigned key; unsigned lvl; unsigned pad0, pad1; };
struct HeadCand { float x1, y1, x2, y2; float score; unsigned key; unsigned pad0, pad1; };
struct RoiParam { int lvl; float x1, y1, rw, rh; int pad0, pad1, pad2; };
struct AnchTab  { float v[4][3][4]; };

typedef unsigned short u16;
typedef __attribute__((ext_vector_type(8))) short short8;
typedef __attribute__((ext_vector_type(4))) float f32x4;
typedef _Float16 f16x8 __attribute__((ext_vector_type(8)));

// ============================ device helpers ============================
__device__ __forceinline__ unsigned keyOf(float f) {
  unsigned u = __float_as_uint(f);
  return (u & 0x80000000u) ? ~u : (u | 0x80000000u);
}

// fp32 -> (f16 hi, f16 lo*4096). value = hi + lo/4096, err ~ 2^-24 relative.
__device__ __forceinline__ void split_f16(float f, u16& hi, u16& lo) {
  union { _Float16 h; u16 u; } a, b;
  a.h = (_Float16)f;
  float r = (f - (float)a.h) * 4096.0f;
  b.h = (_Float16)r;
  hi = a.u; lo = b.u;
}

__device__ __forceinline__ unsigned long long shfl64(unsigned long long v, int src) {
  int lo = __shfl((int)(unsigned)(v & 0xffffffffull), src);
  int hi = __shfl((int)(unsigned)(v >> 32), src);
  return ((unsigned long long)(unsigned)hi << 32) | (unsigned)lo;
}

__device__ __forceinline__ float iou_pair(float4 a, float4 b) {
#pragma clang fp contract(off)
  float ix1 = fmaxf(a.x, b.x), iy1 = fmaxf(a.y, b.y);
  float ix2 = fminf(a.z, b.z), iy2 = fminf(a.w, b.w);
  float iw = fmaxf(ix2 - ix1, 0.f), ih = fmaxf(iy2 - iy1, 0.f);
  float inter = iw * ih;
  float a1 = (a.z - a.x) * (a.w - a.y);
  float a2 = (b.z - b.x) * (b.w - b.y);
  float uni = a1 + a2 - inter;
  return uni > 0.f ? inter / uni : 0.f;
}

__device__ __forceinline__ float4 decode_clip(float bx1, float by1, float bx2, float by2,
                                              float d0, float d1, float d2, float d3,
                                              float wx, float wy, float ww, float wh) {
#pragma clang fp contract(off)
  float w = bx2 - bx1, h = by2 - by1;
  float cx = bx1 + 0.5f * w, cy = by1 + 0.5f * h;
  float dx = d0 / wx, dy = d1 / wy;
  float dw = fminf(d2 / ww, 4.135166556742356f);
  float dh = fminf(d3 / wh, 4.135166556742356f);
  float pcx = dx * w + cx, pcy = dy * h + cy;
  float pw = expf(dw) * w, ph = expf(dh) * h;
  float x1 = pcx - 0.5f * pw, y1 = pcy - 0.5f * ph;
  float x2 = pcx + 0.5f * pw, y2 = pcy + 0.5f * ph;
  x1 = fminf(fmaxf(x1, 0.f), 800.f); y1 = fminf(fmaxf(y1, 0.f), 800.f);
  x2 = fminf(fmaxf(x2, 0.f), 800.f); y2 = fminf(fmaxf(y2, 0.f), 800.f);
  return make_float4(x1, y1, x2, y2);
}

// block-wide exclusive scan of a bool over 1024 threads (16 waves)
__device__ __forceinline__ unsigned block_scan_bool(bool p, unsigned* wbuf, unsigned& total) {
  unsigned long long m = __ballot(p);
  int lane = threadIdx.x & 63;
  int wid = threadIdx.x >> 6;
  unsigned exc = (unsigned)__popcll(m & ((lane == 0) ? 0ull : ((~0ull) >> (64 - lane))));
  if (lane == 0) wbuf[wid] = (unsigned)__popcll(m);
  __syncthreads();
  unsigned pre = 0, tot = 0;
#pragma unroll
  for (int w = 0; w < 16; w++) { unsigned c = wbuf[w]; if (w < wid) pre += c; tot += c; }
  total = tot;
  __syncthreads();
  return pre + exc;
}

// ============================ zero fill ============================
__global__ __launch_bounds__(256) void zero_u32_kernel(unsigned* __restrict__ p, int n32) {
  for (int i = blockIdx.x * 256 + threadIdx.x; i < n32; i += gridDim.x * 256) p[i] = 0u;
}

// ============================ NCHW -> padded HWC f16-split transpose ============================
template <int H, int W>
__global__ __launch_bounds__(256) void transpose_pad_kernel(
    const float* __restrict__ feat, u16* __restrict__ Fh, u16* __restrict__ Fl) {
  __shared__ float tile[128][65];
  int y = blockIdx.y;
  int x0 = blockIdx.x * 64;
  for (int e = threadIdx.x; e < 128 * 64; e += 256) {
    int ci = e >> 6, x = e & 63;
    float v = 0.f;
    if (x0 + x < W) v = feat[(size_t)ci * (H * W) + y * W + x0 + x];
    tile[ci][x] = v;
  }
  __syncthreads();
  for (int e = threadIdx.x; e < 64 * 128; e += 256) {
    int x = e >> 7, ci = e & 127;
    if (x0 + x >= W) continue;
    u16 hi, lo;
    split_f16(tile[ci][x], hi, lo);
    size_t out = ((size_t)(y + 1) * (W + 2) + (x0 + x + 1)) * 128 + ci;
    Fh[out] = hi; Fl[out] = lo;
  }
}

// ============================ conv weight repack: [co][ci][tap] -> [tap][co][ci] f16 split ============================
__global__ __launch_bounds__(256) void conv_w_repack_kernel(
    const float* __restrict__ w3, u16* __restrict__ Wh, u16* __restrict__ Wl) {
  int idx = blockIdx.x * 256 + threadIdx.x;
  if (idx >= 9 * 128 * 128) return;
  int tap = idx >> 14;
  int r = idx & 16383;
  int co = r >> 7, ci = r & 127;
  u16 hi, lo;
  split_f16(w3[co * 1152 + ci * 9 + tap], hi, lo);
  Wh[idx] = hi; Wl[idx] = lo;
}

// ============================ implicit-GEMM MFMA 3x3 conv (f16x3 dual-acc) ============================
// block: 128 positions x 128 out-channels; 4 waves each 64x64. tbuf[m][co] = relu(conv+bias).
template <int H, int W>
__global__ __launch_bounds__(256) void conv_mfma_kernel(
    const u16* __restrict__ Fh, const u16* __restrict__ Fl,
    const u16* __restrict__ Wh, const u16* __restrict__ Wl,
    const float* __restrict__ b3, float* __restrict__ tbuf) {
  __shared__ u16 sAh[128][40], sAl[128][40], sBh[128][40], sBl[128][40];
  int tid = threadIdx.x;
  int m0 = blockIdx.x * 128;
  int w = tid >> 6, lane = tid & 63;
  int wm = (w >> 1) * 64, wn = (w & 1) * 64;
  int quad = lane >> 4, lrow = lane & 15;
  f32x4 acc1[4][4], acc2[4][4];
#pragma unroll
  for (int i = 0; i < 4; i++)
#pragma unroll
    for (int j = 0; j < 4; j++) { acc1[i][j] = (f32x4)0.f; acc2[i][j] = (f32x4)0.f; }

  for (int tap = 0; tap < 9; tap++) {
    int ky = tap / 3, kx = tap - (tap / 3) * 3;
    for (int c = 0; c < 4; c++) {
      for (int e = tid; e < 512; e += 256) {
        int row = e >> 2, seg = (e & 3) * 8;
        int m = m0 + row;
        int y = m / W, x = m - y * W;
        size_t pidx = ((size_t)(y + ky) * (W + 2) + x + kx) * 128 + c * 32 + seg;
        *(short8*)&sAh[row][seg] = *(const short8*)&Fh[pidx];
        *(short8*)&sAl[row][seg] = *(const short8*)&Fl[pidx];
        size_t bidx = ((size_t)tap * 128 + row) * 128 + c * 32 + seg;
        *(short8*)&sBh[row][seg] = *(const short8*)&Wh[bidx];
        *(short8*)&sBl[row][seg] = *(const short8*)&Wl[bidx];
      }
      __syncthreads();
      int kb = quad * 8;
      f16x8 afh[4], afl[4], bfh[4], bfl[4];
#pragma unroll
      for (int t = 0; t < 4; t++) {
        afh[t] = *(const f16x8*)&sAh[wm + t * 16 + lrow][kb];
        afl[t] = *(const f16x8*)&sAl[wm + t * 16 + lrow][kb];
        bfh[t] = *(const f16x8*)&sBh[wn + t * 16 + lrow][kb];
        bfl[t] = *(const f16x8*)&sBl[wn + t * 16 + lrow][kb];
      }
#pragma unroll
      for (int mt = 0; mt < 4; mt++)
#pragma unroll
        for (int nt = 0; nt < 4; nt++) {
          acc1[mt][nt] = __builtin_amdgcn_mfma_f32_16x16x32_f16(afh[mt], bfh[nt], acc1[mt][nt], 0, 0, 0);
          acc2[mt][nt] = __builtin_amdgcn_mfma_f32_16x16x32_f16(afh[mt], bfl[nt], acc2[mt][nt], 0, 0, 0);
          acc2[mt][nt] = __builtin_amdgcn_mfma_f32_16x16x32_f16(afl[mt], bfh[nt], acc2[mt][nt], 0, 0, 0);
        }
      __syncthreads();
    }
  }
#pragma unroll
  for (int nt = 0; nt < 4; nt++) {
    int col = wn + nt * 16 + lrow;
    float bias = b3[col];
#pragma unroll
    for (int mt = 0; mt < 4; mt++) {
#pragma unroll
      for (int reg = 0; reg < 4; reg++) {
        int row = m0 + wm + mt * 16 + quad * 4 + reg;
        float v = acc1[mt][nt][reg] + kISC * acc2[mt][nt][reg] + bias;
        tbuf[(size_t)row * 128 + col] = fmaxf(v, 0.f);
      }
    }
  }
}

// ============================ 1x1 heads from t (HWC fp32) ============================
__global__ __launch_bounds__(256) void head_1x1_kernel(
    const float* __restrict__ tbuf,
    const float* __restrict__ wc, const float* __restrict__ bcs,
    const float* __restrict__ wb, const float* __restrict__ bbx,
    unsigned* __restrict__ keys, float* __restrict__ deltas, int aoff, int HW) {
  __shared__ float wl[15][128];
  __shared__ float bl[15];
  for (int e = threadIdx.x; e < 15 * 128; e += 256) {
    int oc = e >> 7, k = e & 127;
    wl[oc][k] = (oc < 3) ? wc[oc * 128 + k] : wb[(oc - 3) * 128 + k];
  }
  if (threadIdx.x < 15)
    bl[threadIdx.x] = (threadIdx.x < 3) ? bcs[threadIdx.x] : bbx[threadIdx.x - 3];
  __syncthreads();
  int m = blockIdx.x * 256 + threadIdx.x;
  if (m >= HW) return;
  const float* trow = tbuf + (size_t)m * 128;
  float dot[15];
#pragma unroll
  for (int o = 0; o < 15; o++) dot[o] = 0.f;
  for (int k = 0; k < 128; k += 4) {
    float4 v = *(const float4*)&trow[k];
#pragma unroll
    for (int o = 0; o < 15; o++) {
      dot[o] = fmaf(wl[o][k], v.x, dot[o]);
      dot[o] = fmaf(wl[o][k + 1], v.y, dot[o]);
      dot[o] = fmaf(wl[o][k + 2], v.z, dot[o]);
      dot[o] = fmaf(wl[o][k + 3], v.w, dot[o]);
    }
  }
#pragma unroll
  for (int oc = 0; oc < 15; oc++) {
    float s = dot[oc] + bl[oc];
    if (oc < 3) {
      keys[aoff + m * 3 + oc] = keyOf(s);
    } else {
      int bc = oc - 3, a = bc >> 2, comp = bc & 3;
      deltas[(size_t)(aoff + m * 3 + a) * 4 + comp] = s;
    }
  }
}

// ============================ radix select per (image,level 0..2) ============================
__global__ __launch_bounds__(1024) void radix_select_kernel(
    const unsigned* __restrict__ keys, unsigned* __restrict__ tkT, unsigned* __restrict__ tkNeed) {
  int job = blockIdx.x;
  int b = job / 3, l = job - b * 3;
  const unsigned* kb = keys + (size_t)b * kAImg + c_AOFF[l];
  int n = c_ALVL[l];
  __shared__ unsigned hist[256];
  __shared__ unsigned s_sel, s_remk;
  unsigned prefix = 0, pmask = 0, remk = 2000;
  for (int shift = 24; shift >= 0; shift -= 8) {
    if (threadIdx.x < 256) hist[threadIdx.x] = 0;
    __syncthreads();
    for (int i = threadIdx.x; i < n; i += 1024) {
      unsigned key = kb[i];
      if ((key & pmask) == prefix) atomicAdd(&hist[(key >> shift) & 255u], 1u);
    }
    __syncthreads();
    if (threadIdx.x == 0) {
      unsigned cum = 0; int sel = 0;
      for (int d = 255; d >= 0; d--) {
        unsigned c = hist[d];
        if (cum + c >= remk) { sel = d; break; }
        cum += c;
      }
      s_sel = (unsigned)sel; s_remk = remk - cum;
    }
    __syncthreads();
    prefix |= (s_sel << shift);
    pmask |= (255u << shift);
    remk = s_remk;
    __syncthreads();
  }
  if (threadIdx.x == 0) { tkT[b * 4 + l] = prefix; tkNeed[b * 4 + l] = remk; }
}

// ============================ candidate build ============================
__global__ __launch_bounds__(1024) void cand_build_kernel(
    const unsigned* __restrict__ keys, const float* __restrict__ deltas,
    const unsigned* __restrict__ tkT, const unsigned* __restrict__ tkNeed,
    Cand* __restrict__ cand, AnchTab tab) {
  int b = blockIdx.x >> 2, l = blockIdx.x & 3;
  int n = c_ALVL[l];
  int W = c_LW[l];
  int stride = c_STRIDE[l];
  const unsigned* kb = keys + (size_t)b * kAImg + c_AOFF[l];
  const float* db = deltas + ((size_t)b * kAImg + c_AOFF[l]) * 4;
  Cand* cb = cand + (size_t)b * kNCand + c_CBASE[l];
  bool selAll = (l == 3);
  unsigned T = selAll ? 0u : tkT[b * 4 + l];
  unsigned need = selAll ? 0u : tkNeed[b * 4 + l];
  __shared__ unsigned wbuf[16];
  __shared__ unsigned s_runeq, s_runout;
  if (threadIdx.x == 0) { s_runeq = 0; s_runout = 0; }
  __syncthreads();
  for (int c0 = 0; c0 < n; c0 += 1024) {
    int i = c0 + (int)threadIdx.x;
    bool act = i < n;
    unsigned key = act ? kb[i] : 0u;
    bool isEq = (!selAll) && act && (key == T);
    unsigned eqTot;
    unsigned eqExc = block_scan_bool(isEq, wbuf, eqTot);
    unsigned runeq = s_runeq;
    unsigned runout = s_runout;
    bool isSel = act && (selAll || key > T || (isEq && (runeq + eqExc) < need));
    unsigned selTot;
    unsigned selExc = block_scan_bool(isSel, wbuf, selTot);
    if (isSel) {
      int slot = (int)(runout + selExc);
      int pos = i / 3, a = i - pos * 3;
      int yy = pos / W, xx = pos - yy * W;
      float sx = (float)(xx * stride), sy = (float)(yy * stride);
      float ax1 = tab.v[l][a][0] + sx;
      float ay1 = tab.v[l][a][1] + sy;
      float ax2 = tab.v[l][a][2] + sx;
      float ay2 = tab.v[l][a][3] + sy;
      float d0 = db[(size_t)i * 4 + 0], d1 = db[(size_t)i * 4 + 1];
      float d2 = db[(size_t)i * 4 + 2], d3 = db[(size_t)i * 4 + 3];
      float4 bx = decode_clip(ax1, ay1, ax2, ay2, d0, d1, d2, d3, 1.f, 1.f, 1.f, 1.f);
      bool ok = (bx.z - bx.x >= 0.001f) && (bx.w - bx.y >= 0.001f);
      Cand cd;
      cd.x1 = bx.x; cd.y1 = bx.y; cd.x2 = bx.z; cd.y2 = bx.w;
      cd.key = ok ? key : 0u; cd.lvl = (unsigned)l; cd.pad0 = 0; cd.pad1 = 0;
      cb[slot] = cd;
    }
    __syncthreads();
    if (threadIdx.x == 0) { s_runeq = runeq + eqTot; s_runout = runout + selTot; }
    __syncthreads();
  }
}

// ============================ single-block bitonic sort (desc key, asc slot) ============================
template <int NPAD>
__global__ __launch_bounds__(1024) void sort_desc_kernel(
    const unsigned* __restrict__ keyBase, int strideWords, int nFixed,
    const unsigned* __restrict__ nPtr, unsigned* __restrict__ sortedSlot,
    unsigned* __restrict__ validCnt, int imgStrideKeyWords, int imgStrideSlot) {
  __shared__ unsigned sk[NPAD];
  __shared__ unsigned short sslot[NPAD];
  __shared__ unsigned s_cnt;
  int b = blockIdx.x;
  const unsigned* kbase = keyBase + (size_t)b * imgStrideKeyWords;
  unsigned* oslot = sortedSlot + (size_t)b * imgStrideSlot;
  unsigned* ocnt = validCnt + b;
  int n = nFixed;
  if (nPtr) { int m = (int)nPtr[b]; n = n < m ? n : m; }
  for (int i = threadIdx.x; i < NPAD; i += 1024) {
    sk[i] = (i < n) ? kbase[(size_t)i * strideWords] : 0u;
    sslot[i] = (unsigned short)i;
  }
  if (threadIdx.x == 0) s_cnt = 0;
  __syncthreads();
  for (int k2 = 2; k2 <= NPAD; k2 <<= 1) {
    for (int j = k2 >> 1; j > 0; j >>= 1) {
      for (int i = threadIdx.x; i < NPAD; i += 1024) {
        int ixj = i ^ j;
        if (ixj > i) {
          unsigned ka = sk[i], kb2 = sk[ixj];
          unsigned short sa = sslot[i], sb = sslot[ixj];
          bool aGreater = (ka > kb2) || (ka == kb2 && sa < sb);
          bool up = ((i & k2) == 0);
          bool doSwap = up ? (!aGreater) : aGreater;
          if (doSwap) { sk[i] = kb2; sk[ixj] = ka; sslot[i] = sb; sslot[ixj] = sa; }
        }
      }
      __syncthreads();
    }
  }
  unsigned local = 0;
  for (int i = threadIdx.x; i < NPAD; i += 1024) {
    oslot[i] = (unsigned)sslot[i];
    if (sk[i] > 0u) local++;
  }
  atomicAdd(&s_cnt, local);
  __syncthreads();
  if (threadIdx.x == 0) *ocnt = s_cnt;
}

// ============================ sorted gather (RPN): offset + raw boxes ============================
__global__ __launch_bounds__(256) void rpn_sort_gather(
    const Cand* __restrict__ cand, const unsigned* __restrict__ ss,
    const unsigned* __restrict__ validCnt, float4* __restrict__ boxOff,
    float4* __restrict__ boxRaw) {
  int b = blockIdx.y;
  int pos = blockIdx.x * 256 + threadIdx.x;
  int valid = (int)validCnt[b];
  float4 raw = make_float4(0.f, 0.f, 0.f, 0.f);
  float4 off4 = raw;
  if (pos < valid) {
#pragma clang fp contract(off)
    Cand c = cand[(size_t)b * kNCand + ss[(size_t)b * 8192 + pos]];
    float off = 801.0f * (float)c.lvl;
    raw = make_float4(c.x1, c.y1, c.x2, c.y2);
    off4 = make_float4(c.x1 + off, c.y1 + off, c.x2 + off, c.y2 + off);
  }
  boxOff[(size_t)b * 8192 + pos] = off4;
  boxRaw[(size_t)b * 8192 + pos] = raw;
}

// ============================ sorted gather (head): boxes + scores ============================
__global__ __launch_bounds__(256) void head_sort_gather(
    const HeadCand* __restrict__ hc, const unsigned* __restrict__ hsorted,
    const unsigned* __restrict__ hvalid, float4* __restrict__ hbox, float* __restrict__ hsc) {
  int pos = blockIdx.x * 256 + threadIdx.x;
  int valid = (int)*hvalid;
  float4 v = make_float4(0.f, 0.f, 0.f, 0.f);
  float s = 0.f;
  if (pos < valid) {
    HeadCand c = hc[hsorted[pos]];
    v = make_float4(c.x1, c.y1, c.x2, c.y2);
    s = c.score;
  }
  hbox[pos] = v;
  hsc[pos] = s;
}

// ============================ NMS suppression-mask build ============================
__global__ __launch_bounds__(64) void nms_mask_kernel(
    const float4* __restrict__ boxesOff, const unsigned* __restrict__ validCnt,
    unsigned long long* __restrict__ mask, int rowStrideWords,
    int imgBoxStride, long long imgMaskStride, float th) {
  int b = blockIdx.z;
  const float4* bx = boxesOff + (size_t)b * imgBoxStride;
  unsigned long long* mrow = mask + (size_t)b * imgMaskStride;
  int valid = (int)validCnt[b];
  int i = blockIdx.x * 64 + threadIdx.x;
  int j0 = blockIdx.y * 64;
  __shared__ float4 sb[64];
  sb[threadIdx.x] = bx[j0 + threadIdx.x];
  __syncthreads();
  float4 a = bx[i];
  unsigned long long bits = 0;
  for (int t = 0; t < 64; t++) {
    int j = j0 + t;
    if (j > i && j < valid && iou_pair(a, sb[t]) > th) bits |= (1ull << t);
  }
  mrow[(size_t)i * rowStrideWords + (j0 >> 6)] = bits;
}

// ============================ NMS reduce ============================
template <int WORDS, int KMAX>
__global__ __launch_bounds__(64) void nms_reduce_kernel(
    const unsigned long long* __restrict__ mask, const unsigned* __restrict__ validCnt,
    unsigned* __restrict__ keptIdx, unsigned* __restrict__ keptCnt,
    long long imgMaskStride) {
  constexpr int WPT = (WORDS + 63) / 64;
  constexpr int C = 8;
  int b = blockIdx.x;
  const unsigned long long* mrow = mask + (size_t)b * imgMaskStride;
  int valid = (int)validCnt[b];
  unsigned* kout = keptIdx + (size_t)b * KMAX;
  int lane = threadIdx.x;
  unsigned long long removed[WPT];
#pragma unroll
  for (int p = 0; p < WPT; p++) removed[p] = 0ull;
  int kept = 0;
  unsigned long long bufA[C][WPT], bufB[C][WPT];

  auto loadc = [&](unsigned long long (&bf)[C][WPT], int cbase) {
#pragma unroll
    for (int t = 0; t < C; t++) {
      int i = cbase + t;
#pragma unroll
      for (int p = 0; p < WPT; p++) {
        int w = lane + 64 * p;
        unsigned long long v = 0ull;
        if (w < WORDS && i < valid) v = mrow[(size_t)i * WORDS + w];
        bf[t][p] = v;
      }
    }
  };

  unsigned long long curw = 0ull;
  int curWidx = -1;

  auto procc = [&](unsigned long long (&bf)[C][WPT], int cbase) {
#pragma unroll
    for (int t = 0; t < C; t++) {
      int i = cbase + t;
      bool act = (i < valid) && (kept < KMAX);
      if (act) {
        int w = i >> 6;
        if (w != curWidx) {
          curWidx = w;
          unsigned long long rv = (WPT > 1 && w >= 64) ? removed[WPT - 1] : removed[0];
          curw = shfl64(rv, w & 63);
        }
        if (!((curw >> (i & 63)) & 1ull)) {
#pragma unroll
          for (int p = 0; p < WPT; p++) removed[p] |= bf[t][p];
          unsigned long long bv = (WPT > 1 && w >= 64) ? bf[t][WPT - 1] : bf[t][0];
          curw |= shfl64(bv, w & 63);
          if (lane == 0) kout[kept] = (unsigned)i;
          kept++;
        }
      }
    }
  };

  loadc(bufA, 0);
  for (int c0 = 0; c0 < valid; c0 += 2 * C) {
    loadc(bufB, c0 + C);
    procc(bufA, c0);
    if (kept >= KMAX) break;
    loadc(bufA, c0 + 2 * C);
    procc(bufB, c0 + C);
    if (kept >= KMAX) break;
  }
  if (threadIdx.x == 0) keptCnt[b] = (unsigned)kept;
}

// ============================ kept-index gathers ============================
__global__ __launch_bounds__(256) void rpn_roi_gather(
    const unsigned* __restrict__ keptIdx, const unsigned* __restrict__ Mc,
    const float4* __restrict__ boxRaw, float* __restrict__ rois) {
  int b = blockIdx.y;
  int k = blockIdx.x * 256 + threadIdx.x;
  if (k >= (int)Mc[b]) return;
  unsigned i = keptIdx[(size_t)b * kPostNms + k];
  float4 v = boxRaw[(size_t)b * 8192 + i];
  float* r = rois + ((size_t)b * kPostNms + k) * 4;
  r[0] = v.x; r[1] = v.y; r[2] = v.z; r[3] = v.w;
}

__global__ __launch_bounds__(128) void head_det_gather(
    const unsigned* __restrict__ keptIdx, const unsigned* __restrict__ cnt,
    const float4* __restrict__ hbox, const float* __restrict__ hsc,
    float* __restrict__ detBox, float* __restrict__ detSc) {
  int k = threadIdx.x;
  if (k >= (int)*cnt || k >= 100) return;
  unsigned i = keptIdx[k];
  float4 v = hbox[i];
  detBox[k * 4 + 0] = v.x; detBox[k * 4 + 1] = v.y;
  detBox[k * 4 + 2] = v.z; detBox[k * 4 + 3] = v.w;
  detSc[k] = hsc[i];
}

// ============================ ROI params ============================
__global__ __launch_bounds__(256) void roi_params_kernel(
    const float* __restrict__ rois, const unsigned* __restrict__ Mc, RoiParam* __restrict__ par) {
  int b = blockIdx.y;
  int i = blockIdx.x * 256 + threadIdx.x;
  if (i >= (int)Mc[b]) return;
  const float* r = rois + ((size_t)b * kPostNms + i) * 4;
  float x1 = r[0], y1 = r[1], x2 = r[2], y2 = r[3];
  float area = (x2 - x1) * (y2 - y1);
  float tgt = floorf(4.0f + log2f(sqrtf(fmaxf(area, 0.f)) / 224.0f + 1e-6f));
  tgt = fminf(fmaxf(tgt, 2.f), 5.f);
  int l = (int)tgt - 2;
  const float scales[4] = {0.25f, 0.125f, 0.0625f, 0.03125f};
  float sc = scales[l];
  RoiParam p;
  p.lvl = l;
  p.x1 = x1 * sc; p.y1 = y1 * sc;
  p.rw = fmaxf(x2 * sc - p.x1, 1.0f);
  p.rh = fmaxf(y2 * sc - p.y1, 1.0f);
  p.pad0 = p.pad1 = p.pad2 = 0;
  par[(size_t)b * kPostNms + i] = p;
}

// ============================ pooled pad (zero rows >= Mc) ============================
__global__ __launch_bounds__(256) void pad_pooled_kernel(
    u16* __restrict__ hi, u16* __restrict__ lo, const unsigned* __restrict__ Mc, int b) {
  int start = (int)Mc[b] * 6272;
  const int total = kMPad * 6272;
  for (int i = start + (int)(blockIdx.x * 256 + threadIdx.x); i < total; i += 512 * 256) {
    hi[i] = 0; lo[i] = 0;
  }
}

// ============================ multi-scale ROI align (writes split-f16) ============================
__global__ __launch_bounds__(256) void roi_align_kernel(
    const float* __restrict__ f0, const float* __restrict__ f1,
    const float* __restrict__ f2, const float* __restrict__ f3,
    const RoiParam* __restrict__ par, const unsigned* __restrict__ Mc,
    u16* __restrict__ pooledHi, u16* __restrict__ pooledLo, int b) {
  int idx = blockIdx.x * 256 + threadIdx.x;
  int roi = idx / 6272;
  if (roi >= (int)Mc[b]) return;
  int rem = idx - roi * 6272;
  int c = rem / 49, bin = rem - c * 49;
  int py = bin / 7, px = bin - py * 7;
  RoiParam p = par[roi];
  int H = c_LH[p.lvl], W = c_LW[p.lvl];
  const float* f = (p.lvl == 0 ? f0 : p.lvl == 1 ? f1 : p.lvl == 2 ? f2 : f3);
  f += ((size_t)b * 128 + c) * (size_t)(H * W);
  float Hf = (float)H, Wf = (float)W;
  float rh7 = p.rh / 7.0f, rw7 = p.rw / 7.0f;
  float sum = 0.f;
#pragma unroll
  for (int sy = 0; sy < 2; sy++) {
    float offy = (float)py + ((float)sy + 0.5f) * 0.5f;
    float Y = p.y1 + offy * rh7;
    float yc = fminf(fmaxf(Y, 0.f), Hf - 1.f);
    float y0f = floorf(yc);
    int y0 = (int)y0f;
    int y1 = min(y0 + 1, H - 1);
    float ly = yc - y0f, hy = 1.f - ly;
#pragma unroll
    for (int sx = 0; sx < 2; sx++) {
      float offx = (float)px + ((float)sx + 0.5f) * 0.5f;
      float X = p.x1 + offx * rw7;
      bool valid = (Y > -1.f) && (Y < Hf) && (X > -1.f) && (X < Wf);
      float xc = fminf(fmaxf(X, 0.f), Wf - 1.f);
      float x0f = floorf(xc);
      int x0 = (int)x0f;
      int x1i = min(x0 + 1, W - 1);
      float lx = xc - x0f, hx = 1.f - lx;
      float v = hy * hx * f[y0 * W + x0] + hy * lx * f[y0 * W + x1i] +
                ly * hx * f[y1 * W + x0] + ly * lx * f[y1 * W + x1i];
      sum += valid ? v : 0.f;
    }
  }
  float v = sum * 0.25f;
  u16 hi, lo;
  split_f16(v, hi, lo);
  pooledHi[idx] = hi;
  pooledLo[idx] = lo;
}

// ============================ weight split conversion ============================
__global__ __launch_bounds__(256) void convert_split_kernel(
    const float* __restrict__ src, u16* __restrict__ hi, u16* __restrict__ lo, int n) {
  for (int i = blockIdx.x * 256 + threadIdx.x; i < n; i += gridDim.x * 256) {
    u16 h, l;
    split_f16(src[i], h, l);
    hi[i] = h; lo[i] = l;
  }
}

// ============================ f16x3 dual-acc split-K MFMA GEMM ============================
// C_part[z][m][n] over K-split z; A=(Ah+Al/4096), B=(Bh+Bl/4096), drop Al*Bl.
__global__ __launch_bounds__(256) void gemm_f16x3_kernel(
    const u16* __restrict__ Ah, const u16* __restrict__ Al,
    const u16* __restrict__ Bh, const u16* __restrict__ Bl,
    float* __restrict__ Cpart, int K, int kChunks) {
  __shared__ u16 sAh[128][40], sAl[128][40], sBh[128][40], sBl[128][40];
  int tid = threadIdx.x;
  int m0 = blockIdx.y * 128, n0 = blockIdx.x * 128;
  int kBase = blockIdx.z * kChunks * 32;
  int w = tid >> 6, lane = tid & 63;
  int wm = (w >> 1) * 64, wn = (w & 1) * 64;
  int quad = lane >> 4, lrow = lane & 15;
  f32x4 acc1[4][4], acc2[4][4];
#pragma unroll
  for (int i = 0; i < 4; i++)
#pragma unroll
    for (int j = 0; j < 4; j++) { acc1[i][j] = (f32x4)0.f; acc2[i][j] = (f32x4)0.f; }

  for (int c = 0; c < kChunks; c++) {
    int k0 = kBase + c * 32;
    for (int e = tid; e < 512; e += 256) {
      int row = e >> 2, kk = (e & 3) * 8;
      size_t ga = (size_t)(m0 + row) * K + k0 + kk;
      size_t gb = (size_t)(n0 + row) * K + k0 + kk;
      *(short8*)&sAh[row][kk] = *(const short8*)&Ah[ga];
      *(short8*)&sAl[row][kk] = *(const short8*)&Al[ga];
      *(short8*)&sBh[row][kk] = *(const short8*)&Bh[gb];
      *(short8*)&sBl[row][kk] = *(const short8*)&Bl[gb];
    }
    __syncthreads();
    int kb = quad * 8;
    f16x8 afh[4], afl[4], bfh[4], bfl[4];
#pragma unroll
    for (int t = 0; t < 4; t++) {
      afh[t] = *(const f16x8*)&sAh[wm + t * 16 + lrow][kb];
      afl[t] = *(const f16x8*)&sAl[wm + t * 16 + lrow][kb];
      bfh[t] = *(const f16x8*)&sBh[wn + t * 16 + lrow][kb];
      bfl[t] = *(const f16x8*)&sBl[wn + t * 16 + lrow][kb];
    }
#pragma unroll
    for (int mt = 0; mt < 4; mt++)
#pragma unroll
      for (int nt = 0; nt < 4; nt++) {
        acc1[mt][nt] = __builtin_amdgcn_mfma_f32_16x16x32_f16(afh[mt], bfh[nt], acc1[mt][nt], 0, 0, 0);
        acc2[mt][nt] = __builtin_amdgcn_mfma_f32_16x16x32_f16(afh[mt], bfl[nt], acc2[mt][nt], 0, 0, 0);
        acc2[mt][nt] = __builtin_amdgcn_mfma_f32_16x16x32_f16(afl[mt], bfh[nt], acc2[mt][nt], 0, 0, 0);
      }
    __syncthreads();
  }
  float* out = Cpart + (size_t)blockIdx.z * (kMPad * 1024);
#pragma unroll
  for (int mt = 0; mt < 4; mt++)
#pragma unroll
    for (int nt = 0; nt < 4; nt++) {
      int col = n0 + wn + nt * 16 + lrow;
#pragma unroll
      for (int reg = 0; reg < 4; reg++) {
        int row = m0 + wm + mt * 16 + quad * 4 + reg;
        out[(size_t)row * 1024 + col] = acc1[mt][nt][reg] + kISC * acc2[mt][nt][reg];
      }
    }
}

// ============================ combine partials: bias+relu -> split-f16 ============================
__global__ __launch_bounds__(256) void combine_relu_split_kernel(
    const float* __restrict__ part, const float* __restrict__ bias,
    u16* __restrict__ hi, u16* __restrict__ lo) {
  int idx = blockIdx.x * 256 + threadIdx.x;
  int n = idx & 1023;
  float v = fmaxf(part[idx] + part[idx + kMPad * 1024] + bias[n], 0.f);
  u16 h, l;
  split_f16(v, h, l);
  hi[idx] = h; lo[idx] = l;
}

// ============================ combine partials: bias+relu -> f32 ============================
__global__ __launch_bounds__(256) void combine_relu_f32_kernel(
    const float* __restrict__ part, const float* __restrict__ bias,
    float* __restrict__ out) {
  int idx = blockIdx.x * 256 + threadIdx.x;
  int n = idx & 1023;
  out[idx] = fmaxf(part[idx] + part[idx + kMPad * 1024] + bias[n], 0.f);
}

// ============================ head linear (cls 2 + bbox 8 per roi) ============================
__global__ __launch_bounds__(64) void head_linear_kernel(
    const float* __restrict__ H2, const float* __restrict__ cw, const float* __restrict__ cb2,
    const float* __restrict__ bw, const float* __restrict__ bb2,
    const unsigned* __restrict__ Mc, float* __restrict__ out10) {
  int r = blockIdx.x;
  if (r >= (int)*Mc) return;
  __shared__ float x[1024];
  const float* h = H2 + (size_t)r * 1024;
  for (int i = threadIdx.x; i < 1024; i += 64) x[i] = h[i];
  __syncthreads();
  int t = threadIdx.x;
  if (t < 10) {
    const float* w = (t < 2) ? (cw + t * 1024) : (bw + (t - 2) * 1024);
    float bias = (t < 2) ? cb2[t] : bb2[t - 2];
    float dot = 0.f;
    for (int k = 0; k < 1024; k++) dot = fmaf(w[k], x[k], dot);
    out10[r * 10 + t] = dot + bias;
  }
}

// ============================ head decode ============================
__global__ __launch_bounds__(256) void head_decode_kernel(
    const float* __restrict__ out10, const float* __restrict__ rois,
    const unsigned* __restrict__ Mc, HeadCand* __restrict__ hc, int b) {
#pragma clang fp contract(off)
  int r = blockIdx.x * 256 + threadIdx.x;
  if (r >= (int)Mc[b]) return;
  const float* h = out10 + (size_t)r * 10;
  float l0 = h[0], l1 = h[1];
  float mx = fmaxf(l0, l1);
  float e0 = expf(l0 - mx), e1 = expf(l1 - mx);
  float sfg = e1 / (e0 + e1);
  const float* rr = rois + ((size_t)b * kPostNms + r) * 4;
  float4 bx = decode_clip(rr[0], rr[1], rr[2], rr[3], h[6], h[7], h[8], h[9],
                          10.f, 10.f, 5.f, 5.f);
  bool keep = (sfg > 0.05f) && (bx.z - bx.x >= 0.01f) && (bx.w - bx.y >= 0.01f);
  HeadCand c;
  c.x1 = bx.x; c.y1 = bx.y; c.x2 = bx.z; c.y2 = bx.w;
  c.score = sfg;
  c.key = keep ? keyOf(sfg) : 0u;
  c.pad0 = c.pad1 = 0;
  hc[r] = c;
}

// ============================ final output ============================
__global__ __launch_bounds__(256) void output_kernel(
    const float* __restrict__ detBox, const float* __restrict__ detSc,
    const unsigned* __restrict__ detCnt, float* __restrict__ out) {
  int t = threadIdx.x;
  if (t >= 200) return;
  int b = t / 100, q = t - b * 100;
  int cnt = (int)detCnt[b];
  float bx0 = 0.f, bx1 = 0.f, bx2 = 0.f, bx3 = 0.f, sc = 0.f, lb = 0.f;
  if (q < cnt) {
    const float* d = detBox + ((size_t)b * 100 + q) * 4;
    bx0 = d[0]; bx1 = d[1]; bx2 = d[2]; bx3 = d[3];
    sc = detSc[b * 100 + q];
    lb = 1.0f;
  }
  float* ob = out + ((size_t)b * 100 + q) * 4;
  ob[0] = bx0; ob[1] = bx1; ob[2] = bx2; ob[3] = bx3;
  out[800 + t] = sc;
  out[1000 + t] = lb;
}

// ============================ host launcher ============================
extern "C" void kernel_launch(void* const* d_in, const int* in_sizes, int n_in,
                              void* d_out, int out_size, void* d_ws, size_t ws_size,
                              hipStream_t stream) {
  (void)in_sizes; (void)n_in; (void)out_size; (void)ws_size;
  const float* feats[4] = {(const float*)d_in[0], (const float*)d_in[1],
                           (const float*)d_in[2], (const float*)d_in[3]};
  const float* w3 = (const float*)d_in[4];
  const float* b3 = (const float*)d_in[5];
  const float* wc = (const float*)d_in[6];
  const float* bcs = (const float*)d_in[7];
  const float* wb = (const float*)d_in[8];
  const float* bbx = (const float*)d_in[9];
  const float* fc6w = (const float*)d_in[10];
  const float* fc6b = (const float*)d_in[11];
  const float* fc7w = (const float*)d_in[12];
  const float* fc7b = (const float*)d_in[13];
  const float* clsw = (const float*)d_in[14];
  const float* clsb = (const float*)d_in[15];
  const float* bboxw = (const float*)d_in[16];
  const float* bboxb = (const float*)d_in[17];

  unsigned char* base = (unsigned char*)d_ws;
  size_t off = 0;
  auto alloc = [&](size_t bytes) -> void* {
    void* p = base + off;
    off += (bytes + 255) & ~(size_t)255;
    return p;
  };
  unsigned* keys = (unsigned*)alloc((size_t)2 * kAImg * 4);
  float* deltas = (float*)alloc((size_t)2 * kAImg * 16);
  unsigned* tkT = (unsigned*)alloc(32);
  unsigned* tkNeed = (unsigned*)alloc(32);
  Cand* cand = (Cand*)alloc((size_t)2 * kNCand * sizeof(Cand));
  unsigned* sortedSlot = (unsigned*)alloc((size_t)2 * 8192 * 4);
  unsigned* validCnt = (unsigned*)alloc(8);
  float4* boxOff = (float4*)alloc((size_t)2 * 8192 * 16);
  float4* boxRaw = (float4*)alloc((size_t)2 * 8192 * 16);
  unsigned long long* rpnMask = (unsigned long long*)alloc((size_t)2 * 8192 * 128 * 8);
  unsigned* keptIdx = (unsigned*)alloc((size_t)2 * kPostNms * 4);
  float* rois = (float*)alloc((size_t)2 * kPostNms * 16);
  unsigned* Mc = (unsigned*)alloc(8);
  RoiParam* roiPar = (RoiParam*)alloc((size_t)2 * kPostNms * sizeof(RoiParam));
  // conv pipeline buffers (reused per image/level)
  u16* padHi = (u16*)alloc((size_t)204 * 202 * 128 * 2);
  u16* padLo = (u16*)alloc((size_t)204 * 202 * 128 * 2);
  u16* wTapHi = (u16*)alloc((size_t)9 * 128 * 128 * 2);
  u16* wTapLo = (u16*)alloc((size_t)9 * 128 * 128 * 2);
  float* tbuf = (float*)alloc((size_t)313 * 128 * 128 * 4);
  u16* pooledHi = (u16*)alloc((size_t)kMPad * 6272 * 2);
  u16* pooledLo = (u16*)alloc((size_t)kMPad * 6272 * 2);
  u16* fc6wHi = (u16*)alloc((size_t)1024 * 6272 * 2);
  u16* fc6wLo = (u16*)alloc((size_t)1024 * 6272 * 2);
  u16* fc7wHi = (u16*)alloc((size_t)1024 * 1024 * 2);
  u16* fc7wLo = (u16*)alloc((size_t)1024 * 1024 * 2);
  float* part = (float*)alloc((size_t)2 * kMPad * 1024 * 4);
  u16* H1hi = (u16*)alloc((size_t)kMPad * 1024 * 2);
  u16* H1lo = (u16*)alloc((size_t)kMPad * 1024 * 2);
  float* H2buf = (float*)alloc((size_t)kMPad * 1024 * 4);
  float* out10 = (float*)alloc((size_t)kPostNms * 10 * 4);
  HeadCand* hc = (HeadCand*)alloc((size_t)kPostNms * sizeof(HeadCand));
  unsigned* hsorted = (unsigned*)alloc((size_t)2048 * 4);
  unsigned* hvalid = (unsigned*)alloc(4);
  float4* hbox = (float4*)alloc((size_t)2048 * 16);
  float* hsc = (float*)alloc((size_t)2048 * 4);
  unsigned long long* hMask = (unsigned long long*)alloc((size_t)2048 * 32 * 8);
  unsigned* hkept = (unsigned*)alloc((size_t)128 * 4);
  float* detBox = (float*)alloc((size_t)2 * 100 * 4 * 4);
  float* detSc = (float*)alloc((size_t)2 * 100 * 4);
  unsigned* detCnt = (unsigned*)alloc(8);

  // anchor base table, double precision, round-half-even (matches np.round)
  AnchTab tab;
  {
    const double aspects[3] = {0.5, 1.0, 2.0};
    const int sizes[4] = {32, 64, 128, 256};
    for (int l = 0; l < 4; l++)
      for (int a = 0; a < 3; a++) {
        double hr = sqrt(aspects[a]);
        double wr = 1.0 / hr;
        double wsz = wr * sizes[l], hsz = hr * sizes[l];
        tab.v[l][a][0] = (float)rint(-wsz / 2.0);
        tab.v[l][a][1] = (float)rint(-hsz / 2.0);
        tab.v[l][a][2] = (float)rint(wsz / 2.0);
        tab.v[l][a][3] = (float)rint(hsz / 2.0);
      }
  }

  const int LH[4] = {200, 100, 50, 25}, LW[4] = {200, 100, 50, 25};
  const int AOFF[4] = {0, 120000, 150000, 157500};

  // weight conversions (same work every call; graph-capture safe)
  convert_split_kernel<<<4096, 256, 0, stream>>>(fc6w, fc6wHi, fc6wLo, 1024 * 6272);
  convert_split_kernel<<<1024, 256, 0, stream>>>(fc7w, fc7wHi, fc7wLo, 1024 * 1024);
  conv_w_repack_kernel<<<(9 * 128 * 128 + 255) / 256, 256, 0, stream>>>(w3, wTapHi, wTapLo);

  // RPN conv pipeline (MFMA implicit GEMM) per image per level
  for (int b = 0; b < 2; b++) {
    for (int l = 0; l < 4; l++) {
      int H = LH[l], W = LW[l];
      int HW = H * W;
      int mtiles = (HW + 127) / 128;
      int n32 = (H + 4) * (W + 2) * 128 / 2;
      zero_u32_kernel<<<512, 256, 0, stream>>>((unsigned*)padHi, n32);
      zero_u32_kernel<<<512, 256, 0, stream>>>((unsigned*)padLo, n32);
      const float* fsrc = feats[l] + (size_t)b * 128 * HW;
      dim3 tgrid((W + 63) / 64, H);
      switch (l) {
        case 0:
          transpose_pad_kernel<200, 200><<<tgrid, 256, 0, stream>>>(fsrc, padHi, padLo);
          conv_mfma_kernel<200, 200><<<mtiles, 256, 0, stream>>>(padHi, padLo, wTapHi, wTapLo, b3, tbuf);
          break;
        case 1:
          transpose_pad_kernel<100, 100><<<tgrid, 256, 0, stream>>>(fsrc, padHi, padLo);
          conv_mfma_kernel<100, 100><<<mtiles, 256, 0, stream>>>(padHi, padLo, wTapHi, wTapLo, b3, tbuf);
          break;
        case 2:
          transpose_pad_kernel<50, 50><<<tgrid, 256, 0, stream>>>(fsrc, padHi, padLo);
          conv_mfma_kernel<50, 50><<<mtiles, 256, 0, stream>>>(padHi, padLo, wTapHi, wTapLo, b3, tbuf);
          break;
        default:
          transpose_pad_kernel<25, 25><<<tgrid, 256, 0, stream>>>(fsrc, padHi, padLo);
          conv_mfma_kernel<25, 25><<<mtiles, 256, 0, stream>>>(padHi, padLo, wTapHi, wTapLo, b3, tbuf);
          break;
      }
      head_1x1_kernel<<<(HW + 255) / 256, 256, 0, stream>>>(
          tbuf, wc, bcs, wb, bbx, keys + (size_t)b * kAImg,
          deltas + (size_t)b * kAImg * 4, AOFF[l], HW);
    }
  }

  radix_select_kernel<<<6, 1024, 0, stream>>>(keys, tkT, tkNeed);
  cand_build_kernel<<<8, 1024, 0, stream>>>(keys, deltas, tkT, tkNeed, cand, tab);
  sort_desc_kernel<8192><<<2, 1024, 0, stream>>>(
      ((const unsigned*)cand) + 4, 8, kNCand, nullptr, sortedSlot, validCnt, kNCand * 8, 8192);
  rpn_sort_gather<<<dim3(32, 2), 256, 0, stream>>>(cand, sortedSlot, validCnt, boxOff, boxRaw);
  nms_mask_kernel<<<dim3(128, 128, 2), 64, 0, stream>>>(
      boxOff, validCnt, rpnMask, 128, 8192, (long long)8192 * 128, 0.7f);
  nms_reduce_kernel<128, kPostNms><<<2, 64, 0, stream>>>(
      rpnMask, validCnt, keptIdx, Mc, (long long)8192 * 128);
  rpn_roi_gather<<<dim3(8, 2), 256, 0, stream>>>(keptIdx, Mc, boxRaw, rois);
  roi_params_kernel<<<dim3(8, 2), 256, 0, stream>>>(rois, Mc, roiPar);

  for (int b = 0; b < 2; b++) {
    pad_pooled_kernel<<<512, 256, 0, stream>>>(pooledHi, pooledLo, Mc, b);
    roi_align_kernel<<<49000, 256, 0, stream>>>(
        feats[0], feats[1], feats[2], feats[3], roiPar + (size_t)b * kPostNms, Mc,
        pooledHi, pooledLo, b);
    // fc6: M=2048, N=1024, K=6272 (split 2 x 98 chunks of 32)
    gemm_f16x3_kernel<<<dim3(8, 16, 2), 256, 0, stream>>>(
        pooledHi, pooledLo, fc6wHi, fc6wLo, part, 6272, 98);
    combine_relu_split_kernel<<<8192, 256, 0, stream>>>(part, fc6b, H1hi, H1lo);
    // fc7: M=2048, N=1024, K=1024 (split 2 x 16 chunks of 32)
    gemm_f16x3_kernel<<<dim3(8, 16, 2), 256, 0, stream>>>(
        H1hi, H1lo, fc7wHi, fc7wLo, part, 1024, 16);
    combine_relu_f32_kernel<<<8192, 256, 0, stream>>>(part, fc7b, H2buf);
    head_linear_kernel<<<2000, 64, 0, stream>>>(H2buf, clsw, clsb, bboxw, bboxb, Mc + b, out10);
    head_decode_kernel<<<8, 256, 0, stream>>>(out10, rois, Mc, hc, b);
    sort_desc_kernel<2048><<<1, 1024, 0, stream>>>(
        ((const unsigned*)hc) + 5, 8, 2000, Mc + b, hsorted, hvalid, 0, 0);
    head_sort_gather<<<8, 256, 0, stream>>>(hc, hsorted, hvalid, hbox, hsc);
    nms_mask_kernel<<<dim3(32, 32, 1), 64, 0, stream>>>(
        hbox, hvalid, hMask, 32, 0, 0, 0.5f);
    nms_reduce_kernel<32, 100><<<1, 64, 0, stream>>>(
        hMask, hvalid, hkept, detCnt + b, 0);
    head_det_gather<<<1, 128, 0, stream>>>(
        hkept, detCnt + b, hbox, hsc, detBox + (size_t)b * 400, detSc + (size_t)b * 100);
  }
  output_kernel<<<1, 256, 0, stream>>>(detBox, detSc, detCnt, (float*)d_out);
}

// Round 6
// 2882.658 us; speedup vs baseline: 4.0572x; 1.0023x over previous
//
#include <hip/hip_runtime.h>
#include <cmath>

// ============================ constants ============================
static constexpr int kAImg = 159375;   // anchors per image
static constexpr int kNCand = 7875;    // 2000+2000+2000+1875
static constexpr int kPostNms = 2000;
static constexpr int kMPad = 2048;     // padded roi count for MFMA GEMM
static constexpr float kISC = 1.0f / 4096.0f;

__constant__ int c_AOFF[4]   = {0, 120000, 150000, 157500};
__constant__ int c_ALVL[4]   = {120000, 30000, 7500, 1875};
__constant__ int c_CBASE[4]  = {0, 2000, 4000, 6000};
__constant__ int c_LW[4]     = {200, 100, 50, 25};
__constant__ int c_LH[4]     = {200, 100, 50, 25};
__constant__ int c_STRIDE[4] = {4, 8, 16, 32};

struct Cand     { float x1, y1, x2, y2; unsigned key; unsigned lvl; unsigned pad0, pad1; };
struct HeadCand { float x1, y1, x2, y2; float score; unsigned key; unsigned pad0, pad1; };
struct RoiParam { int lvl; float x1, y1, rw, rh; int pad0, pad1, pad2; };
struct AnchTab  { float v[4][3][4]; };

typedef unsigned short u16;
typedef __attribute__((ext_vector_type(8))) short short8;
typedef __attribute__((ext_vector_type(4))) float f32x4;
typedef _Float16 f16x8 __attribute__((ext_vector_type(8)));

// ============================ device helpers ============================
__device__ __forceinline__ unsigned keyOf(float f) {
  unsigned u = __float_as_uint(f);
  return (u & 0x80000000u) ? ~u : (u | 0x80000000u);
}

// fp32 -> (f16 hi, f16 lo*4096). value = hi + lo/4096, err ~ 2^-24 relative.
__device__ __forceinline__ void split_f16(float f, u16& hi, u16& lo) {
  union { _Float16 h; u16 u; } a, b;
  a.h = (_Float16)f;
  float r = (f - (float)a.h) * 4096.0f;
  b.h = (_Float16)r;
  hi = a.u; lo = b.u;
}

__device__ __forceinline__ unsigned long long shfl64(unsigned long long v, int src) {
  int lo = __shfl((int)(unsigned)(v & 0xffffffffull), src);
  int hi = __shfl((int)(unsigned)(v >> 32), src);
  return ((unsigned long long)(unsigned)hi << 32) | (unsigned)lo;
}

__device__ __forceinline__ float iou_pair(float4 a, float4 b) {
#pragma clang fp contract(off)
  float ix1 = fmaxf(a.x, b.x), iy1 = fmaxf(a.y, b.y);
  float ix2 = fminf(a.z, b.z), iy2 = fminf(a.w, b.w);
  float iw = fmaxf(ix2 - ix1, 0.f), ih = fmaxf(iy2 - iy1, 0.f);
  float inter = iw * ih;
  float a1 = (a.z - a.x) * (a.w - a.y);
  float a2 = (b.z - b.x) * (b.w - b.y);
  float uni = a1 + a2 - inter;
  return uni > 0.f ? inter / uni : 0.f;
}

__device__ __forceinline__ float4 decode_clip(float bx1, float by1, float bx2, float by2,
                                              float d0, float d1, float d2, float d3,
                                              float wx, float wy, float ww, float wh) {
#pragma clang fp contract(off)
  float w = bx2 - bx1, h = by2 - by1;
  float cx = bx1 + 0.5f * w, cy = by1 + 0.5f * h;
  float dx = d0 / wx, dy = d1 / wy;
  float dw = fminf(d2 / ww, 4.135166556742356f);
  float dh = fminf(d3 / wh, 4.135166556742356f);
  float pcx = dx * w + cx, pcy = dy * h + cy;
  float pw = expf(dw) * w, ph = expf(dh) * h;
  float x1 = pcx - 0.5f * pw, y1 = pcy - 0.5f * ph;
  float x2 = pcx + 0.5f * pw, y2 = pcy + 0.5f * ph;
  x1 = fminf(fmaxf(x1, 0.f), 800.f); y1 = fminf(fmaxf(y1, 0.f), 800.f);
  x2 = fminf(fmaxf(x2, 0.f), 800.f); y2 = fminf(fmaxf(y2, 0.f), 800.f);
  return make_float4(x1, y1, x2, y2);
}

// block-wide exclusive scan of a bool over 1024 threads (16 waves)
__device__ __forceinline__ unsigned block_scan_bool(bool p, unsigned* wbuf, unsigned& total) {
  unsigned long long m = __ballot(p);
  int lane = threadIdx.x & 63;
  int wid = threadIdx.x >> 6;
  unsigned exc = (unsigned)__popcll(m & ((lane == 0) ? 0ull : ((~0ull) >> (64 - lane))));
  if (lane == 0) wbuf[wid] = (unsigned)__popcll(m);
  __syncthreads();
  unsigned pre = 0, tot = 0;
#pragma unroll
  for (int w = 0; w < 16; w++) { unsigned c = wbuf[w]; if (w < wid) pre += c; tot += c; }
  total = tot;
  __syncthreads();
  return pre + exc;
}

// ============================ zero fill ============================
__global__ __launch_bounds__(256) void zero_u32_kernel(unsigned* __restrict__ p, int n32) {
  for (int i = blockIdx.x * 256 + threadIdx.x; i < n32; i += gridDim.x * 256) p[i] = 0u;
}

// ============================ NCHW -> padded HWC f16-split transpose ============================
template <int H, int W>
__global__ __launch_bounds__(256) void transpose_pad_kernel(
    const float* __restrict__ feat, u16* __restrict__ Fh, u16* __restrict__ Fl) {
  __shared__ float tile[128][65];
  int y = blockIdx.y;
  int x0 = blockIdx.x * 64;
  for (int e = threadIdx.x; e < 128 * 64; e += 256) {
    int ci = e >> 6, x = e & 63;
    float v = 0.f;
    if (x0 + x < W) v = feat[(size_t)ci * (H * W) + y * W + x0 + x];
    tile[ci][x] = v;
  }
  __syncthreads();
  for (int e = threadIdx.x; e < 64 * 128; e += 256) {
    int x = e >> 7, ci = e & 127;
    if (x0 + x >= W) continue;
    u16 hi, lo;
    split_f16(tile[ci][x], hi, lo);
    size_t out = ((size_t)(y + 1) * (W + 2) + (x0 + x + 1)) * 128 + ci;
    Fh[out] = hi; Fl[out] = lo;
  }
}

// ============================ conv weight repack: [co][ci][tap] -> [tap][co][ci] f16 split ============================
__global__ __launch_bounds__(256) void conv_w_repack_kernel(
    const float* __restrict__ w3, u16* __restrict__ Wh, u16* __restrict__ Wl) {
  int idx = blockIdx.x * 256 + threadIdx.x;
  if (idx >= 9 * 128 * 128) return;
  int tap = idx >> 14;
  int r = idx & 16383;
  int co = r >> 7, ci = r & 127;
  u16 hi, lo;
  split_f16(w3[co * 1152 + ci * 9 + tap], hi, lo);
  Wh[idx] = hi; Wl[idx] = lo;
}

// ============================ implicit-GEMM MFMA 3x3 conv (f16x3 dual-acc) ============================
template <int H, int W>
__global__ __launch_bounds__(256) void conv_mfma_kernel(
    const u16* __restrict__ Fh, const u16* __restrict__ Fl,
    const u16* __restrict__ Wh, const u16* __restrict__ Wl,
    const float* __restrict__ b3, float* __restrict__ tbuf) {
  __shared__ u16 sAh[128][40], sAl[128][40], sBh[128][40], sBl[128][40];
  int tid = threadIdx.x;
  int m0 = blockIdx.x * 128;
  int w = tid >> 6, lane = tid & 63;
  int wm = (w >> 1) * 64, wn = (w & 1) * 64;
  int quad = lane >> 4, lrow = lane & 15;
  f32x4 acc1[4][4], acc2[4][4];
#pragma unroll
  for (int i = 0; i < 4; i++)
#pragma unroll
    for (int j = 0; j < 4; j++) { acc1[i][j] = (f32x4)0.f; acc2[i][j] = (f32x4)0.f; }

  for (int tap = 0; tap < 9; tap++) {
    int ky = tap / 3, kx = tap - (tap / 3) * 3;
    for (int c = 0; c < 4; c++) {
      for (int e = tid; e < 512; e += 256) {
        int row = e >> 2, seg = (e & 3) * 8;
        int m = m0 + row;
        int y = m / W, x = m - y * W;
        size_t pidx = ((size_t)(y + ky) * (W + 2) + x + kx) * 128 + c * 32 + seg;
        *(short8*)&sAh[row][seg] = *(const short8*)&Fh[pidx];
        *(short8*)&sAl[row][seg] = *(const short8*)&Fl[pidx];
        size_t bidx = ((size_t)tap * 128 + row) * 128 + c * 32 + seg;
        *(short8*)&sBh[row][seg] = *(const short8*)&Wh[bidx];
        *(short8*)&sBl[row][seg] = *(const short8*)&Wl[bidx];
      }
      __syncthreads();
      int kb = quad * 8;
      f16x8 afh[4], afl[4], bfh[4], bfl[4];
#pragma unroll
      for (int t = 0; t < 4; t++) {
        afh[t] = *(const f16x8*)&sAh[wm + t * 16 + lrow][kb];
        afl[t] = *(const f16x8*)&sAl[wm + t * 16 + lrow][kb];
        bfh[t] = *(const f16x8*)&sBh[wn + t * 16 + lrow][kb];
        bfl[t] = *(const f16x8*)&sBl[wn + t * 16 + lrow][kb];
      }
#pragma unroll
      for (int mt = 0; mt < 4; mt++)
#pragma unroll
        for (int nt = 0; nt < 4; nt++) {
          acc1[mt][nt] = __builtin_amdgcn_mfma_f32_16x16x32_f16(afh[mt], bfh[nt], acc1[mt][nt], 0, 0, 0);
          acc2[mt][nt] = __builtin_amdgcn_mfma_f32_16x16x32_f16(afh[mt], bfl[nt], acc2[mt][nt], 0, 0, 0);
          acc2[mt][nt] = __builtin_amdgcn_mfma_f32_16x16x32_f16(afl[mt], bfh[nt], acc2[mt][nt], 0, 0, 0);
        }
      __syncthreads();
    }
  }
#pragma unroll
  for (int nt = 0; nt < 4; nt++) {
    int col = wn + nt * 16 + lrow;
    float bias = b3[col];
#pragma unroll
    for (int mt = 0; mt < 4; mt++) {
#pragma unroll
      for (int reg = 0; reg < 4; reg++) {
        int row = m0 + wm + mt * 16 + quad * 4 + reg;
        float v = acc1[mt][nt][reg] + kISC * acc2[mt][nt][reg] + bias;
        tbuf[(size_t)row * 128 + col] = fmaxf(v, 0.f);
      }
    }
  }
}

// ============================ 1x1 heads from t (HWC fp32) ============================
__global__ __launch_bounds__(256) void head_1x1_kernel(
    const float* __restrict__ tbuf,
    const float* __restrict__ wc, const float* __restrict__ bcs,
    const float* __restrict__ wb, const float* __restrict__ bbx,
    unsigned* __restrict__ keys, float* __restrict__ deltas, int aoff, int HW) {
  __shared__ float wl[15][128];
  __shared__ float bl[15];
  for (int e = threadIdx.x; e < 15 * 128; e += 256) {
    int oc = e >> 7, k = e & 127;
    wl[oc][k] = (oc < 3) ? wc[oc * 128 + k] : wb[(oc - 3) * 128 + k];
  }
  if (threadIdx.x < 15)
    bl[threadIdx.x] = (threadIdx.x < 3) ? bcs[threadIdx.x] : bbx[threadIdx.x - 3];
  __syncthreads();
  int m = blockIdx.x * 256 + threadIdx.x;
  if (m >= HW) return;
  const float* trow = tbuf + (size_t)m * 128;
  float dot[15];
#pragma unroll
  for (int o = 0; o < 15; o++) dot[o] = 0.f;
  for (int k = 0; k < 128; k += 4) {
    float4 v = *(const float4*)&trow[k];
#pragma unroll
    for (int o = 0; o < 15; o++) {
      dot[o] = fmaf(wl[o][k], v.x, dot[o]);
      dot[o] = fmaf(wl[o][k + 1], v.y, dot[o]);
      dot[o] = fmaf(wl[o][k + 2], v.z, dot[o]);
      dot[o] = fmaf(wl[o][k + 3], v.w, dot[o]);
    }
  }
#pragma unroll
  for (int oc = 0; oc < 15; oc++) {
    float s = dot[oc] + bl[oc];
    if (oc < 3) {
      keys[aoff + m * 3 + oc] = keyOf(s);
    } else {
      int bc = oc - 3, a = bc >> 2, comp = bc & 3;
      deltas[(size_t)(aoff + m * 3 + a) * 4 + comp] = s;
    }
  }
}

// ============================ radix select per (image,level 0..2) ============================
__global__ __launch_bounds__(1024) void radix_select_kernel(
    const unsigned* __restrict__ keys, unsigned* __restrict__ tkT, unsigned* __restrict__ tkNeed) {
  int job = blockIdx.x;
  int b = job / 3, l = job - b * 3;
  const unsigned* kb = keys + (size_t)b * kAImg + c_AOFF[l];
  int n = c_ALVL[l];
  __shared__ unsigned hist[256];
  __shared__ unsigned s_sel, s_remk;
  unsigned prefix = 0, pmask = 0, remk = 2000;
  for (int shift = 24; shift >= 0; shift -= 8) {
    if (threadIdx.x < 256) hist[threadIdx.x] = 0;
    __syncthreads();
    for (int i = threadIdx.x; i < n; i += 1024) {
      unsigned key = kb[i];
      if ((key & pmask) == prefix) atomicAdd(&hist[(key >> shift) & 255u], 1u);
    }
    __syncthreads();
    if (threadIdx.x == 0) {
      unsigned cum = 0; int sel = 0;
      for (int d = 255; d >= 0; d--) {
        unsigned c = hist[d];
        if (cum + c >= remk) { sel = d; break; }
        cum += c;
      }
      s_sel = (unsigned)sel; s_remk = remk - cum;
    }
    __syncthreads();
    prefix |= (s_sel << shift);
    pmask |= (255u << shift);
    remk = s_remk;
    __syncthreads();
  }
  if (threadIdx.x == 0) { tkT[b * 4 + l] = prefix; tkNeed[b * 4 + l] = remk; }
}

// ============================ candidate build ============================
__global__ __launch_bounds__(1024) void cand_build_kernel(
    const unsigned* __restrict__ keys, const float* __restrict__ deltas,
    const unsigned* __restrict__ tkT, const unsigned* __restrict__ tkNeed,
    Cand* __restrict__ cand, AnchTab tab) {
  int b = blockIdx.x >> 2, l = blockIdx.x & 3;
  int n = c_ALVL[l];
  int W = c_LW[l];
  int stride = c_STRIDE[l];
  const unsigned* kb = keys + (size_t)b * kAImg + c_AOFF[l];
  const float* db = deltas + ((size_t)b * kAImg + c_AOFF[l]) * 4;
  Cand* cb = cand + (size_t)b * kNCand + c_CBASE[l];
  bool selAll = (l == 3);
  unsigned T = selAll ? 0u : tkT[b * 4 + l];
  unsigned need = selAll ? 0u : tkNeed[b * 4 + l];
  __shared__ unsigned wbuf[16];
  __shared__ unsigned s_runeq, s_runout;
  if (threadIdx.x == 0) { s_runeq = 0; s_runout = 0; }
  __syncthreads();
  for (int c0 = 0; c0 < n; c0 += 1024) {
    int i = c0 + (int)threadIdx.x;
    bool act = i < n;
    unsigned key = act ? kb[i] : 0u;
    bool isEq = (!selAll) && act && (key == T);
    unsigned eqTot;
    unsigned eqExc = block_scan_bool(isEq, wbuf, eqTot);
    unsigned runeq = s_runeq;
    unsigned runout = s_runout;
    bool isSel = act && (selAll || key > T || (isEq && (runeq + eqExc) < need));
    unsigned selTot;
    unsigned selExc = block_scan_bool(isSel, wbuf, selTot);
    if (isSel) {
      int slot = (int)(runout + selExc);
      int pos = i / 3, a = i - pos * 3;
      int yy = pos / W, xx = pos - yy * W;
      float sx = (float)(xx * stride), sy = (float)(yy * stride);
      float ax1 = tab.v[l][a][0] + sx;
      float ay1 = tab.v[l][a][1] + sy;
      float ax2 = tab.v[l][a][2] + sx;
      float ay2 = tab.v[l][a][3] + sy;
      float d0 = db[(size_t)i * 4 + 0], d1 = db[(size_t)i * 4 + 1];
      float d2 = db[(size_t)i * 4 + 2], d3 = db[(size_t)i * 4 + 3];
      float4 bx = decode_clip(ax1, ay1, ax2, ay2, d0, d1, d2, d3, 1.f, 1.f, 1.f, 1.f);
      bool ok = (bx.z - bx.x >= 0.001f) && (bx.w - bx.y >= 0.001f);
      Cand cd;
      cd.x1 = bx.x; cd.y1 = bx.y; cd.x2 = bx.z; cd.y2 = bx.w;
      cd.key = ok ? key : 0u; cd.lvl = (unsigned)l; cd.pad0 = 0; cd.pad1 = 0;
      cb[slot] = cd;
    }
    __syncthreads();
    if (threadIdx.x == 0) { s_runeq = runeq + eqTot; s_runout = runout + selTot; }
    __syncthreads();
  }
}

// ============================ single-block bitonic sort (desc key, asc slot) ============================
template <int NPAD>
__global__ __launch_bounds__(1024) void sort_desc_kernel(
    const unsigned* __restrict__ keyBase, int strideWords, int nFixed,
    const unsigned* __restrict__ nPtr, unsigned* __restrict__ sortedSlot,
    unsigned* __restrict__ validCnt, int imgStrideKeyWords, int imgStrideSlot) {
  __shared__ unsigned sk[NPAD];
  __shared__ unsigned short sslot[NPAD];
  __shared__ unsigned s_cnt;
  int b = blockIdx.x;
  const unsigned* kbase = keyBase + (size_t)b * imgStrideKeyWords;
  unsigned* oslot = sortedSlot + (size_t)b * imgStrideSlot;
  unsigned* ocnt = validCnt + b;
  int n = nFixed;
  if (nPtr) { int m = (int)nPtr[b]; n = n < m ? n : m; }
  for (int i = threadIdx.x; i < NPAD; i += 1024) {
    sk[i] = (i < n) ? kbase[(size_t)i * strideWords] : 0u;
    sslot[i] = (unsigned short)i;
  }
  if (threadIdx.x == 0) s_cnt = 0;
  __syncthreads();
  for (int k2 = 2; k2 <= NPAD; k2 <<= 1) {
    for (int j = k2 >> 1; j > 0; j >>= 1) {
      for (int i = threadIdx.x; i < NPAD; i += 1024) {
        int ixj = i ^ j;
        if (ixj > i) {
          unsigned ka = sk[i], kb2 = sk[ixj];
          unsigned short sa = sslot[i], sb = sslot[ixj];
          bool aGreater = (ka > kb2) || (ka == kb2 && sa < sb);
          bool up = ((i & k2) == 0);
          bool doSwap = up ? (!aGreater) : aGreater;
          if (doSwap) { sk[i] = kb2; sk[ixj] = ka; sslot[i] = sb; sslot[ixj] = sa; }
        }
      }
      __syncthreads();
    }
  }
  unsigned local = 0;
  for (int i = threadIdx.x; i < NPAD; i += 1024) {
    oslot[i] = (unsigned)sslot[i];
    if (sk[i] > 0u) local++;
  }
  atomicAdd(&s_cnt, local);
  __syncthreads();
  if (threadIdx.x == 0) *ocnt = s_cnt;
}

// ============================ sorted gather (RPN): raw boxes per sorted pos ============================
__global__ __launch_bounds__(256) void rpn_sort_gather(
    const Cand* __restrict__ cand, const unsigned* __restrict__ ss,
    const unsigned* __restrict__ validCnt, float4* __restrict__ boxRaw) {
  int b = blockIdx.y;
  int pos = blockIdx.x * 256 + threadIdx.x;
  int valid = (int)validCnt[b];
  float4 raw = make_float4(0.f, 0.f, 0.f, 0.f);
  if (pos < valid) {
    Cand c = cand[(size_t)b * kNCand + ss[(size_t)b * 8192 + pos]];
    raw = make_float4(c.x1, c.y1, c.x2, c.y2);
  }
  boxRaw[(size_t)b * 8192 + pos] = raw;
}

// ============================ per-level stable compaction (sorted order, offset boxes) ============================
__global__ __launch_bounds__(1024) void lvl_compact_kernel(
    const Cand* __restrict__ cand, const unsigned* __restrict__ ss,
    const unsigned* __restrict__ validCnt, float4* __restrict__ boxLvl,
    unsigned* __restrict__ lvlList, unsigned* __restrict__ lvlCnt) {
  int b = blockIdx.x;
  int valid = (int)validCnt[b];
  __shared__ unsigned wbuf[16];
  __shared__ unsigned s_run;
  for (int l = 0; l < 4; l++) {
    if (threadIdx.x == 0) s_run = 0;
    __syncthreads();
    for (int c0 = 0; c0 < 8192; c0 += 1024) {
      int pos = c0 + (int)threadIdx.x;
      bool act = pos < valid;
      unsigned lv = 99u;
      float4 off4 = make_float4(0.f, 0.f, 0.f, 0.f);
      if (act) {
#pragma clang fp contract(off)
        Cand c = cand[(size_t)b * kNCand + ss[(size_t)b * 8192 + pos]];
        lv = c.lvl;
        float off = 801.0f * (float)c.lvl;
        off4 = make_float4(c.x1 + off, c.y1 + off, c.x2 + off, c.y2 + off);
      }
      bool isl = act && (lv == (unsigned)l);
      unsigned tot;
      unsigned exc = block_scan_bool(isl, wbuf, tot);
      unsigned run = s_run;
      if (isl) {
        unsigned slot = run + exc;
        lvlList[((size_t)b * 4 + l) * 2048 + slot] = (unsigned)pos;
        boxLvl[((size_t)b * 4 + l) * 2048 + slot] = off4;
      }
      __syncthreads();
      if (threadIdx.x == 0) s_run = run + tot;
      __syncthreads();
    }
    if (threadIdx.x == 0) lvlCnt[b * 4 + l] = s_run;
    __syncthreads();
  }
}

// ============================ sorted gather (head): boxes + scores ============================
__global__ __launch_bounds__(256) void head_sort_gather(
    const HeadCand* __restrict__ hc, const unsigned* __restrict__ hsorted,
    const unsigned* __restrict__ hvalid, float4* __restrict__ hbox, float* __restrict__ hsc) {
  int pos = blockIdx.x * 256 + threadIdx.x;
  int valid = (int)*hvalid;
  float4 v = make_float4(0.f, 0.f, 0.f, 0.f);
  float s = 0.f;
  if (pos < valid) {
    HeadCand c = hc[hsorted[pos]];
    v = make_float4(c.x1, c.y1, c.x2, c.y2);
    s = c.score;
  }
  hbox[pos] = v;
  hsc[pos] = s;
}

// ============================ NMS suppression-mask build ============================
__global__ __launch_bounds__(64) void nms_mask_kernel(
    const float4* __restrict__ boxesOff, const unsigned* __restrict__ validCnt,
    unsigned long long* __restrict__ mask, int rowStrideWords,
    int imgBoxStride, long long imgMaskStride, float th) {
  int b = blockIdx.z;
  const float4* bx = boxesOff + (size_t)b * imgBoxStride;
  unsigned long long* mrow = mask + (size_t)b * imgMaskStride;
  int valid = (int)validCnt[b];
  int i = blockIdx.x * 64 + threadIdx.x;
  int j0 = blockIdx.y * 64;
  __shared__ float4 sb[64];
  sb[threadIdx.x] = bx[j0 + threadIdx.x];
  __syncthreads();
  float4 a = bx[i];
  unsigned long long bits = 0;
  for (int t = 0; t < 64; t++) {
    int j = j0 + t;
    if (j > i && j < valid && iou_pair(a, sb[t]) > th) bits |= (1ull << t);
  }
  mrow[(size_t)i * rowStrideWords + (j0 >> 6)] = bits;
}

// ============================ NMS reduce (serial scan, register-resident removed mask) ============================
template <int WORDS, int KMAX>
__global__ __launch_bounds__(64) void nms_reduce_kernel(
    const unsigned long long* __restrict__ mask, const unsigned* __restrict__ validCnt,
    unsigned* __restrict__ keptIdx, unsigned* __restrict__ keptCnt,
    long long imgMaskStride) {
  constexpr int WPT = (WORDS + 63) / 64;
  constexpr int C = 8;
  int b = blockIdx.x;
  const unsigned long long* mrow = mask + (size_t)b * imgMaskStride;
  int valid = (int)validCnt[b];
  unsigned* kout = keptIdx + (size_t)b * KMAX;
  int lane = threadIdx.x;
  unsigned long long removed[WPT];
#pragma unroll
  for (int p = 0; p < WPT; p++) removed[p] = 0ull;
  int kept = 0;
  unsigned long long bufA[C][WPT], bufB[C][WPT];

  auto loadc = [&](unsigned long long (&bf)[C][WPT], int cbase) {
#pragma unroll
    for (int t = 0; t < C; t++) {
      int i = cbase + t;
#pragma unroll
      for (int p = 0; p < WPT; p++) {
        int w = lane + 64 * p;
        unsigned long long v = 0ull;
        if (w < WORDS && i < valid) v = mrow[(size_t)i * WORDS + w];
        bf[t][p] = v;
      }
    }
  };

  unsigned long long curw = 0ull;
  int curWidx = -1;

  auto procc = [&](unsigned long long (&bf)[C][WPT], int cbase) {
#pragma unroll
    for (int t = 0; t < C; t++) {
      int i = cbase + t;
      bool act = (i < valid) && (kept < KMAX);
      if (act) {
        int w = i >> 6;
        if (w != curWidx) {
          curWidx = w;
          unsigned long long rv = (WPT > 1 && w >= 64) ? removed[WPT - 1] : removed[0];
          curw = shfl64(rv, w & 63);
        }
        if (!((curw >> (i & 63)) & 1ull)) {
#pragma unroll
          for (int p = 0; p < WPT; p++) removed[p] |= bf[t][p];
          unsigned long long bv = (WPT > 1 && w >= 64) ? bf[t][WPT - 1] : bf[t][0];
          curw |= shfl64(bv, w & 63);
          if (lane == 0) kout[kept] = (unsigned)i;
          kept++;
        }
      }
    }
  };

  loadc(bufA, 0);
  for (int c0 = 0; c0 < valid; c0 += 2 * C) {
    loadc(bufB, c0 + C);
    procc(bufA, c0);
    if (kept >= KMAX) break;
    loadc(bufA, c0 + 2 * C);
    procc(bufB, c0 + C);
    if (kept >= KMAX) break;
  }
  if (threadIdx.x == 0) keptCnt[b] = (unsigned)kept;
}

// ============================ scatter per-level kept -> global-pos flags ============================
__global__ __launch_bounds__(256) void flag_scatter_kernel(
    const unsigned* __restrict__ keptLoc, const unsigned* __restrict__ lvlKeptCnt,
    const unsigned* __restrict__ lvlList, unsigned char* __restrict__ kflag) {
  int job = blockIdx.y;
  int k = blockIdx.x * 256 + threadIdx.x;
  if (k >= (int)lvlKeptCnt[job]) return;
  unsigned local = keptLoc[(size_t)job * 2048 + k];
  unsigned pos = lvlList[(size_t)job * 2048 + local];
  int b = job >> 2;
  kflag[(size_t)b * 8192 + pos] = 1;
}

// ============================ merge kept flags: first 2000 in global sorted order ============================
__global__ __launch_bounds__(1024) void merge_kept_kernel(
    const unsigned char* __restrict__ kflag, const unsigned* __restrict__ validCnt,
    unsigned* __restrict__ keptIdx, unsigned* __restrict__ Mc) {
  int b = blockIdx.x;
  int valid = (int)validCnt[b];
  __shared__ unsigned wbuf[16];
  __shared__ unsigned s_run;
  if (threadIdx.x == 0) s_run = 0;
  __syncthreads();
  for (int c0 = 0; c0 < 8192; c0 += 1024) {
    int i = c0 + (int)threadIdx.x;
    bool k = (i < valid) && kflag[(size_t)b * 8192 + i];
    unsigned tot;
    unsigned exc = block_scan_bool(k, wbuf, tot);
    unsigned run = s_run;
    if (k) {
      unsigned slot = run + exc;
      if (slot < kPostNms) keptIdx[(size_t)b * kPostNms + slot] = (unsigned)i;
    }
    __syncthreads();
    if (threadIdx.x == 0) s_run = run + tot;
    __syncthreads();
  }
  if (threadIdx.x == 0) {
    unsigned r = s_run;
    Mc[b] = r < kPostNms ? r : kPostNms;
  }
}

// ============================ kept-index gathers ============================
__global__ __launch_bounds__(256) void rpn_roi_gather(
    const unsigned* __restrict__ keptIdx, const unsigned* __restrict__ Mc,
    const float4* __restrict__ boxRaw, float* __restrict__ rois) {
  int b = blockIdx.y;
  int k = blockIdx.x * 256 + threadIdx.x;
  if (k >= (int)Mc[b]) return;
  unsigned i = keptIdx[(size_t)b * kPostNms + k];
  float4 v = boxRaw[(size_t)b * 8192 + i];
  float* r = rois + ((size_t)b * kPostNms + k) * 4;
  r[0] = v.x; r[1] = v.y; r[2] = v.z; r[3] = v.w;
}

__global__ __launch_bounds__(128) void head_det_gather(
    const unsigned* __restrict__ keptIdx, const unsigned* __restrict__ cnt,
    const float4* __restrict__ hbox, const float* __restrict__ hsc,
    float* __restrict__ detBox, float* __restrict__ detSc) {
  int k = threadIdx.x;
  if (k >= (int)*cnt || k >= 100) return;
  unsigned i = keptIdx[k];
  float4 v = hbox[i];
  detBox[k * 4 + 0] = v.x; detBox[k * 4 + 1] = v.y;
  detBox[k * 4 + 2] = v.z; detBox[k * 4 + 3] = v.w;
  detSc[k] = hsc[i];
}

// ============================ ROI params ============================
__global__ __launch_bounds__(256) void roi_params_kernel(
    const float* __restrict__ rois, const unsigned* __restrict__ Mc, RoiParam* __restrict__ par) {
  int b = blockIdx.y;
  int i = blockIdx.x * 256 + threadIdx.x;
  if (i >= (int)Mc[b]) return;
  const float* r = rois + ((size_t)b * kPostNms + i) * 4;
  float x1 = r[0], y1 = r[1], x2 = r[2], y2 = r[3];
  float area = (x2 - x1) * (y2 - y1);
  float tgt = floorf(4.0f + log2f(sqrtf(fmaxf(area, 0.f)) / 224.0f + 1e-6f));
  tgt = fminf(fmaxf(tgt, 2.f), 5.f);
  int l = (int)tgt - 2;
  const float scales[4] = {0.25f, 0.125f, 0.0625f, 0.03125f};
  float sc = scales[l];
  RoiParam p;
  p.lvl = l;
  p.x1 = x1 * sc; p.y1 = y1 * sc;
  p.rw = fmaxf(x2 * sc - p.x1, 1.0f);
  p.rh = fmaxf(y2 * sc - p.y1, 1.0f);
  p.pad0 = p.pad1 = p.pad2 = 0;
  par[(size_t)b * kPostNms + i] = p;
}

// ============================ pooled pad (zero rows >= Mc) ============================
__global__ __launch_bounds__(256) void pad_pooled_kernel(
    u16* __restrict__ hi, u16* __restrict__ lo, const unsigned* __restrict__ Mc, int b) {
  int start = (int)Mc[b] * 6272;
  const int total = kMPad * 6272;
  for (int i = start + (int)(blockIdx.x * 256 + threadIdx.x); i < total; i += 512 * 256) {
    hi[i] = 0; lo[i] = 0;
  }
}

// ============================ multi-scale ROI align (writes split-f16) ============================
__global__ __launch_bounds__(256) void roi_align_kernel(
    const float* __restrict__ f0, const float* __restrict__ f1,
    const float* __restrict__ f2, const float* __restrict__ f3,
    const RoiParam* __restrict__ par, const unsigned* __restrict__ Mc,
    u16* __restrict__ pooledHi, u16* __restrict__ pooledLo, int b) {
  int idx = blockIdx.x * 256 + threadIdx.x;
  int roi = idx / 6272;
  if (roi >= (int)Mc[b]) return;
  int rem = idx - roi * 6272;
  int c = rem / 49, bin = rem - c * 49;
  int py = bin / 7, px = bin - py * 7;
  RoiParam p = par[roi];
  int H = c_LH[p.lvl], W = c_LW[p.lvl];
  const float* f = (p.lvl == 0 ? f0 : p.lvl == 1 ? f1 : p.lvl == 2 ? f2 : f3);
  f += ((size_t)b * 128 + c) * (size_t)(H * W);
  float Hf = (float)H, Wf = (float)W;
  float rh7 = p.rh / 7.0f, rw7 = p.rw / 7.0f;
  float sum = 0.f;
#pragma unroll
  for (int sy = 0; sy < 2; sy++) {
    float offy = (float)py + ((float)sy + 0.5f) * 0.5f;
    float Y = p.y1 + offy * rh7;
    float yc = fminf(fmaxf(Y, 0.f), Hf - 1.f);
    float y0f = floorf(yc);
    int y0 = (int)y0f;
    int y1 = min(y0 + 1, H - 1);
    float ly = yc - y0f, hy = 1.f - ly;
#pragma unroll
    for (int sx = 0; sx < 2; sx++) {
      float offx = (float)px + ((float)sx + 0.5f) * 0.5f;
      float X = p.x1 + offx * rw7;
      bool valid = (Y > -1.f) && (Y < Hf) && (X > -1.f) && (X < Wf);
      float xc = fminf(fmaxf(X, 0.f), Wf - 1.f);
      float x0f = floorf(xc);
      int x0 = (int)x0f;
      int x1i = min(x0 + 1, W - 1);
      float lx = xc - x0f, hx = 1.f - lx;
      float v = hy * hx * f[y0 * W + x0] + hy * lx * f[y0 * W + x1i] +
                ly * hx * f[y1 * W + x0] + ly * lx * f[y1 * W + x1i];
      sum += valid ? v : 0.f;
    }
  }
  float v = sum * 0.25f;
  u16 hi, lo;
  split_f16(v, hi, lo);
  pooledHi[idx] = hi;
  pooledLo[idx] = lo;
}

// ============================ weight split conversion ============================
__global__ __launch_bounds__(256) void convert_split_kernel(
    const float* __restrict__ src, u16* __restrict__ hi, u16* __restrict__ lo, int n) {
  for (int i = blockIdx.x * 256 + threadIdx.x; i < n; i += gridDim.x * 256) {
    u16 h, l;
    split_f16(src[i], h, l);
    hi[i] = h; lo[i] = l;
  }
}

// ============================ f16x3 dual-acc split-K MFMA GEMM ============================
__global__ __launch_bounds__(256) void gemm_f16x3_kernel(
    const u16* __restrict__ Ah, const u16* __restrict__ Al,
    const u16* __restrict__ Bh, const u16* __restrict__ Bl,
    float* __restrict__ Cpart, int K, int kChunks) {
  __shared__ u16 sAh[128][40], sAl[128][40], sBh[128][40], sBl[128][40];
  int tid = threadIdx.x;
  int m0 = blockIdx.y * 128, n0 = blockIdx.x * 128;
  int kBase = blockIdx.z * kChunks * 32;
  int w = tid >> 6, lane = tid & 63;
  int wm = (w >> 1) * 64, wn = (w & 1) * 64;
  int quad = lane >> 4, lrow = lane & 15;
  f32x4 acc1[4][4], acc2[4][4];
#pragma unroll
  for (int i = 0; i < 4; i++)
#pragma unroll
    for (int j = 0; j < 4; j++) { acc1[i][j] = (f32x4)0.f; acc2[i][j] = (f32x4)0.f; }

  for (int c = 0; c < kChunks; c++) {
    int k0 = kBase + c * 32;
    for (int e = tid; e < 512; e += 256) {
      int row = e >> 2, kk = (e & 3) * 8;
      size_t ga = (size_t)(m0 + row) * K + k0 + kk;
      size_t gb = (size_t)(n0 + row) * K + k0 + kk;
      *(short8*)&sAh[row][kk] = *(const short8*)&Ah[ga];
      *(short8*)&sAl[row][kk] = *(const short8*)&Al[ga];
      *(short8*)&sBh[row][kk] = *(const short8*)&Bh[gb];
      *(short8*)&sBl[row][kk] = *(const short8*)&Bl[gb];
    }
    __syncthreads();
    int kb = quad * 8;
    f16x8 afh[4], afl[4], bfh[4], bfl[4];
#pragma unroll
    for (int t = 0; t < 4; t++) {
      afh[t] = *(const f16x8*)&sAh[wm + t * 16 + lrow][kb];
      afl[t] = *(const f16x8*)&sAl[wm + t * 16 + lrow][kb];
      bfh[t] = *(const f16x8*)&sBh[wn + t * 16 + lrow][kb];
      bfl[t] = *(const f16x8*)&sBl[wn + t * 16 + lrow][kb];
    }
#pragma unroll
    for (int mt = 0; mt < 4; mt++)
#pragma unroll
      for (int nt = 0; nt < 4; nt++) {
        acc1[mt][nt] = __builtin_amdgcn_mfma_f32_16x16x32_f16(afh[mt], bfh[nt], acc1[mt][nt], 0, 0, 0);
        acc2[mt][nt] = __builtin_amdgcn_mfma_f32_16x16x32_f16(afh[mt], bfl[nt], acc2[mt][nt], 0, 0, 0);
        acc2[mt][nt] = __builtin_amdgcn_mfma_f32_16x16x32_f16(afl[mt], bfh[nt], acc2[mt][nt], 0, 0, 0);
      }
    __syncthreads();
  }
  float* out = Cpart + (size_t)blockIdx.z * (kMPad * 1024);
#pragma unroll
  for (int mt = 0; mt < 4; mt++)
#pragma unroll
    for (int nt = 0; nt < 4; nt++) {
      int col = n0 + wn + nt * 16 + lrow;
#pragma unroll
      for (int reg = 0; reg < 4; reg++) {
        int row = m0 + wm + mt * 16 + quad * 4 + reg;
        out[(size_t)row * 1024 + col] = acc1[mt][nt][reg] + kISC * acc2[mt][nt][reg];
      }
    }
}

// ============================ combine partials: bias+relu -> split-f16 ============================
__global__ __launch_bounds__(256) void combine_relu_split_kernel(
    const float* __restrict__ part, const float* __restrict__ bias,
    u16* __restrict__ hi, u16* __restrict__ lo) {
  int idx = blockIdx.x * 256 + threadIdx.x;
  int n = idx & 1023;
  float v = fmaxf(part[idx] + part[idx + kMPad * 1024] + bias[n], 0.f);
  u16 h, l;
  split_f16(v, h, l);
  hi[idx] = h; lo[idx] = l;
}

// ============================ combine partials: bias+relu -> f32 ============================
__global__ __launch_bounds__(256) void combine_relu_f32_kernel(
    const float* __restrict__ part, const float* __restrict__ bias,
    float* __restrict__ out) {
  int idx = blockIdx.x * 256 + threadIdx.x;
  int n = idx & 1023;
  out[idx] = fmaxf(part[idx] + part[idx + kMPad * 1024] + bias[n], 0.f);
}

// ============================ head linear (cls 2 + bbox 8 per roi) ============================
__global__ __launch_bounds__(64) void head_linear_kernel(
    const float* __restrict__ H2, const float* __restrict__ cw, const float* __restrict__ cb2,
    const float* __restrict__ bw, const float* __restrict__ bb2,
    const unsigned* __restrict__ Mc, float* __restrict__ out10) {
  int r = blockIdx.x;
  if (r >= (int)*Mc) return;
  __shared__ float x[1024];
  const float* h = H2 + (size_t)r * 1024;
  for (int i = threadIdx.x; i < 1024; i += 64) x[i] = h[i];
  __syncthreads();
  int t = threadIdx.x;
  if (t < 10) {
    const float* w = (t < 2) ? (cw + t * 1024) : (bw + (t - 2) * 1024);
    float bias = (t < 2) ? cb2[t] : bb2[t - 2];
    float dot = 0.f;
    for (int k = 0; k < 1024; k++) dot = fmaf(w[k], x[k], dot);
    out10[r * 10 + t] = dot + bias;
  }
}

// ============================ head decode ============================
__global__ __launch_bounds__(256) void head_decode_kernel(
    const float* __restrict__ out10, const float* __restrict__ rois,
    const unsigned* __restrict__ Mc, HeadCand* __restrict__ hc, int b) {
#pragma clang fp contract(off)
  int r = blockIdx.x * 256 + threadIdx.x;
  if (r >= (int)Mc[b]) return;
  const float* h = out10 + (size_t)r * 10;
  float l0 = h[0], l1 = h[1];
  float mx = fmaxf(l0, l1);
  float e0 = expf(l0 - mx), e1 = expf(l1 - mx);
  float sfg = e1 / (e0 + e1);
  const float* rr = rois + ((size_t)b * kPostNms + r) * 4;
  float4 bx = decode_clip(rr[0], rr[1], rr[2], rr[3], h[6], h[7], h[8], h[9],
                          10.f, 10.f, 5.f, 5.f);
  bool keep = (sfg > 0.05f) && (bx.z - bx.x >= 0.01f) && (bx.w - bx.y >= 0.01f);
  HeadCand c;
  c.x1 = bx.x; c.y1 = bx.y; c.x2 = bx.z; c.y2 = bx.w;
  c.score = sfg;
  c.key = keep ? keyOf(sfg) : 0u;
  c.pad0 = c.pad1 = 0;
  hc[r] = c;
}

// ============================ final output ============================
__global__ __launch_bounds__(256) void output_kernel(
    const float* __restrict__ detBox, const float* __restrict__ detSc,
    const unsigned* __restrict__ detCnt, float* __restrict__ out) {
  int t = threadIdx.x;
  if (t >= 200) return;
  int b = t / 100, q = t - b * 100;
  int cnt = (int)detCnt[b];
  float bx0 = 0.f, bx1 = 0.f, bx2 = 0.f, bx3 = 0.f, sc = 0.f, lb = 0.f;
  if (q < cnt) {
    const float* d = detBox + ((size_t)b * 100 + q) * 4;
    bx0 = d[0]; bx1 = d[1]; bx2 = d[2]; bx3 = d[3];
    sc = detSc[b * 100 + q];
    lb = 1.0f;
  }
  float* ob = out + ((size_t)b * 100 + q) * 4;
  ob[0] = bx0; ob[1] = bx1; ob[2] = bx2; ob[3] = bx3;
  out[800 + t] = sc;
  out[1000 + t] = lb;
}

// ============================ host launcher ============================
extern "C" void kernel_launch(void* const* d_in, const int* in_sizes, int n_in,
                              void* d_out, int out_size, void* d_ws, size_t ws_size,
                              hipStream_t stream) {
  (void)in_sizes; (void)n_in; (void)out_size; (void)ws_size;
  const float* feats[4] = {(const float*)d_in[0], (const float*)d_in[1],
                           (const float*)d_in[2], (const float*)d_in[3]};
  const float* w3 = (const float*)d_in[4];
  const float* b3 = (const float*)d_in[5];
  const float* wc = (const float*)d_in[6];
  const float* bcs = (const float*)d_in[7];
  const float* wb = (const float*)d_in[8];
  const float* bbx = (const float*)d_in[9];
  const float* fc6w = (const float*)d_in[10];
  const float* fc6b = (const float*)d_in[11];
  const float* fc7w = (const float*)d_in[12];
  const float* fc7b = (const float*)d_in[13];
  const float* clsw = (const float*)d_in[14];
  const float* clsb = (const float*)d_in[15];
  const float* bboxw = (const float*)d_in[16];
  const float* bboxb = (const float*)d_in[17];

  unsigned char* base = (unsigned char*)d_ws;
  size_t off = 0;
  auto alloc = [&](size_t bytes) -> void* {
    void* p = base + off;
    off += (bytes + 255) & ~(size_t)255;
    return p;
  };
  unsigned* keys = (unsigned*)alloc((size_t)2 * kAImg * 4);
  float* deltas = (float*)alloc((size_t)2 * kAImg * 16);
  unsigned* tkT = (unsigned*)alloc(32);
  unsigned* tkNeed = (unsigned*)alloc(32);
  Cand* cand = (Cand*)alloc((size_t)2 * kNCand * sizeof(Cand));
  unsigned* sortedSlot = (unsigned*)alloc((size_t)2 * 8192 * 4);
  unsigned* validCnt = (unsigned*)alloc(8);
  float4* boxRaw = (float4*)alloc((size_t)2 * 8192 * 16);
  float4* boxLvl = (float4*)alloc((size_t)8 * 2048 * 16);
  unsigned* lvlList = (unsigned*)alloc((size_t)8 * 2048 * 4);
  unsigned* lvlCnt = (unsigned*)alloc(32);
  unsigned long long* lvlMask = (unsigned long long*)alloc((size_t)8 * 2048 * 32 * 8);
  unsigned* keptLoc = (unsigned*)alloc((size_t)8 * 2048 * 4);
  unsigned* lvlKeptCnt = (unsigned*)alloc(32);
  unsigned char* kflag = (unsigned char*)alloc((size_t)2 * 8192);
  unsigned* keptIdx = (unsigned*)alloc((size_t)2 * kPostNms * 4);
  float* rois = (float*)alloc((size_t)2 * kPostNms * 16);
  unsigned* Mc = (unsigned*)alloc(8);
  RoiParam* roiPar = (RoiParam*)alloc((size_t)2 * kPostNms * sizeof(RoiParam));
  // conv pipeline buffers (reused per image/level)
  u16* padHi = (u16*)alloc((size_t)204 * 202 * 128 * 2);
  u16* padLo = (u16*)alloc((size_t)204 * 202 * 128 * 2);
  u16* wTapHi = (u16*)alloc((size_t)9 * 128 * 128 * 2);
  u16* wTapLo = (u16*)alloc((size_t)9 * 128 * 128 * 2);
  float* tbuf = (float*)alloc((size_t)313 * 128 * 128 * 4);
  u16* pooledHi = (u16*)alloc((size_t)kMPad * 6272 * 2);
  u16* pooledLo = (u16*)alloc((size_t)kMPad * 6272 * 2);
  u16* fc6wHi = (u16*)alloc((size_t)1024 * 6272 * 2);
  u16* fc6wLo = (u16*)alloc((size_t)1024 * 6272 * 2);
  u16* fc7wHi = (u16*)alloc((size_t)1024 * 1024 * 2);
  u16* fc7wLo = (u16*)alloc((size_t)1024 * 1024 * 2);
  float* part = (float*)alloc((size_t)2 * kMPad * 1024 * 4);
  u16* H1hi = (u16*)alloc((size_t)kMPad * 1024 * 2);
  u16* H1lo = (u16*)alloc((size_t)kMPad * 1024 * 2);
  float* H2buf = (float*)alloc((size_t)kMPad * 1024 * 4);
  float* out10 = (float*)alloc((size_t)kPostNms * 10 * 4);
  HeadCand* hc = (HeadCand*)alloc((size_t)kPostNms * sizeof(HeadCand));
  unsigned* hsorted = (unsigned*)alloc((size_t)2048 * 4);
  unsigned* hvalid = (unsigned*)alloc(4);
  float4* hbox = (float4*)alloc((size_t)2048 * 16);
  float* hsc = (float*)alloc((size_t)2048 * 4);
  unsigned long long* hMask = (unsigned long long*)alloc((size_t)2048 * 32 * 8);
  unsigned* hkept = (unsigned*)alloc((size_t)128 * 4);
  float* detBox = (float*)alloc((size_t)2 * 100 * 4 * 4);
  float* detSc = (float*)alloc((size_t)2 * 100 * 4);
  unsigned* detCnt = (unsigned*)alloc(8);

  // anchor base table, double precision, round-half-even (matches np.round)
  AnchTab tab;
  {
    const double aspects[3] = {0.5, 1.0, 2.0};
    const int sizes[4] = {32, 64, 128, 256};
    for (int l = 0; l < 4; l++)
      for (int a = 0; a < 3; a++) {
        double hr = sqrt(aspects[a]);
        double wr = 1.0 / hr;
        double wsz = wr * sizes[l], hsz = hr * sizes[l];
        tab.v[l][a][0] = (float)rint(-wsz / 2.0);
        tab.v[l][a][1] = (float)rint(-hsz / 2.0);
        tab.v[l][a][2] = (float)rint(wsz / 2.0);
        tab.v[l][a][3] = (float)rint(hsz / 2.0);
      }
  }

  const int LH[4] = {200, 100, 50, 25}, LW[4] = {200, 100, 50, 25};
  const int AOFF[4] = {0, 120000, 150000, 157500};

  // weight conversions (same work every call; graph-capture safe)
  convert_split_kernel<<<4096, 256, 0, stream>>>(fc6w, fc6wHi, fc6wLo, 1024 * 6272);
  convert_split_kernel<<<1024, 256, 0, stream>>>(fc7w, fc7wHi, fc7wLo, 1024 * 1024);
  conv_w_repack_kernel<<<(9 * 128 * 128 + 255) / 256, 256, 0, stream>>>(w3, wTapHi, wTapLo);

  // RPN conv pipeline (MFMA implicit GEMM) per image per level
  for (int b = 0; b < 2; b++) {
    for (int l = 0; l < 4; l++) {
      int H = LH[l], W = LW[l];
      int HW = H * W;
      int mtiles = (HW + 127) / 128;
      int n32 = (H + 4) * (W + 2) * 128 / 2;
      zero_u32_kernel<<<512, 256, 0, stream>>>((unsigned*)padHi, n32);
      zero_u32_kernel<<<512, 256, 0, stream>>>((unsigned*)padLo, n32);
      const float* fsrc = feats[l] + (size_t)b * 128 * HW;
      dim3 tgrid((W + 63) / 64, H);
      switch (l) {
        case 0:
          transpose_pad_kernel<200, 200><<<tgrid, 256, 0, stream>>>(fsrc, padHi, padLo);
          conv_mfma_kernel<200, 200><<<mtiles, 256, 0, stream>>>(padHi, padLo, wTapHi, wTapLo, b3, tbuf);
          break;
        case 1:
          transpose_pad_kernel<100, 100><<<tgrid, 256, 0, stream>>>(fsrc, padHi, padLo);
          conv_mfma_kernel<100, 100><<<mtiles, 256, 0, stream>>>(padHi, padLo, wTapHi, wTapLo, b3, tbuf);
          break;
        case 2:
          transpose_pad_kernel<50, 50><<<tgrid, 256, 0, stream>>>(fsrc, padHi, padLo);
          conv_mfma_kernel<50, 50><<<mtiles, 256, 0, stream>>>(padHi, padLo, wTapHi, wTapLo, b3, tbuf);
          break;
        default:
          transpose_pad_kernel<25, 25><<<tgrid, 256, 0, stream>>>(fsrc, padHi, padLo);
          conv_mfma_kernel<25, 25><<<mtiles, 256, 0, stream>>>(padHi, padLo, wTapHi, wTapLo, b3, tbuf);
          break;
      }
      head_1x1_kernel<<<(HW + 255) / 256, 256, 0, stream>>>(
          tbuf, wc, bcs, wb, bbx, keys + (size_t)b * kAImg,
          deltas + (size_t)b * kAImg * 4, AOFF[l], HW);
    }
  }

  radix_select_kernel<<<6, 1024, 0, stream>>>(keys, tkT, tkNeed);
  cand_build_kernel<<<8, 1024, 0, stream>>>(keys, deltas, tkT, tkNeed, cand, tab);
  sort_desc_kernel<8192><<<2, 1024, 0, stream>>>(
      ((const unsigned*)cand) + 4, 8, kNCand, nullptr, sortedSlot, validCnt, kNCand * 8, 8192);
  rpn_sort_gather<<<dim3(32, 2), 256, 0, stream>>>(cand, sortedSlot, validCnt, boxRaw);
  lvl_compact_kernel<<<2, 1024, 0, stream>>>(cand, sortedSlot, validCnt, boxLvl, lvlList, lvlCnt);
  // per-(image,level) masks: 8 jobs, 2048 boxes, 32 words/row
  nms_mask_kernel<<<dim3(32, 32, 8), 64, 0, stream>>>(
      boxLvl, lvlCnt, lvlMask, 32, 2048, (long long)2048 * 32, 0.7f);
  nms_reduce_kernel<32, 2048><<<8, 64, 0, stream>>>(
      lvlMask, lvlCnt, keptLoc, lvlKeptCnt, (long long)2048 * 32);
  zero_u32_kernel<<<16, 256, 0, stream>>>((unsigned*)kflag, 4096);
  flag_scatter_kernel<<<dim3(8, 8), 256, 0, stream>>>(keptLoc, lvlKeptCnt, lvlList, kflag);
  merge_kept_kernel<<<2, 1024, 0, stream>>>(kflag, validCnt, keptIdx, Mc);
  rpn_roi_gather<<<dim3(8, 2), 256, 0, stream>>>(keptIdx, Mc, boxRaw, rois);
  roi_params_kernel<<<dim3(8, 2), 256, 0, stream>>>(rois, Mc, roiPar);

  for (int b = 0; b < 2; b++) {
    pad_pooled_kernel<<<512, 256, 0, stream>>>(pooledHi, pooledLo, Mc, b);
    roi_align_kernel<<<49000, 256, 0, stream>>>(
        feats[0], feats[1], feats[2], feats[3], roiPar + (size_t)b * kPostNms, Mc,
        pooledHi, pooledLo, b);
    // fc6: M=2048, N=1024, K=6272 (split 2 x 98 chunks of 32)
    gemm_f16x3_kernel<<<dim3(8, 16, 2), 256, 0, stream>>>(
        pooledHi, pooledLo, fc6wHi, fc6wLo, part, 6272, 98);
    combine_relu_split_kernel<<<8192, 256, 0, stream>>>(part, fc6b, H1hi, H1lo);
    // fc7: M=2048, N=1024, K=1024 (split 2 x 16 chunks of 32)
    gemm_f16x3_kernel<<<dim3(8, 16, 2), 256, 0, stream>>>(
        H1hi, H1lo, fc7wHi, fc7wLo, part, 1024, 16);
    combine_relu_f32_kernel<<<8192, 256, 0, stream>>>(part, fc7b, H2buf);
    head_linear_kernel<<<2000, 64, 0, stream>>>(H2buf, clsw, clsb, bboxw, bboxb, Mc + b, out10);
    head_decode_kernel<<<8, 256, 0, stream>>>(out10, rois, Mc, hc, b);
    sort_desc_kernel<2048><<<1, 1024, 0, stream>>>(
        ((const unsigned*)hc) + 5, 8, 2000, Mc + b, hsorted, hvalid, 0, 0);
    head_sort_gather<<<8, 256, 0, stream>>>(hc, hsorted, hvalid, hbox, hsc);
    nms_mask_kernel<<<dim3(32, 32, 1), 64, 0, stream>>>(
        hbox, hvalid, hMask, 32, 0, 0, 0.5f);
    nms_reduce_kernel<32, 100><<<1, 64, 0, stream>>>(
        hMask, hvalid, hkept, detCnt + b, 0);
    head_det_gather<<<1, 128, 0, stream>>>(
        hkept, detCnt + b, hbox, hsc, detBox + (size_t)b * 400, detSc + (size_t)b * 100);
  }
  output_kernel<<<1, 256, 0, stream>>>(detBox, detSc, detCnt, (float*)d_out);
}